// Round 2
// baseline (10848.376 us; speedup 1.0000x reference)
//
#include <hip/hip_runtime.h>
#include <hip/hip_bf16.h>

#define N_NODES 50000
#define N_EDGES 800000
#define ET (N_EDGES + N_NODES)   // self-loops appended at the end
#define D1 128                   // heads1*ch1 = 8*16
#define H1 8
#define D2 64
#define NEG 0.2f
#define EPSF 1e-16f

// ---- ws layout (float offsets) ----
#define O_XL1   0          // 6,400,000
#define O_XR1   6400000    // 6,400,000
#define O_XF    12800000   // 6,400,000  (x as f32; later reused as Cacc)
#define O_E1    19200000   // 6,800,000  (ET*H1)
#define O_EMAX1 26000000   // 400,000
#define O_DEN1  26400000   // 400,000
#define O_WF    26800000   // 50,000 (converted params)
#define O_SRC   26850000   // 850,000 ints
#define O_DST   27700000   // 850,000 ints
#define O_FLAGS 28550000   // 2 ints
// total ~28.55M floats = 114.2 MB

// ---- Wf internal offsets ----
#define W_WL1   0
#define W_BL1   16384
#define W_WR1   16512
#define W_BR1   32896
#define W_ATT1  33024
#define W_BIAS1 33152
#define W_WL2   33280
#define W_BL2   41472
#define W_WR2   41536
#define W_BR2   49728
#define W_ATT2  49792
#define W_BIAS2 49856

// float atomic max via int/uint trick (valid for mixed signs; init <= all values)
__device__ __forceinline__ void atomicMaxF(float* a, float v) {
    if (v >= 0.f) atomicMax((int*)a, __float_as_int(v));
    else          atomicMin((unsigned int*)a, __float_as_uint(v));
}

__global__ void fill_k(float* p, int n, float v) {
    int i = blockIdx.x * blockDim.x + threadIdx.x;
    if (i < n) p[i] = v;
}

// flags[0]: 1 if float data is bf16-packed, 0 if f32.
// flags[1]: 1 if edge_index is int64 (int32-view odd words all zero), 0 if int32.
__global__ void detect_k(const unsigned short* x16, const int* ei32, int* flags) {
    if (threadIdx.x != 0 || blockIdx.x != 0) return;
    int hits = 0;
    for (int j = 0; j < 65536; j += 2) {          // even half-words: f32 low-mantissa if f32
        unsigned short u = x16[j];
        if (((u >> 7) & 0xFF) == 0xFF) hits++;    // exp all-ones => can't be sane bf16 data
    }
    flags[0] = (hits > 0) ? 0 : 1;
    int nz = 0;
    for (int j = 1; j < 64; j += 2) nz |= ei32[j];
    flags[1] = (nz == 0) ? 1 : 0;
}

__global__ void cvt_arr(const void* src, float* dst, int n, const int* flags) {
    int i = blockIdx.x * 256 + threadIdx.x;
    if (i >= n) return;
    if (flags[0]) {
        unsigned short u = ((const unsigned short*)src)[i];
        dst[i] = __uint_as_float((unsigned)u << 16);
    } else {
        dst[i] = ((const float*)src)[i];
    }
}

__global__ void cvt_edges(const int* ei, const int* flags, int* srcA, int* dstA) {
    int e = blockIdx.x * 256 + threadIdx.x;
    if (e >= ET) return;
    int s, d;
    if (e < N_EDGES) {
        if (flags[1]) { s = ei[2 * e]; d = ei[2 * (N_EDGES + e)]; }
        else          { s = ei[e];     d = ei[N_EDGES + e]; }
    } else {
        s = d = e - N_EDGES;
    }
    srcA[e] = s; dstA[e] = d;
}

// xl = x@Wl + bl ; xr = x@Wr + br (per-node block, 256 threads: lower half xl, upper half xr)
__global__ __launch_bounds__(256) void gemm1_k(const float* __restrict__ x, const float* __restrict__ Wf,
                                               float* __restrict__ xl, float* __restrict__ xr) {
    int n = blockIdx.x;
    __shared__ float xs[D1];
    int t = threadIdx.x;
    if (t < D1) xs[t] = x[(size_t)n * D1 + t];
    __syncthreads();
    int col = t & (D1 - 1);
    const float* W = Wf + ((t < D1) ? W_WL1 : W_WR1);
    const float* b = Wf + ((t < D1) ? W_BL1 : W_BR1);
    float acc = 0.f;
#pragma unroll
    for (int k = 0; k < D1; k++) acc += xs[k] * W[k * D1 + col];
    acc += b[col];
    ((t < D1) ? xl : xr)[(size_t)n * D1 + col] = acc;
}

__global__ __launch_bounds__(128) void gemm2_k(const float* __restrict__ h, const float* __restrict__ Wf,
                                               float* __restrict__ xl2, float* __restrict__ xr2) {
    int n = blockIdx.x;
    __shared__ float hs[D1];
    int t = threadIdx.x;
    hs[t] = h[(size_t)n * D1 + t];
    __syncthreads();
    int col = t & (D2 - 1);
    const float* W = Wf + ((t < D2) ? W_WL2 : W_WR2);
    const float* b = Wf + ((t < D2) ? W_BL2 : W_BR2);
    float acc = 0.f;
#pragma unroll
    for (int k = 0; k < D1; k++) acc += hs[k] * W[k * D2 + col];
    acc += b[col];
    ((t < D2) ? xl2 : xr2)[(size_t)n * D2 + col] = acc;
}

__global__ __launch_bounds__(256) void l1_edge_e(const int* __restrict__ srcA, const int* __restrict__ dstA,
                                                 const float* __restrict__ xl, const float* __restrict__ xr,
                                                 const float* __restrict__ att,
                                                 float* __restrict__ e1, float* __restrict__ emax) {
    __shared__ float att_s[D1];
    if (threadIdx.x < D1) att_s[threadIdx.x] = att[threadIdx.x];
    __syncthreads();
    int eid = blockIdx.x * 256 + threadIdx.x;
    if (eid >= ET) return;
    int s = srcA[eid], d = dstA[eid];
    const float4* ps = (const float4*)(xl + (size_t)s * D1);
    const float4* pd = (const float4*)(xr + (size_t)d * D1);
    float e[H1];
#pragma unroll
    for (int h = 0; h < H1; h++) e[h] = 0.f;
#pragma unroll
    for (int q = 0; q < D1 / 4; q++) {
        float4 a = ps[q], b = pd[q];
        int h = q >> 2;
        float m;
        m = a.x + b.x; m = m > 0.f ? m : NEG * m; e[h] += m * att_s[4 * q + 0];
        m = a.y + b.y; m = m > 0.f ? m : NEG * m; e[h] += m * att_s[4 * q + 1];
        m = a.z + b.z; m = m > 0.f ? m : NEG * m; e[h] += m * att_s[4 * q + 2];
        m = a.w + b.w; m = m > 0.f ? m : NEG * m; e[h] += m * att_s[4 * q + 3];
    }
#pragma unroll
    for (int h = 0; h < H1; h++) {
        e1[(size_t)eid * H1 + h] = e[h];
        atomicMaxF(&emax[d * H1 + h], e[h]);
    }
}

__global__ __launch_bounds__(256) void l1_edge_exp(const int* __restrict__ dstA,
                                                   float* __restrict__ e1,
                                                   const float* __restrict__ emax, float* __restrict__ den) {
    int eid = blockIdx.x * 256 + threadIdx.x;
    if (eid >= ET) return;
    int d = dstA[eid];
#pragma unroll
    for (int h = 0; h < H1; h++) {
        float ee = expf(e1[(size_t)eid * H1 + h] - emax[d * H1 + h]);
        e1[(size_t)eid * H1 + h] = ee;
        atomicAdd(&den[d * H1 + h], ee);
    }
}

__global__ __launch_bounds__(256) void l1_scatter(const int* __restrict__ srcA, const int* __restrict__ dstA,
                                                  const float* __restrict__ e1, const float* __restrict__ den,
                                                  const float* __restrict__ xl, float* __restrict__ out) {
    int eid = blockIdx.x * 256 + threadIdx.x;
    if (eid >= ET) return;
    int s = srcA[eid], d = dstA[eid];
    float alpha[H1];
#pragma unroll
    for (int h = 0; h < H1; h++) alpha[h] = e1[(size_t)eid * H1 + h] / (den[d * H1 + h] + EPSF);
    const float4* ps = (const float4*)(xl + (size_t)s * D1);
    float* od = out + (size_t)d * D1;
#pragma unroll
    for (int q = 0; q < D1 / 4; q++) {
        float4 a = ps[q];
        float al = alpha[q >> 2];
        atomicAdd(&od[4 * q + 0], a.x * al);
        atomicAdd(&od[4 * q + 1], a.y * al);
        atomicAdd(&od[4 * q + 2], a.z * al);
        atomicAdd(&od[4 * q + 3], a.w * al);
    }
}

__global__ void l1_finish(float* __restrict__ C, const float* __restrict__ bias) {
    int i = blockIdx.x * blockDim.x + threadIdx.x;
    if (i < N_NODES * D1) {
        float v = C[i] + bias[i & (D1 - 1)];
        C[i] = v > 0.f ? v : expm1f(v);
    }
}

__global__ __launch_bounds__(256) void l2_edge_e(const int* __restrict__ srcA, const int* __restrict__ dstA,
                                                 const float* __restrict__ xl, const float* __restrict__ xr,
                                                 const float* __restrict__ att,
                                                 float* __restrict__ e2, float* __restrict__ emax) {
    __shared__ float att_s[D2];
    if (threadIdx.x < D2) att_s[threadIdx.x] = att[threadIdx.x];
    __syncthreads();
    int eid = blockIdx.x * 256 + threadIdx.x;
    if (eid >= ET) return;
    int s = srcA[eid], d = dstA[eid];
    const float4* ps = (const float4*)(xl + (size_t)s * D2);
    const float4* pd = (const float4*)(xr + (size_t)d * D2);
    float e = 0.f;
#pragma unroll
    for (int q = 0; q < D2 / 4; q++) {
        float4 a = ps[q], b = pd[q];
        float m;
        m = a.x + b.x; m = m > 0.f ? m : NEG * m; e += m * att_s[4 * q + 0];
        m = a.y + b.y; m = m > 0.f ? m : NEG * m; e += m * att_s[4 * q + 1];
        m = a.z + b.z; m = m > 0.f ? m : NEG * m; e += m * att_s[4 * q + 2];
        m = a.w + b.w; m = m > 0.f ? m : NEG * m; e += m * att_s[4 * q + 3];
    }
    e2[eid] = e;
    atomicMaxF(&emax[d], e);
}

__global__ __launch_bounds__(256) void l2_edge_exp(const int* __restrict__ dstA,
                                                   float* __restrict__ e2,
                                                   const float* __restrict__ emax, float* __restrict__ den) {
    int eid = blockIdx.x * 256 + threadIdx.x;
    if (eid >= ET) return;
    int d = dstA[eid];
    float ee = expf(e2[eid] - emax[d]);
    e2[eid] = ee;
    atomicAdd(&den[d], ee);
}

__global__ __launch_bounds__(256) void l2_scatter(const int* __restrict__ srcA, const int* __restrict__ dstA,
                                                  const float* __restrict__ e2, const float* __restrict__ den,
                                                  const float* __restrict__ xl, float* __restrict__ out) {
    int eid = blockIdx.x * 256 + threadIdx.x;
    if (eid >= ET) return;
    int s = srcA[eid], d = dstA[eid];
    float alpha = e2[eid] / (den[d] + EPSF);
    const float4* ps = (const float4*)(xl + (size_t)s * D2);
    float* od = out + (size_t)d * D2;
#pragma unroll
    for (int q = 0; q < D2 / 4; q++) {
        float4 a = ps[q];
        atomicAdd(&od[4 * q + 0], a.x * alpha);
        atomicAdd(&od[4 * q + 1], a.y * alpha);
        atomicAdd(&od[4 * q + 2], a.z * alpha);
        atomicAdd(&od[4 * q + 3], a.w * alpha);
    }
}

// out layout (float): h [0,3.2M) ; log_softmax [3.2M,6.4M) ; predictions [6.4M,6.45M)
__global__ __launch_bounds__(64) void final_k(const float* __restrict__ h2, const float* __restrict__ bias,
                                              float* __restrict__ out) {
    int n = blockIdx.x;
    int c = threadIdx.x;  // 64 lanes = 1 wave
    float v = h2[(size_t)n * D2 + c] + bias[c];
    out[(size_t)n * D2 + c] = v;
    float mx = v;
#pragma unroll
    for (int off = 32; off > 0; off >>= 1) mx = fmaxf(mx, __shfl_xor(mx, off));
    float sum = expf(v - mx);
#pragma unroll
    for (int off = 32; off > 0; off >>= 1) sum += __shfl_xor(sum, off);
    float ls = v - mx - logf(sum);
    out[(size_t)N_NODES * D2 + (size_t)n * D2 + c] = ls;
    float bv = v; int bi = c;
#pragma unroll
    for (int off = 32; off > 0; off >>= 1) {
        float ov = __shfl_xor(bv, off);
        int   oi = __shfl_xor(bi, off);
        if (ov > bv || (ov == bv && oi < bi)) { bv = ov; bi = oi; }
    }
    if (c == 0) out[(size_t)2 * N_NODES * D2 + n] = (float)bi;
}

extern "C" void kernel_launch(void* const* d_in, const int* in_sizes, int n_in,
                              void* d_out, int out_size, void* d_ws, size_t ws_size,
                              hipStream_t stream) {
    const void* x     = d_in[0];
    const int*  ei    = (const int*)d_in[1];

    float* ws = (float*)d_ws;
    float* xl1   = ws + O_XL1;
    float* xr1   = ws + O_XR1;
    float* xf    = ws + O_XF;      // x in f32; becomes Cacc after gemm1
    float* Cacc  = ws + O_XF;
    float* e1    = ws + O_E1;
    float* emax1 = ws + O_EMAX1;
    float* den1  = ws + O_DEN1;
    float* Wf    = ws + O_WF;
    int*   srcA  = (int*)(ws + O_SRC);
    int*   dstA  = (int*)(ws + O_DST);
    int*   flags = (int*)(ws + O_FLAGS);

    // layer-2 aliases (regions free by then)
    float* xl2   = xl1;
    float* xr2   = xl1 + 3200000;
    float* h2    = xr1;
    float* e2    = e1;
    float* emax2 = emax1;
    float* den2  = den1;

    const int EB = (ET + 255) / 256;

    // ---- dtype detection + canonicalization ----
    detect_k<<<1, 64, 0, stream>>>((const unsigned short*)x, ei, flags);
    cvt_edges<<<EB, 256, 0, stream>>>(ei, flags, srcA, dstA);
    cvt_arr<<<(6400000 + 255) / 256, 256, 0, stream>>>(x, xf, 6400000, flags);
    cvt_arr<<<64, 256, 0, stream>>>(d_in[2],  Wf + W_WL1,  16384, flags);
    cvt_arr<<<1, 256, 0, stream>>>(d_in[3],   Wf + W_BL1,  128,   flags);
    cvt_arr<<<64, 256, 0, stream>>>(d_in[4],  Wf + W_WR1,  16384, flags);
    cvt_arr<<<1, 256, 0, stream>>>(d_in[5],   Wf + W_BR1,  128,   flags);
    cvt_arr<<<1, 256, 0, stream>>>(d_in[6],   Wf + W_ATT1, 128,   flags);
    cvt_arr<<<1, 256, 0, stream>>>(d_in[7],   Wf + W_BIAS1,128,   flags);
    cvt_arr<<<32, 256, 0, stream>>>(d_in[8],  Wf + W_WL2,  8192,  flags);
    cvt_arr<<<1, 256, 0, stream>>>(d_in[9],   Wf + W_BL2,  64,    flags);
    cvt_arr<<<32, 256, 0, stream>>>(d_in[10], Wf + W_WR2,  8192,  flags);
    cvt_arr<<<1, 256, 0, stream>>>(d_in[11],  Wf + W_BR2,  64,    flags);
    cvt_arr<<<1, 256, 0, stream>>>(d_in[12],  Wf + W_ATT2, 64,    flags);
    cvt_arr<<<1, 256, 0, stream>>>(d_in[13],  Wf + W_BIAS2,64,    flags);

    // ---- layer 1 ----
    gemm1_k<<<N_NODES, 256, 0, stream>>>(xf, Wf, xl1, xr1);
    fill_k<<<(6400000 + 255) / 256, 256, 0, stream>>>(Cacc, 6400000, 0.f);
    fill_k<<<(400000 + 255) / 256, 256, 0, stream>>>(emax1, 400000, -1e30f);
    fill_k<<<(400000 + 255) / 256, 256, 0, stream>>>(den1, 400000, 0.f);
    l1_edge_e<<<EB, 256, 0, stream>>>(srcA, dstA, xl1, xr1, Wf + W_ATT1, e1, emax1);
    l1_edge_exp<<<EB, 256, 0, stream>>>(dstA, e1, emax1, den1);
    l1_scatter<<<EB, 256, 0, stream>>>(srcA, dstA, e1, den1, xl1, Cacc);
    l1_finish<<<(N_NODES * D1 + 255) / 256, 256, 0, stream>>>(Cacc, Wf + W_BIAS1);

    // ---- layer 2 ----
    gemm2_k<<<N_NODES, 128, 0, stream>>>(Cacc, Wf, xl2, xr2);
    fill_k<<<(3200000 + 255) / 256, 256, 0, stream>>>(h2, 3200000, 0.f);
    fill_k<<<(50000 + 255) / 256, 256, 0, stream>>>(emax2, 50000, -1e30f);
    fill_k<<<(50000 + 255) / 256, 256, 0, stream>>>(den2, 50000, 0.f);
    l2_edge_e<<<EB, 256, 0, stream>>>(srcA, dstA, xl2, xr2, Wf + W_ATT2, e2, emax2);
    l2_edge_exp<<<EB, 256, 0, stream>>>(dstA, e2, emax2, den2);
    l2_scatter<<<EB, 256, 0, stream>>>(srcA, dstA, e2, den2, xl2, h2);

    final_k<<<N_NODES, 64, 0, stream>>>(h2, Wf + W_BIAS2, (float*)d_out);
}

// Round 3
// 832.615 us; speedup vs baseline: 13.0293x; 13.0293x over previous
//
#include <hip/hip_runtime.h>
#include <hip/hip_bf16.h>

#define N_NODES 50000
#define N_EDGES 800000
#define ET (N_EDGES + N_NODES)   // self-loops appended at the end
#define D1 128                   // heads1*ch1 = 8*16
#define H1 8
#define D2 64
#define NEG 0.2f
#define EPSF 1e-16f

// ---- ws layout (float offsets) ----
#define O_XL1    0          // 6,400,000
#define O_XR1    6400000    // 6,400,000
#define O_XF     12800000   // 6,400,000  (x as f32; reused as h after gemm1)
#define O_WF     19200000   // 50,000 (converted params)
#define O_SRC    19250000   // 850,000 ints
#define O_DST    20100000   // 850,000 ints
#define O_DEG    20950000   // 50,000 ints
#define O_ROWPTR 21000000   // 50,001 ints
#define O_CURSOR 21050001   // 50,000 ints
#define O_CSR    21100001   // 850,000 ints
#define O_FLAGS  21950001   // 2 ints
// total ~21.95M floats = 87.8 MB

// ---- Wf internal offsets ----
#define W_WL1   0
#define W_BL1   16384
#define W_WR1   16512
#define W_BR1   32896
#define W_ATT1  33024
#define W_BIAS1 33152
#define W_WL2   33280
#define W_BL2   41472
#define W_WR2   41536
#define W_BR2   49728
#define W_ATT2  49792
#define W_BIAS2 49856

__global__ void fill_k(float* p, int n, float v) {
    int i = blockIdx.x * blockDim.x + threadIdx.x;
    if (i < n) p[i] = v;
}

// flags[0]: 1 if float data is bf16-packed, 0 if f32.
// flags[1]: 1 if edge_index is int64 (int32-view odd words all zero), 0 if int32.
__global__ __launch_bounds__(64) void detect_k(const unsigned short* x16, const int* ei32, int* flags) {
    int lane = threadIdx.x;
    int hits = 0;
    for (int j = lane; j < 32768; j += 64) {       // low half-words of first 32768 floats
        unsigned short u = x16[2 * j];
        if (((u >> 7) & 0xFF) == 0xFF) hits++;     // exp all-ones: impossible for sane bf16 data
    }
#pragma unroll
    for (int off = 32; off > 0; off >>= 1) hits += __shfl_xor(hits, off);
    int nz = 0;
    if (lane < 32) nz = ei32[2 * lane + 1];        // odd words zero <=> int64 indices
#pragma unroll
    for (int off = 32; off > 0; off >>= 1) nz |= __shfl_xor(nz, off);
    if (lane == 0) { flags[0] = hits ? 0 : 1; flags[1] = nz ? 0 : 1; }
}

__global__ void cvt_arr(const void* src, float* dst, int n, const int* flags) {
    int i = blockIdx.x * 256 + threadIdx.x;
    if (i >= n) return;
    if (flags[0]) {
        unsigned short u = ((const unsigned short*)src)[i];
        dst[i] = __uint_as_float((unsigned)u << 16);
    } else {
        dst[i] = ((const float*)src)[i];
    }
}

// canonicalize edges (+self-loops) and histogram dst degrees
__global__ void cvt_edges(const int* ei, const int* flags, int* srcA, int* dstA, int* deg) {
    int e = blockIdx.x * 256 + threadIdx.x;
    if (e >= ET) return;
    int s, d;
    if (e < N_EDGES) {
        if (flags[1]) { s = ei[2 * e]; d = ei[2 * (N_EDGES + e)]; }
        else          { s = ei[e];     d = ei[N_EDGES + e]; }
    } else {
        s = d = e - N_EDGES;
    }
    srcA[e] = s; dstA[e] = d;
    atomicAdd(&deg[d], 1);
}

// exclusive scan of deg -> rowptr[0..N], cursor = rowptr copy. One block of 1024.
#define SCAN_T 1024
#define CHUNK 49   // 1024*49 = 50176 >= 50000
__global__ __launch_bounds__(SCAN_T) void scan_k(const int* __restrict__ deg,
                                                 int* __restrict__ rowptr, int* __restrict__ cursor) {
    __shared__ int part[SCAN_T];
    int t = threadIdx.x;
    int base = t * CHUNK;
    int sum = 0;
    for (int j = 0; j < CHUNK; j++) { int i = base + j; if (i < N_NODES) sum += deg[i]; }
    part[t] = sum;
    __syncthreads();
    for (int off = 1; off < SCAN_T; off <<= 1) {
        int v = (t >= off) ? part[t - off] : 0;
        __syncthreads();
        part[t] += v;
        __syncthreads();
    }
    int run = (t == 0) ? 0 : part[t - 1];
    for (int j = 0; j < CHUNK; j++) {
        int i = base + j;
        if (i < N_NODES) { rowptr[i] = run; cursor[i] = run; run += deg[i]; }
    }
    if (t == SCAN_T - 1) rowptr[N_NODES] = run;
}

__global__ void csr_scatter(const int* __restrict__ srcA, const int* __restrict__ dstA,
                            int* __restrict__ cursor, int* __restrict__ csr_src) {
    int e = blockIdx.x * 256 + threadIdx.x;
    if (e >= ET) return;
    int d = dstA[e];
    int idx = atomicAdd(&cursor[d], 1);
    csr_src[idx] = srcA[e];
}

// xl = x@Wl + bl ; xr = x@Wr + br (per-node block, 256 threads: lower half xl, upper half xr)
__global__ __launch_bounds__(256) void gemm1_k(const float* __restrict__ x, const float* __restrict__ Wf,
                                               float* __restrict__ xl, float* __restrict__ xr) {
    int n = blockIdx.x;
    __shared__ float xs[D1];
    int t = threadIdx.x;
    if (t < D1) xs[t] = x[(size_t)n * D1 + t];
    __syncthreads();
    int col = t & (D1 - 1);
    const float* W = Wf + ((t < D1) ? W_WL1 : W_WR1);
    const float* b = Wf + ((t < D1) ? W_BL1 : W_BR1);
    float acc = 0.f;
#pragma unroll
    for (int k = 0; k < D1; k++) acc += xs[k] * W[k * D1 + col];
    acc += b[col];
    ((t < D1) ? xl : xr)[(size_t)n * D1 + col] = acc;
}

__global__ __launch_bounds__(128) void gemm2_k(const float* __restrict__ h, const float* __restrict__ Wf,
                                               float* __restrict__ xl2, float* __restrict__ xr2) {
    int n = blockIdx.x;
    __shared__ float hs[D1];
    int t = threadIdx.x;
    hs[t] = h[(size_t)n * D1 + t];
    __syncthreads();
    int col = t & (D2 - 1);
    const float* W = Wf + ((t < D2) ? W_WL2 : W_WR2);
    const float* b = Wf + ((t < D2) ? W_BL2 : W_BR2);
    float acc = 0.f;
#pragma unroll
    for (int k = 0; k < D1; k++) acc += hs[k] * W[k * D2 + col];
    acc += b[col];
    ((t < D2) ? xl2 : xr2)[(size_t)n * D2 + col] = acc;
}

// fused layer-1 aggregation: per-node online softmax over incoming edges + bias1 + ELU -> h
// block = 128 threads = one node; thread t = channel t, head = t>>4.
__global__ __launch_bounds__(128) void l1_agg(const int* __restrict__ rowptr, const int* __restrict__ csr_src,
                                              const float* __restrict__ xl, const float* __restrict__ xr,
                                              const float* __restrict__ Wf, float* __restrict__ hout) {
    int n = blockIdx.x;
    int t = threadIdx.x;
    float xr_v  = xr[(size_t)n * D1 + t];
    float att_v = Wf[W_ATT1 + t];
    int i0 = rowptr[n], i1 = rowptr[n + 1];
    float m = -1e30f, l = 0.f, acc = 0.f;
    for (int i = i0; i < i1; i++) {
        int s = csr_src[i];                       // block-uniform -> broadcast
        float xlv = xl[(size_t)s * D1 + t];       // coalesced 512B gather
        float mm = xlv + xr_v;
        mm = mm > 0.f ? mm : NEG * mm;
        float p = mm * att_v;
#pragma unroll
        for (int off = 1; off < 16; off <<= 1) p += __shfl_xor(p, off);  // per-head e
        float mn = fmaxf(m, p);
        float sc = __expf(m - mn);
        float w  = __expf(p - mn);
        l   = l * sc + w;
        acc = acc * sc + w * xlv;
        m = mn;
    }
    float v = acc / (l + EPSF) + Wf[W_BIAS1 + t];
    hout[(size_t)n * D1 + t] = v > 0.f ? v : expm1f(v);
}

// fused layer-2 aggregation + bias2 + log_softmax + argmax.
// block = 64 threads = one wave = one node; thread c = class c.
// out layout (float): h [0,3.2M) ; log_softmax [3.2M,6.4M) ; predictions [6.4M,6.45M)
__global__ __launch_bounds__(64) void l2_agg(const int* __restrict__ rowptr, const int* __restrict__ csr_src,
                                             const float* __restrict__ xl, const float* __restrict__ xr,
                                             const float* __restrict__ Wf, float* __restrict__ out) {
    int n = blockIdx.x;
    int c = threadIdx.x;
    float xr_v  = xr[(size_t)n * D2 + c];
    float att_v = Wf[W_ATT2 + c];
    int i0 = rowptr[n], i1 = rowptr[n + 1];
    float m = -1e30f, l = 0.f, acc = 0.f;
    for (int i = i0; i < i1; i++) {
        int s = csr_src[i];
        float xlv = xl[(size_t)s * D2 + c];
        float mm = xlv + xr_v;
        mm = mm > 0.f ? mm : NEG * mm;
        float p = mm * att_v;
#pragma unroll
        for (int off = 1; off < 64; off <<= 1) p += __shfl_xor(p, off);  // single-head e
        float mn = fmaxf(m, p);
        float sc = __expf(m - mn);
        float w  = __expf(p - mn);
        l   = l * sc + w;
        acc = acc * sc + w * xlv;
        m = mn;
    }
    float v = acc / (l + EPSF) + Wf[W_BIAS2 + c];
    out[(size_t)n * D2 + c] = v;
    // log-softmax
    float mx = v;
#pragma unroll
    for (int off = 32; off > 0; off >>= 1) mx = fmaxf(mx, __shfl_xor(mx, off));
    float sum = expf(v - mx);
#pragma unroll
    for (int off = 32; off > 0; off >>= 1) sum += __shfl_xor(sum, off);
    out[(size_t)N_NODES * D2 + (size_t)n * D2 + c] = v - mx - logf(sum);
    // argmax, first occurrence on ties
    float bv = v; int bi = c;
#pragma unroll
    for (int off = 32; off > 0; off >>= 1) {
        float ov = __shfl_xor(bv, off);
        int   oi = __shfl_xor(bi, off);
        if (ov > bv || (ov == bv && oi < bi)) { bv = ov; bi = oi; }
    }
    if (c == 0) out[(size_t)2 * N_NODES * D2 + n] = (float)bi;
}

extern "C" void kernel_launch(void* const* d_in, const int* in_sizes, int n_in,
                              void* d_out, int out_size, void* d_ws, size_t ws_size,
                              hipStream_t stream) {
    const void* x  = d_in[0];
    const int*  ei = (const int*)d_in[1];

    float* ws = (float*)d_ws;
    float* xl1    = ws + O_XL1;
    float* xr1    = ws + O_XR1;
    float* xf     = ws + O_XF;          // x f32; becomes h after l1_agg
    float* hbuf   = ws + O_XF;
    float* Wf     = ws + O_WF;
    int*   srcA   = (int*)(ws + O_SRC);
    int*   dstA   = (int*)(ws + O_DST);
    int*   deg    = (int*)(ws + O_DEG);
    int*   rowptr = (int*)(ws + O_ROWPTR);
    int*   cursor = (int*)(ws + O_CURSOR);
    int*   csr    = (int*)(ws + O_CSR);
    int*   flags  = (int*)(ws + O_FLAGS);

    // layer-2 aliases (xl1/xr1 regions free after l1_agg)
    float* xl2 = xl1;
    float* xr2 = xl1 + 3200000;

    const int EB = (ET + 255) / 256;

    // ---- dtype detection + canonicalization + CSR build ----
    detect_k<<<1, 64, 0, stream>>>((const unsigned short*)x, ei, flags);
    fill_k<<<(N_NODES + 255) / 256, 256, 0, stream>>>((float*)deg, N_NODES, 0.f);  // int 0
    cvt_edges<<<EB, 256, 0, stream>>>(ei, flags, srcA, dstA, deg);
    scan_k<<<1, SCAN_T, 0, stream>>>(deg, rowptr, cursor);
    csr_scatter<<<EB, 256, 0, stream>>>(srcA, dstA, cursor, csr);

    cvt_arr<<<(6400000 + 255) / 256, 256, 0, stream>>>(x, xf, 6400000, flags);
    cvt_arr<<<64, 256, 0, stream>>>(d_in[2],  Wf + W_WL1,  16384, flags);
    cvt_arr<<<1, 256, 0, stream>>>(d_in[3],   Wf + W_BL1,  128,   flags);
    cvt_arr<<<64, 256, 0, stream>>>(d_in[4],  Wf + W_WR1,  16384, flags);
    cvt_arr<<<1, 256, 0, stream>>>(d_in[5],   Wf + W_BR1,  128,   flags);
    cvt_arr<<<1, 256, 0, stream>>>(d_in[6],   Wf + W_ATT1, 128,   flags);
    cvt_arr<<<1, 256, 0, stream>>>(d_in[7],   Wf + W_BIAS1,128,   flags);
    cvt_arr<<<32, 256, 0, stream>>>(d_in[8],  Wf + W_WL2,  8192,  flags);
    cvt_arr<<<1, 256, 0, stream>>>(d_in[9],   Wf + W_BL2,  64,    flags);
    cvt_arr<<<32, 256, 0, stream>>>(d_in[10], Wf + W_WR2,  8192,  flags);
    cvt_arr<<<1, 256, 0, stream>>>(d_in[11],  Wf + W_BR2,  64,    flags);
    cvt_arr<<<1, 256, 0, stream>>>(d_in[12],  Wf + W_ATT2, 64,    flags);
    cvt_arr<<<1, 256, 0, stream>>>(d_in[13],  Wf + W_BIAS2,64,    flags);

    // ---- layer 1 ----
    gemm1_k<<<N_NODES, 256, 0, stream>>>(xf, Wf, xl1, xr1);
    l1_agg<<<N_NODES, 128, 0, stream>>>(rowptr, csr, xl1, xr1, Wf, hbuf);

    // ---- layer 2 ----
    gemm2_k<<<N_NODES, 128, 0, stream>>>(hbuf, Wf, xl2, xr2);
    l2_agg<<<N_NODES, 64, 0, stream>>>(rowptr, csr, xl2, xr2, Wf, (float*)d_out);
}

// Round 6
// 642.576 us; speedup vs baseline: 16.8826x; 1.2957x over previous
//
#include <hip/hip_runtime.h>
#include <hip/hip_bf16.h>

typedef unsigned short u16;
typedef __attribute__((ext_vector_type(8))) short bf8v;   // 8 x bf16 (4 VGPRs)
typedef __attribute__((ext_vector_type(4))) float f4v;    // 4 x f32 acc

#define N_NODES 50000
#define N_EDGES 800000
#define ET (N_EDGES + N_NODES)
#define D1 128
#define H1 8
#define D2 64
#define NEG 0.2f
#define EPSF 1e-16f
#define NTILES 3125          // 50000/16 exactly
#define NTILES_PAD 3128      // padded to block granularity (4 tiles/block)
#define NP (NTILES_PAD * 16) // 50048 rows
#define APLANE 3203072       // NP*128 u16 = 3,203,072 f32 slots per plane

// ---- ws layout (float offsets) ---- total ~25.2M f32 = 100.7 MB
#define O_XL1    0           // 6,400,000 f32
#define O_XR1    6400000     // 6,400,000 f32
#define O_AH     12800000    // A planes shared by A1 (x) then A2 (h): 3 x 3,203,072
#define O_AM     16003072
#define O_AL     19206144
#define O_B1H    22409216    // 16384 f32 slots each (32768 u16)
#define O_B1M    22425600
#define O_B1L    22441984
#define O_B2H    22458368    // 8192 f32 slots each
#define O_B2M    22466560
#define O_B2L    22474752
#define O_WF     22482944    // 1,024 f32
#define O_SRC    22483968    // 850,000 int
#define O_DST    23333968    // 850,000 int
#define O_DEG    24183968    // 50,000 int
#define O_ROWPTR 24233968    // 50,001 int
#define O_CURSOR 24283969    // 50,000 int
#define O_CSR    24333969    // 850,000 int
#define O_FLAGS  25183969    // 2 int

// ---- Wf internal offsets (f32 small params) ----
#define W_BL1   0
#define W_BR1   128
#define W_ATT1  256
#define W_BIAS1 384
#define W_BL2   512
#define W_BR2   576
#define W_ATT2  640
#define W_BIAS2 704

__global__ void fill_k(float* p, int n, float v) {
    int i = blockIdx.x * blockDim.x + threadIdx.x;
    if (i < n) p[i] = v;
}

// flags[0]: 1 if float data is bf16-packed, 0 if f32.
// flags[1]: 1 if edge_index is int64 (int32-view odd words all zero), 0 if int32.
__global__ __launch_bounds__(64) void detect_k(const u16* x16, const int* ei32, int* flags) {
    int lane = threadIdx.x;
    int hits = 0;
    for (int j = lane; j < 32768; j += 64) {
        u16 u = x16[2 * j];
        if (((u >> 7) & 0xFF) == 0xFF) hits++;
    }
#pragma unroll
    for (int off = 32; off > 0; off >>= 1) hits += __shfl_xor(hits, off);
    int nz = 0;
    if (lane < 32) nz = ei32[2 * lane + 1];
#pragma unroll
    for (int off = 32; off > 0; off >>= 1) nz |= __shfl_xor(nz, off);
    if (lane == 0) { flags[0] = hits ? 0 : 1; flags[1] = nz ? 0 : 1; }
}

__device__ __forceinline__ float load_f32(const void* src, int i, int isbf16) {
    if (isbf16) {
        u16 u = ((const u16*)src)[i];
        return __uint_as_float((unsigned)u << 16);
    }
    return ((const float*)src)[i];
}

__device__ __forceinline__ u16 f2b(float v) {
    __hip_bfloat16 h = __float2bfloat16(v);
    return *(u16*)&h;
}
__device__ __forceinline__ float b2f(u16 u) { return __uint_as_float((unsigned)u << 16); }

// 3-way split: v ~ hi + mid + lo with error ~2^-24 |v| (subtractions Sterbenz-exact)
__device__ __forceinline__ void split3(float v, u16& hi, u16& mid, u16& lo) {
    hi = f2b(v);
    float r1 = v - b2f(hi);
    mid = f2b(r1);
    float r2 = r1 - b2f(mid);
    lo = f2b(r2);
}

__global__ void cvt_arr(const void* src, float* dst, int n, const int* flags) {
    int i = blockIdx.x * 256 + threadIdx.x;
    if (i >= n) return;
    dst[i] = load_f32(src, i, flags[0]);
}

// pack x -> A fragment layout: idx = (r>>4)*2048 + (k>>3)*128 + (r&15)*8 + (k&7), 3 planes
__global__ void pack_x(const void* x, u16* AH, u16* AM, u16* AL, const int* flags) {
    int i = blockIdx.x * 256 + threadIdx.x;
    if (i >= NP * D1) return;
    int r = i >> 7, k = i & 127;
    u16 hi = 0, mid = 0, lo = 0;
    if (r < N_NODES) split3(load_f32(x, r * D1 + k, flags[0]), hi, mid, lo);
    int idx = (r >> 4) * 2048 + (k >> 3) * 128 + (r & 15) * 8 + (k & 7);
    AH[idx] = hi; AM[idx] = mid; AL[idx] = lo;
}

// pack [Wl1|Wr1] (each [128][128]) -> B1[((k>>3)*256 + n)*8 + (k&7)], n in [0,256)
__global__ void pack_w1(const void* Wl, const void* Wr, u16* BH, u16* BM, u16* BL, const int* flags) {
    int i = blockIdx.x * 256 + threadIdx.x;
    if (i >= 128 * 256) return;
    int k = i >> 8, n = i & 255;
    float v = (n < 128) ? load_f32(Wl, k * 128 + n, flags[0])
                        : load_f32(Wr, k * 128 + (n - 128), flags[0]);
    u16 hi, mid, lo; split3(v, hi, mid, lo);
    int idx = ((k >> 3) * 256 + n) * 8 + (k & 7);
    BH[idx] = hi; BM[idx] = mid; BL[idx] = lo;
}

// pack [Wl2|Wr2] (each [128][64]) -> B2[((k>>3)*128 + n)*8 + (k&7)], n in [0,128)
__global__ void pack_w2(const void* Wl, const void* Wr, u16* BH, u16* BM, u16* BL, const int* flags) {
    int i = blockIdx.x * 256 + threadIdx.x;
    if (i >= 128 * 128) return;
    int k = i >> 7, n = i & 127;
    float v = (n < 64) ? load_f32(Wl, k * 64 + n, flags[0])
                       : load_f32(Wr, k * 64 + (n - 64), flags[0]);
    u16 hi, mid, lo; split3(v, hi, mid, lo);
    int idx = ((k >> 3) * 128 + n) * 8 + (k & 7);
    BH[idx] = hi; BM[idx] = mid; BL[idx] = lo;
}

// canonicalize edges (+self-loops) and histogram dst degrees
__global__ void cvt_edges(const int* ei, const int* flags, int* srcA, int* dstA, int* deg) {
    int e = blockIdx.x * 256 + threadIdx.x;
    if (e >= ET) return;
    int s, d;
    if (e < N_EDGES) {
        if (flags[1]) { s = ei[2 * e]; d = ei[2 * (N_EDGES + e)]; }
        else          { s = ei[e];     d = ei[N_EDGES + e]; }
    } else {
        s = d = e - N_EDGES;
    }
    srcA[e] = s; dstA[e] = d;
    atomicAdd(&deg[d], 1);
}

#define SCAN_T 1024
#define CHUNK 49
__global__ __launch_bounds__(SCAN_T) void scan_k(const int* __restrict__ deg,
                                                 int* __restrict__ rowptr, int* __restrict__ cursor) {
    __shared__ int part[SCAN_T];
    int t = threadIdx.x;
    int base = t * CHUNK;
    int sum = 0;
    for (int j = 0; j < CHUNK; j++) { int i = base + j; if (i < N_NODES) sum += deg[i]; }
    part[t] = sum;
    __syncthreads();
    for (int off = 1; off < SCAN_T; off <<= 1) {
        int v = (t >= off) ? part[t - off] : 0;
        __syncthreads();
        part[t] += v;
        __syncthreads();
    }
    int run = (t == 0) ? 0 : part[t - 1];
    for (int j = 0; j < CHUNK; j++) {
        int i = base + j;
        if (i < N_NODES) { rowptr[i] = run; cursor[i] = run; run += deg[i]; }
    }
    if (t == SCAN_T - 1) rowptr[N_NODES] = run;
}

__global__ void csr_scatter(const int* __restrict__ srcA, const int* __restrict__ dstA,
                            int* __restrict__ cursor, int* __restrict__ csr_src) {
    int e = blockIdx.x * 256 + threadIdx.x;
    if (e >= ET) return;
    int d = dstA[e];
    int idx = atomicAdd(&cursor[d], 1);
    csr_src[idx] = srcA[e];
}

// 6-term split-precision MFMA accumulate: acc += A*B with ~2^-24 relative error
#define MFMA6(acc, ah, am, al, bh, bm, bl)                                    \
    acc = __builtin_amdgcn_mfma_f32_16x16x32_bf16(ah, bl, acc, 0, 0, 0);      \
    acc = __builtin_amdgcn_mfma_f32_16x16x32_bf16(am, bm, acc, 0, 0, 0);      \
    acc = __builtin_amdgcn_mfma_f32_16x16x32_bf16(al, bh, acc, 0, 0, 0);      \
    acc = __builtin_amdgcn_mfma_f32_16x16x32_bf16(ah, bm, acc, 0, 0, 0);      \
    acc = __builtin_amdgcn_mfma_f32_16x16x32_bf16(am, bh, acc, 0, 0, 0);      \
    acc = __builtin_amdgcn_mfma_f32_16x16x32_bf16(ah, bh, acc, 0, 0, 0);

// MFMA GEMM 1: [NP x 128] @ [128 x 256] -> xl(+bl), xr(+br). 4 waves/block, wave = 16 rows.
__global__ __launch_bounds__(256) void gemm1_mfma(const u16* __restrict__ AH, const u16* __restrict__ AM,
                                                  const u16* __restrict__ AL,
                                                  const u16* __restrict__ BH, const u16* __restrict__ BM,
                                                  const u16* __restrict__ BL,
                                                  const float* __restrict__ Wf,
                                                  float* __restrict__ xl, float* __restrict__ xr) {
    int w = threadIdx.x >> 6, l = threadIdx.x & 63;
    int tile = blockIdx.x * 4 + w;
    int lr = l & 15, lg = l >> 4;
    f4v acc[16];
#pragma unroll
    for (int nt = 0; nt < 16; nt++) acc[nt] = (f4v)(0.f);
    int aoff = tile * 2048 + lg * 128 + lr * 8;
#pragma unroll
    for (int ks = 0; ks < 4; ks++) {
        bf8v ah = *(const bf8v*)(AH + aoff + ks * 512);
        bf8v am = *(const bf8v*)(AM + aoff + ks * 512);
        bf8v al = *(const bf8v*)(AL + aoff + ks * 512);
        int boff = ((ks * 4 + lg) * 256 + lr) * 8;
#pragma unroll
        for (int nt = 0; nt < 16; nt++) {
            bf8v bh = *(const bf8v*)(BH + boff + nt * 128);
            bf8v bm = *(const bf8v*)(BM + boff + nt * 128);
            bf8v bl = *(const bf8v*)(BL + boff + nt * 128);
            MFMA6(acc[nt], ah, am, al, bh, bm, bl)
        }
    }
    int r0 = tile * 16 + lg * 4;
    if (r0 >= N_NODES) return;
#pragma unroll
    for (int nt = 0; nt < 16; nt++) {
        int col = nt * 16 + lr;
        float bias = (col < D1) ? Wf[W_BL1 + col] : Wf[W_BR1 + col - D1];
        float* dst = (col < D1) ? (xl + col) : (xr + col - D1);
#pragma unroll
        for (int j = 0; j < 4; j++) {
            int row = r0 + j;
            dst[(size_t)row * D1] = acc[nt][j] + bias;
        }
    }
}

// MFMA GEMM 2: [NP x 128] @ [128 x 128] -> xl2(+bl2), xr2(+br2).
__global__ __launch_bounds__(256) void gemm2_mfma(const u16* __restrict__ AH, const u16* __restrict__ AM,
                                                  const u16* __restrict__ AL,
                                                  const u16* __restrict__ BH, const u16* __restrict__ BM,
                                                  const u16* __restrict__ BL,
                                                  const float* __restrict__ Wf,
                                                  float* __restrict__ xl2, float* __restrict__ xr2) {
    int w = threadIdx.x >> 6, l = threadIdx.x & 63;
    int tile = blockIdx.x * 4 + w;
    int lr = l & 15, lg = l >> 4;
    f4v acc[8];
#pragma unroll
    for (int nt = 0; nt < 8; nt++) acc[nt] = (f4v)(0.f);
    int aoff = tile * 2048 + lg * 128 + lr * 8;
#pragma unroll
    for (int ks = 0; ks < 4; ks++) {
        bf8v ah = *(const bf8v*)(AH + aoff + ks * 512);
        bf8v am = *(const bf8v*)(AM + aoff + ks * 512);
        bf8v al = *(const bf8v*)(AL + aoff + ks * 512);
        int boff = ((ks * 4 + lg) * 128 + lr) * 8;
#pragma unroll
        for (int nt = 0; nt < 8; nt++) {
            bf8v bh = *(const bf8v*)(BH + boff + nt * 128);
            bf8v bm = *(const bf8v*)(BM + boff + nt * 128);
            bf8v bl = *(const bf8v*)(BL + boff + nt * 128);
            MFMA6(acc[nt], ah, am, al, bh, bm, bl)
        }
    }
    int r0 = tile * 16 + lg * 4;
    if (r0 >= N_NODES) return;
#pragma unroll
    for (int nt = 0; nt < 8; nt++) {
        int col = nt * 16 + lr;
        float bias = (col < D2) ? Wf[W_BL2 + col] : Wf[W_BR2 + col - D2];
        float* dst = (col < D2) ? (xl2 + col) : (xr2 + col - D2);
#pragma unroll
        for (int j = 0; j < 4; j++) {
            int row = r0 + j;
            dst[(size_t)row * D2] = acc[nt][j] + bias;
        }
    }
}

// fused layer-1 aggregation: online softmax + bias1 + ELU -> h packed as 3-plane A2 fragments
__global__ __launch_bounds__(128) void l1_agg(const int* __restrict__ rowptr, const int* __restrict__ csr_src,
                                              const float* __restrict__ xl, const float* __restrict__ xr,
                                              const float* __restrict__ Wf,
                                              u16* __restrict__ A2H, u16* __restrict__ A2M, u16* __restrict__ A2L) {
    int n = blockIdx.x;
    int t = threadIdx.x;
    float xr_v  = xr[(size_t)n * D1 + t];
    float att_v = Wf[W_ATT1 + t];
    int i0 = rowptr[n], i1 = rowptr[n + 1];
    float m = -1e30f, l = 0.f, acc = 0.f;
    for (int i = i0; i < i1; i++) {
        int s = csr_src[i];
        float xlv = xl[(size_t)s * D1 + t];
        float mm = xlv + xr_v;
        mm = mm > 0.f ? mm : NEG * mm;
        float p = mm * att_v;
#pragma unroll
        for (int off = 1; off < 16; off <<= 1) p += __shfl_xor(p, off);
        float mn = fmaxf(m, p);
        float sc = __expf(m - mn);
        float w  = __expf(p - mn);
        l   = l * sc + w;
        acc = acc * sc + w * xlv;
        m = mn;
    }
    float v = acc / (l + EPSF) + Wf[W_BIAS1 + t];
    v = v > 0.f ? v : expm1f(v);
    u16 hi, mid, lo; split3(v, hi, mid, lo);
    int idx = (n >> 4) * 2048 + (t >> 3) * 128 + (n & 15) * 8 + (t & 7);
    A2H[idx] = hi; A2M[idx] = mid; A2L[idx] = lo;
}

// fused layer-2 aggregation + bias2 + log_softmax + argmax.
// out layout (f32): h [0,3.2M) ; log_softmax [3.2M,6.4M) ; predictions [6.4M,6.45M)
__global__ __launch_bounds__(64) void l2_agg(const int* __restrict__ rowptr, const int* __restrict__ csr_src,
                                             const float* __restrict__ xl, const float* __restrict__ xr,
                                             const float* __restrict__ Wf, float* __restrict__ out) {
    int n = blockIdx.x;
    int c = threadIdx.x;
    float xr_v  = xr[(size_t)n * D2 + c];
    float att_v = Wf[W_ATT2 + c];
    int i0 = rowptr[n], i1 = rowptr[n + 1];
    float m = -1e30f, l = 0.f, acc = 0.f;
    for (int i = i0; i < i1; i++) {
        int s = csr_src[i];
        float xlv = xl[(size_t)s * D2 + c];
        float mm = xlv + xr_v;
        mm = mm > 0.f ? mm : NEG * mm;
        float p = mm * att_v;
#pragma unroll
        for (int off = 1; off < 64; off <<= 1) p += __shfl_xor(p, off);
        float mn = fmaxf(m, p);
        float sc = __expf(m - mn);
        float w  = __expf(p - mn);
        l   = l * sc + w;
        acc = acc * sc + w * xlv;
        m = mn;
    }
    float v = acc / (l + EPSF) + Wf[W_BIAS2 + c];
    out[(size_t)n * D2 + c] = v;
    float mx = v;
#pragma unroll
    for (int off = 32; off > 0; off >>= 1) mx = fmaxf(mx, __shfl_xor(mx, off));
    float sum = expf(v - mx);
#pragma unroll
    for (int off = 32; off > 0; off >>= 1) sum += __shfl_xor(sum, off);
    out[(size_t)N_NODES * D2 + (size_t)n * D2 + c] = v - mx - logf(sum);
    float bv = v; int bi = c;
#pragma unroll
    for (int off = 32; off > 0; off >>= 1) {
        float ov = __shfl_xor(bv, off);
        int   oi = __shfl_xor(bi, off);
        if (ov > bv || (ov == bv && oi < bi)) { bv = ov; bi = oi; }
    }
    if (c == 0) out[(size_t)2 * N_NODES * D2 + n] = (float)bi;
}

extern "C" void kernel_launch(void* const* d_in, const int* in_sizes, int n_in,
                              void* d_out, int out_size, void* d_ws, size_t ws_size,
                              hipStream_t stream) {
    const void* x  = d_in[0];
    const int*  ei = (const int*)d_in[1];

    float* ws = (float*)d_ws;
    float* xl1    = ws + O_XL1;
    float* xr1    = ws + O_XR1;
    u16*   AH     = (u16*)(ws + O_AH);   // shared A1 (x) then A2 (h)
    u16*   AM     = (u16*)(ws + O_AM);
    u16*   AL     = (u16*)(ws + O_AL);
    u16*   B1H    = (u16*)(ws + O_B1H);
    u16*   B1M    = (u16*)(ws + O_B1M);
    u16*   B1L    = (u16*)(ws + O_B1L);
    u16*   B2H    = (u16*)(ws + O_B2H);
    u16*   B2M    = (u16*)(ws + O_B2M);
    u16*   B2L    = (u16*)(ws + O_B2L);
    float* Wf     = ws + O_WF;
    int*   srcA   = (int*)(ws + O_SRC);
    int*   dstA   = (int*)(ws + O_DST);
    int*   deg    = (int*)(ws + O_DEG);
    int*   rowptr = (int*)(ws + O_ROWPTR);
    int*   cursor = (int*)(ws + O_CURSOR);
    int*   csr    = (int*)(ws + O_CSR);
    int*   flags  = (int*)(ws + O_FLAGS);

    // layer-2 aliases (xl1/xr1 free after l1_agg)
    float* xl2 = xl1;
    float* xr2 = xl1 + 3200000;

    const int EB = (ET + 255) / 256;

    // ---- detection, CSR build, packing ----
    detect_k<<<1, 64, 0, stream>>>((const u16*)x, ei, flags);
    fill_k<<<(N_NODES + 255) / 256, 256, 0, stream>>>((float*)deg, N_NODES, 0.f);  // int 0
    cvt_edges<<<EB, 256, 0, stream>>>(ei, flags, srcA, dstA, deg);
    scan_k<<<1, SCAN_T, 0, stream>>>(deg, rowptr, cursor);
    csr_scatter<<<EB, 256, 0, stream>>>(srcA, dstA, cursor, csr);

    pack_x<<<(NP * D1 + 255) / 256, 256, 0, stream>>>(x, AH, AM, AL, flags);
    pack_w1<<<128, 256, 0, stream>>>(d_in[2], d_in[4], B1H, B1M, B1L, flags);
    pack_w2<<<64, 256, 0, stream>>>(d_in[8], d_in[10], B2H, B2M, B2L, flags);

    cvt_arr<<<1, 256, 0, stream>>>(d_in[3],  Wf + W_BL1,  128, flags);
    cvt_arr<<<1, 256, 0, stream>>>(d_in[5],  Wf + W_BR1,  128, flags);
    cvt_arr<<<1, 256, 0, stream>>>(d_in[6],  Wf + W_ATT1, 128, flags);
    cvt_arr<<<1, 256, 0, stream>>>(d_in[7],  Wf + W_BIAS1,128, flags);
    cvt_arr<<<1, 256, 0, stream>>>(d_in[9],  Wf + W_BL2,  64,  flags);
    cvt_arr<<<1, 256, 0, stream>>>(d_in[11], Wf + W_BR2,  64,  flags);
    cvt_arr<<<1, 256, 0, stream>>>(d_in[12], Wf + W_ATT2, 64,  flags);
    cvt_arr<<<1, 256, 0, stream>>>(d_in[13], Wf + W_BIAS2,64,  flags);

    // ---- layer 1 ----
    gemm1_mfma<<<NTILES_PAD / 4, 256, 0, stream>>>(AH, AM, AL, B1H, B1M, B1L, Wf, xl1, xr1);
    // l1_agg overwrites the A planes with h fragments (A1 dead after gemm1; pads stay 0)
    l1_agg<<<N_NODES, 128, 0, stream>>>(rowptr, csr, xl1, xr1, Wf, AH, AM, AL);

    // ---- layer 2 ----
    gemm2_mfma<<<NTILES_PAD / 4, 256, 0, stream>>>(AH, AM, AL, B2H, B2M, B2L, Wf, xl2, xr2);
    l2_agg<<<N_NODES, 64, 0, stream>>>(rowptr, csr, xl2, xr2, Wf, (float*)d_out);
}

// Round 7
// 484.664 us; speedup vs baseline: 22.3833x; 1.3258x over previous
//
#include <hip/hip_runtime.h>
#include <hip/hip_bf16.h>

typedef unsigned short u16;
typedef __attribute__((ext_vector_type(8))) short bf8v;   // 8 x bf16 (4 VGPRs)
typedef __attribute__((ext_vector_type(4))) float f4v;    // 4 x f32 acc

#define N_NODES 50000
#define N_EDGES 800000
#define ET (N_EDGES + N_NODES)
#define D1 128
#define D2 64
#define NEG 0.2f
#define EPSF 1e-16f
#define NTILES_PAD 3128
#define NP (NTILES_PAD * 16) // 50048 rows

// ---- ws layout (float offsets) ----
#define O_XL1    0           // 6,400,000 f32
#define O_XR1    6400000     // 6,400,000 f32
#define O_AH     12800000    // A planes shared by A1 (x) then A2 (h): 3 x 3,203,072
#define O_AM     16003072
#define O_AL     19206144
#define O_B1H    22409216    // 16384 f32 slots each
#define O_B1M    22425600
#define O_B1L    22441984
#define O_B2H    22458368    // 8192 f32 slots each
#define O_B2M    22466560
#define O_B2L    22474752
#define O_WF     22482944    // 1,024 f32
#define O_SRC    22483968    // 850,000 int
#define O_DST    23333968    // 850,000 int
#define O_DEG    24183968    // 50,000 int
#define O_ROWPTR 24233968    // 50,001 int
#define O_CURSOR 24283969    // 50,000 int
#define O_CSR    24333969    // 850,000 int
#define O_FLAGS  25183969    // 2 int

// ---- Wf internal offsets ----
#define W_BL1   0
#define W_BR1   128
#define W_ATT1  256
#define W_BIAS1 384
#define W_BL2   512
#define W_BR2   576
#define W_ATT2  640
#define W_BIAS2 704

// prep_k block ranges
#define NB_CSR   3321        // (ET+255)/256
#define NB_PACKX 25024       // NP*128/256
#define NB_PREP  (NB_CSR + NB_PACKX + 128 + 64 + 1)

__device__ __forceinline__ float load_f32(const void* src, int i, int isbf16) {
    if (isbf16) {
        u16 u = ((const u16*)src)[i];
        return __uint_as_float((unsigned)u << 16);
    }
    return ((const float*)src)[i];
}
__device__ __forceinline__ u16 f2b(float v) {
    __hip_bfloat16 h = __float2bfloat16(v);
    return *(u16*)&h;
}
__device__ __forceinline__ float b2f(u16 u) { return __uint_as_float((unsigned)u << 16); }

// 3-way split: v ~ hi + mid + lo, error ~2^-24 |v|
__device__ __forceinline__ void split3(float v, u16& hi, u16& mid, u16& lo) {
    hi = f2b(v);
    float r1 = v - b2f(hi);
    mid = f2b(r1);
    float r2 = r1 - b2f(mid);
    lo = f2b(r2);
}

// ---- fused init: deg=0 fill (blocks 0..195) + dtype detection (block 196) ----
__global__ void init_k(int* deg, const u16* x16, const int* ei32, int* flags) {
    int b = blockIdx.x;
    if (b < 196) {
        int i = b * 256 + threadIdx.x;
        if (i < N_NODES) deg[i] = 0;
        return;
    }
    int lane = threadIdx.x;
    if (lane >= 64) return;
    int hits = 0;
    for (int j = lane; j < 32768; j += 64) {
        u16 u = x16[2 * j];
        if (((u >> 7) & 0xFF) == 0xFF) hits++;
    }
#pragma unroll
    for (int off = 32; off > 0; off >>= 1) hits += __shfl_xor(hits, off);
    int nz = 0;
    if (lane < 32) nz = ei32[2 * lane + 1];
#pragma unroll
    for (int off = 32; off > 0; off >>= 1) nz |= __shfl_xor(nz, off);
    if (lane == 0) { flags[0] = hits ? 0 : 1; flags[1] = nz ? 0 : 1; }
}

// canonicalize edges (+self-loops) and histogram dst degrees
__global__ void cvt_edges(const int* ei, const int* flags, int* srcA, int* dstA, int* deg) {
    int e = blockIdx.x * 256 + threadIdx.x;
    if (e >= ET) return;
    int s, d;
    if (e < N_EDGES) {
        if (flags[1]) { s = ei[2 * e]; d = ei[2 * (N_EDGES + e)]; }
        else          { s = ei[e];     d = ei[N_EDGES + e]; }
    } else {
        s = d = e - N_EDGES;
    }
    srcA[e] = s; dstA[e] = d;
    atomicAdd(&deg[d], 1);
}

#define SCAN_T 1024
#define CHUNK 49
__global__ __launch_bounds__(SCAN_T) void scan_k(const int* __restrict__ deg,
                                                 int* __restrict__ rowptr, int* __restrict__ cursor) {
    __shared__ int part[SCAN_T];
    int t = threadIdx.x;
    int base = t * CHUNK;
    int sum = 0;
    for (int j = 0; j < CHUNK; j++) { int i = base + j; if (i < N_NODES) sum += deg[i]; }
    part[t] = sum;
    __syncthreads();
    for (int off = 1; off < SCAN_T; off <<= 1) {
        int v = (t >= off) ? part[t - off] : 0;
        __syncthreads();
        part[t] += v;
        __syncthreads();
    }
    int run = (t == 0) ? 0 : part[t - 1];
    for (int j = 0; j < CHUNK; j++) {
        int i = base + j;
        if (i < N_NODES) { rowptr[i] = run; cursor[i] = run; run += deg[i]; }
    }
    if (t == SCAN_T - 1) rowptr[N_NODES] = run;
}

// ---- mega prep: csr_scatter | pack_x | pack_w1 | pack_w2 | params ----
__global__ void prep_k(const int* __restrict__ srcA, const int* __restrict__ dstA,
                       int* __restrict__ cursor, int* __restrict__ csr,
                       const void* x, u16* AH, u16* AM, u16* AL,
                       const void* Wl1, const void* Wr1, u16* B1H, u16* B1M, u16* B1L,
                       const void* Wl2, const void* Wr2, u16* B2H, u16* B2M, u16* B2L,
                       const void* bl1, const void* br1, const void* att1, const void* bias1,
                       const void* bl2, const void* br2, const void* att2, const void* bias2,
                       float* Wf, const int* flags) {
    int b = blockIdx.x, t = threadIdx.x;
    int fb = flags[0];
    if (b < NB_CSR) {
        int e = b * 256 + t;
        if (e < ET) {
            int d = dstA[e];
            int idx = atomicAdd(&cursor[d], 1);
            csr[idx] = srcA[e];
        }
        return;
    }
    b -= NB_CSR;
    if (b < NB_PACKX) {
        int i = b * 256 + t;           // i < NP*128 exactly
        int r = i >> 7, k = i & 127;
        u16 hi = 0, mid = 0, lo = 0;
        if (r < N_NODES) split3(load_f32(x, r * D1 + k, fb), hi, mid, lo);
        int idx = (r >> 4) * 2048 + (k >> 3) * 128 + (r & 15) * 8 + (k & 7);
        AH[idx] = hi; AM[idx] = mid; AL[idx] = lo;
        return;
    }
    b -= NB_PACKX;
    if (b < 128) {
        int i = b * 256 + t;           // i < 32768
        int k = i >> 8, n = i & 255;
        float v = (n < 128) ? load_f32(Wl1, k * 128 + n, fb)
                            : load_f32(Wr1, k * 128 + (n - 128), fb);
        u16 hi, mid, lo; split3(v, hi, mid, lo);
        int idx = ((k >> 3) * 256 + n) * 8 + (k & 7);
        B1H[idx] = hi; B1M[idx] = mid; B1L[idx] = lo;
        return;
    }
    b -= 128;
    if (b < 64) {
        int i = b * 256 + t;           // i < 16384
        int k = i >> 7, n = i & 127;
        float v = (n < 64) ? load_f32(Wl2, k * 64 + n, fb)
                           : load_f32(Wr2, k * 64 + (n - 64), fb);
        u16 hi, mid, lo; split3(v, hi, mid, lo);
        int idx = ((k >> 3) * 128 + n) * 8 + (k & 7);
        B2H[idx] = hi; B2M[idx] = mid; B2L[idx] = lo;
        return;
    }
    // params block
    if (t < 128) {
        Wf[W_BL1 + t]   = load_f32(bl1, t, fb);
        Wf[W_BR1 + t]   = load_f32(br1, t, fb);
        Wf[W_ATT1 + t]  = load_f32(att1, t, fb);
        Wf[W_BIAS1 + t] = load_f32(bias1, t, fb);
        if (t < 64) {
            Wf[W_BL2 + t]   = load_f32(bl2, t, fb);
            Wf[W_BR2 + t]   = load_f32(br2, t, fb);
            Wf[W_ATT2 + t]  = load_f32(att2, t, fb);
            Wf[W_BIAS2 + t] = load_f32(bias2, t, fb);
        }
    }
}

// 6-term split-precision MFMA accumulate: acc += A*B with ~2^-24 relative error
#define MFMA6(acc, ah, am, al, bh, bm, bl)                                    \
    acc = __builtin_amdgcn_mfma_f32_16x16x32_bf16(ah, bl, acc, 0, 0, 0);      \
    acc = __builtin_amdgcn_mfma_f32_16x16x32_bf16(am, bm, acc, 0, 0, 0);      \
    acc = __builtin_amdgcn_mfma_f32_16x16x32_bf16(al, bh, acc, 0, 0, 0);      \
    acc = __builtin_amdgcn_mfma_f32_16x16x32_bf16(ah, bm, acc, 0, 0, 0);      \
    acc = __builtin_amdgcn_mfma_f32_16x16x32_bf16(am, bh, acc, 0, 0, 0);      \
    acc = __builtin_amdgcn_mfma_f32_16x16x32_bf16(ah, bh, acc, 0, 0, 0);

__global__ __launch_bounds__(256) void gemm1_mfma(const u16* __restrict__ AH, const u16* __restrict__ AM,
                                                  const u16* __restrict__ AL,
                                                  const u16* __restrict__ BH, const u16* __restrict__ BM,
                                                  const u16* __restrict__ BL,
                                                  const float* __restrict__ Wf,
                                                  float* __restrict__ xl, float* __restrict__ xr) {
    int w = threadIdx.x >> 6, l = threadIdx.x & 63;
    int tile = blockIdx.x * 4 + w;
    int lr = l & 15, lg = l >> 4;
    f4v acc[16];
#pragma unroll
    for (int nt = 0; nt < 16; nt++) acc[nt] = (f4v)(0.f);
    int aoff = tile * 2048 + lg * 128 + lr * 8;
#pragma unroll
    for (int ks = 0; ks < 4; ks++) {
        bf8v ah = *(const bf8v*)(AH + aoff + ks * 512);
        bf8v am = *(const bf8v*)(AM + aoff + ks * 512);
        bf8v al = *(const bf8v*)(AL + aoff + ks * 512);
        int boff = ((ks * 4 + lg) * 256 + lr) * 8;
#pragma unroll
        for (int nt = 0; nt < 16; nt++) {
            bf8v bh = *(const bf8v*)(BH + boff + nt * 128);
            bf8v bm = *(const bf8v*)(BM + boff + nt * 128);
            bf8v bl = *(const bf8v*)(BL + boff + nt * 128);
            MFMA6(acc[nt], ah, am, al, bh, bm, bl)
        }
    }
    int r0 = tile * 16 + lg * 4;
    if (r0 >= N_NODES) return;
#pragma unroll
    for (int nt = 0; nt < 16; nt++) {
        int col = nt * 16 + lr;
        float bias = (col < D1) ? Wf[W_BL1 + col] : Wf[W_BR1 + col - D1];
        float* dst = (col < D1) ? (xl + col) : (xr + col - D1);
#pragma unroll
        for (int j = 0; j < 4; j++) {
            int row = r0 + j;
            dst[(size_t)row * D1] = acc[nt][j] + bias;
        }
    }
}

__global__ __launch_bounds__(256) void gemm2_mfma(const u16* __restrict__ AH, const u16* __restrict__ AM,
                                                  const u16* __restrict__ AL,
                                                  const u16* __restrict__ BH, const u16* __restrict__ BM,
                                                  const u16* __restrict__ BL,
                                                  const float* __restrict__ Wf,
                                                  float* __restrict__ xl2, float* __restrict__ xr2) {
    int w = threadIdx.x >> 6, l = threadIdx.x & 63;
    int tile = blockIdx.x * 4 + w;
    int lr = l & 15, lg = l >> 4;
    f4v acc[8];
#pragma unroll
    for (int nt = 0; nt < 8; nt++) acc[nt] = (f4v)(0.f);
    int aoff = tile * 2048 + lg * 128 + lr * 8;
#pragma unroll
    for (int ks = 0; ks < 4; ks++) {
        bf8v ah = *(const bf8v*)(AH + aoff + ks * 512);
        bf8v am = *(const bf8v*)(AM + aoff + ks * 512);
        bf8v al = *(const bf8v*)(AL + aoff + ks * 512);
        int boff = ((ks * 4 + lg) * 128 + lr) * 8;
#pragma unroll
        for (int nt = 0; nt < 8; nt++) {
            bf8v bh = *(const bf8v*)(BH + boff + nt * 128);
            bf8v bm = *(const bf8v*)(BM + boff + nt * 128);
            bf8v bl = *(const bf8v*)(BL + boff + nt * 128);
            MFMA6(acc[nt], ah, am, al, bh, bm, bl)
        }
    }
    int r0 = tile * 16 + lg * 4;
    if (r0 >= N_NODES) return;
#pragma unroll
    for (int nt = 0; nt < 8; nt++) {
        int col = nt * 16 + lr;
        float bias = (col < D2) ? Wf[W_BL2 + col] : Wf[W_BR2 + col - D2];
        float* dst = (col < D2) ? (xl2 + col) : (xr2 + col - D2);
#pragma unroll
        for (int j = 0; j < 4; j++) {
            int row = r0 + j;
            dst[(size_t)row * D2] = acc[nt][j] + bias;
        }
    }
}

// layer-1 aggregation: 32 lanes/node (float4/lane), no-max softmax (e1 small; clamp safety),
// + bias1 + ELU -> 3-plane A2 fragments. Block 256 = 8 nodes. Grid 6250.
__global__ __launch_bounds__(256) void l1_agg(const int* __restrict__ rowptr, const int* __restrict__ csr,
                                              const float* __restrict__ xl, const float* __restrict__ xr,
                                              const float* __restrict__ Wf,
                                              u16* __restrict__ A2H, u16* __restrict__ A2M, u16* __restrict__ A2L) {
    int n = (blockIdx.x * 256 + threadIdx.x) >> 5;   // node (grid exact: 6250*8 = 50000)
    int q = threadIdx.x & 31;                        // lane group: channels 4q..4q+3, head = q>>2
    const float4* xl4 = (const float4*)xl;
    float4 xr4 = ((const float4*)(xr + (size_t)n * D1))[q];
    float4 at4 = ((const float4*)(Wf + W_ATT1))[q];
    int i0 = rowptr[n], i1 = rowptr[n + 1];
    float l = 0.f;
    float4 acc = {0.f, 0.f, 0.f, 0.f};
    for (int i = i0; i < i1; i++) {
        int s = csr[i];
        float4 a = xl4[(size_t)s * 32 + q];
        float m0 = a.x + xr4.x; m0 = fmaxf(m0, NEG * m0);
        float m1 = a.y + xr4.y; m1 = fmaxf(m1, NEG * m1);
        float m2 = a.z + xr4.z; m2 = fmaxf(m2, NEG * m2);
        float m3 = a.w + xr4.w; m3 = fmaxf(m3, NEG * m3);
        float p = m0 * at4.x + m1 * at4.y + m2 * at4.z + m3 * at4.w;
        p += __shfl_xor(p, 1);
        p += __shfl_xor(p, 2);                       // head-sum over 4 lanes
        p = fminf(p, 60.f);                          // overflow guard (e1 sigma ~3)
        float w = __expf(p);
        l += w;
        acc.x = fmaf(w, a.x, acc.x);
        acc.y = fmaf(w, a.y, acc.y);
        acc.z = fmaf(w, a.z, acc.z);
        acc.w = fmaf(w, a.w, acc.w);
    }
    float rinv = 1.f / l;                            // l > 0 (self-loop)
    float4 bi4 = ((const float4*)(Wf + W_BIAS1))[q];
    float v0 = acc.x * rinv + bi4.x; v0 = v0 > 0.f ? v0 : expm1f(v0);
    float v1 = acc.y * rinv + bi4.y; v1 = v1 > 0.f ? v1 : expm1f(v1);
    float v2 = acc.z * rinv + bi4.z; v2 = v2 > 0.f ? v2 : expm1f(v2);
    float v3 = acc.w * rinv + bi4.w; v3 = v3 > 0.f ? v3 : expm1f(v3);
    // pack: idx = (n>>4)*2048 + (k>>3)*128 + (n&15)*8 + (k&7), k = 4q+j
    int base = (n >> 4) * 2048 + (q >> 1) * 128 + (n & 15) * 8 + (q & 1) * 4;
    ushort4 h4, m4, l4;
    split3(v0, h4.x, m4.x, l4.x);
    split3(v1, h4.y, m4.y, l4.y);
    split3(v2, h4.z, m4.z, l4.z);
    split3(v3, h4.w, m4.w, l4.w);
    *(ushort4*)(A2H + base) = h4;
    *(ushort4*)(A2M + base) = m4;
    *(ushort4*)(A2L + base) = l4;
}

// layer-2 aggregation: 16 lanes/node (float4/lane), online-max softmax (e2 sigma ~16),
// + bias2 + log_softmax + argmax. Block 256 = 16 nodes. Grid 3125.
// out layout (f32): h [0,3.2M) ; log_softmax [3.2M,6.4M) ; predictions [6.4M,6.45M)
__global__ __launch_bounds__(256) void l2_agg(const int* __restrict__ rowptr, const int* __restrict__ csr,
                                              const float* __restrict__ xl, const float* __restrict__ xr,
                                              const float* __restrict__ Wf, float* __restrict__ out) {
    int n = (blockIdx.x * 256 + threadIdx.x) >> 4;   // node (grid exact: 3125*16 = 50000)
    int q = threadIdx.x & 15;                        // channels 4q..4q+3
    const float4* xl4 = (const float4*)xl;
    float4 xr4 = ((const float4*)(xr + (size_t)n * D2))[q];
    float4 at4 = ((const float4*)(Wf + W_ATT2))[q];
    int i0 = rowptr[n], i1 = rowptr[n + 1];
    float m = -1e30f, l = 0.f;
    float4 acc = {0.f, 0.f, 0.f, 0.f};
    for (int i = i0; i < i1; i++) {
        int s = csr[i];
        float4 a = xl4[(size_t)s * 16 + q];
        float m0 = a.x + xr4.x; m0 = fmaxf(m0, NEG * m0);
        float m1 = a.y + xr4.y; m1 = fmaxf(m1, NEG * m1);
        float m2 = a.z + xr4.z; m2 = fmaxf(m2, NEG * m2);
        float m3 = a.w + xr4.w; m3 = fmaxf(m3, NEG * m3);
        float p = m0 * at4.x + m1 * at4.y + m2 * at4.z + m3 * at4.w;
        p += __shfl_xor(p, 1);
        p += __shfl_xor(p, 2);
        p += __shfl_xor(p, 4);
        p += __shfl_xor(p, 8);                       // head-sum over 16 lanes
        float mn = fmaxf(m, p);
        float sc = __expf(m - mn);
        float w  = __expf(p - mn);
        l = l * sc + w;
        acc.x = fmaf(acc.x, sc, w * a.x);
        acc.y = fmaf(acc.y, sc, w * a.y);
        acc.z = fmaf(acc.z, sc, w * a.z);
        acc.w = fmaf(acc.w, sc, w * a.w);
        m = mn;
    }
    float rinv = 1.f / (l + EPSF);
    float4 bi4 = ((const float4*)(Wf + W_BIAS2))[q];
    float v0 = acc.x * rinv + bi4.x;
    float v1 = acc.y * rinv + bi4.y;
    float v2 = acc.z * rinv + bi4.z;
    float v3 = acc.w * rinv + bi4.w;
    float4 hv = {v0, v1, v2, v3};
    ((float4*)(out + (size_t)n * D2))[q] = hv;
    // log-softmax over 64 classes = 16 lanes x 4
    float mx = fmaxf(fmaxf(v0, v1), fmaxf(v2, v3));
#pragma unroll
    for (int off = 1; off < 16; off <<= 1) mx = fmaxf(mx, __shfl_xor(mx, off));
    float sum = expf(v0 - mx) + expf(v1 - mx) + expf(v2 - mx) + expf(v3 - mx);
#pragma unroll
    for (int off = 1; off < 16; off <<= 1) sum += __shfl_xor(sum, off);
    float lse = mx + logf(sum);
    float4 ls = {v0 - lse, v1 - lse, v2 - lse, v3 - lse};
    ((float4*)(out + (size_t)N_NODES * D2 + (size_t)n * D2))[q] = ls;
    // argmax, first occurrence on ties (channels 4q+j are lane-contiguous)
    float bv = v0; int bi = 4 * q;
    if (v1 > bv) { bv = v1; bi = 4 * q + 1; }
    if (v2 > bv) { bv = v2; bi = 4 * q + 2; }
    if (v3 > bv) { bv = v3; bi = 4 * q + 3; }
#pragma unroll
    for (int off = 1; off < 16; off <<= 1) {
        float ov = __shfl_xor(bv, off);
        int   oi = __shfl_xor(bi, off);
        if (ov > bv || (ov == bv && oi < bi)) { bv = ov; bi = oi; }
    }
    if (q == 0) out[(size_t)2 * N_NODES * D2 + n] = (float)bi;
}

extern "C" void kernel_launch(void* const* d_in, const int* in_sizes, int n_in,
                              void* d_out, int out_size, void* d_ws, size_t ws_size,
                              hipStream_t stream) {
    const void* x  = d_in[0];
    const int*  ei = (const int*)d_in[1];

    float* ws = (float*)d_ws;
    float* xl1    = ws + O_XL1;
    float* xr1    = ws + O_XR1;
    u16*   AH     = (u16*)(ws + O_AH);
    u16*   AM     = (u16*)(ws + O_AM);
    u16*   AL     = (u16*)(ws + O_AL);
    u16*   B1H    = (u16*)(ws + O_B1H);
    u16*   B1M    = (u16*)(ws + O_B1M);
    u16*   B1L    = (u16*)(ws + O_B1L);
    u16*   B2H    = (u16*)(ws + O_B2H);
    u16*   B2M    = (u16*)(ws + O_B2M);
    u16*   B2L    = (u16*)(ws + O_B2L);
    float* Wf     = ws + O_WF;
    int*   srcA   = (int*)(ws + O_SRC);
    int*   dstA   = (int*)(ws + O_DST);
    int*   deg    = (int*)(ws + O_DEG);
    int*   rowptr = (int*)(ws + O_ROWPTR);
    int*   cursor = (int*)(ws + O_CURSOR);
    int*   csr    = (int*)(ws + O_CSR);
    int*   flags  = (int*)(ws + O_FLAGS);

    float* xl2 = xl1;
    float* xr2 = xl1 + 3200000;

    init_k<<<197, 256, 0, stream>>>(deg, (const u16*)x, ei, flags);
    cvt_edges<<<NB_CSR, 256, 0, stream>>>(ei, flags, srcA, dstA, deg);
    scan_k<<<1, SCAN_T, 0, stream>>>(deg, rowptr, cursor);
    prep_k<<<NB_PREP, 256, 0, stream>>>(srcA, dstA, cursor, csr,
                                        x, AH, AM, AL,
                                        d_in[2], d_in[4], B1H, B1M, B1L,
                                        d_in[8], d_in[10], B2H, B2M, B2L,
                                        d_in[3], d_in[5], d_in[6], d_in[7],
                                        d_in[9], d_in[11], d_in[12], d_in[13],
                                        Wf, flags);

    gemm1_mfma<<<NTILES_PAD / 4, 256, 0, stream>>>(AH, AM, AL, B1H, B1M, B1L, Wf, xl1, xr1);
    l1_agg<<<6250, 256, 0, stream>>>(rowptr, csr, xl1, xr1, Wf, AH, AM, AL);
    gemm2_mfma<<<NTILES_PAD / 4, 256, 0, stream>>>(AH, AM, AL, B2H, B2M, B2L, Wf, xl2, xr2);
    l2_agg<<<3125, 256, 0, stream>>>(rowptr, csr, xl2, xr2, Wf, (float*)d_out);
}

// Round 8
// 366.273 us; speedup vs baseline: 29.6183x; 1.3232x over previous
//
#include <hip/hip_runtime.h>
#include <hip/hip_bf16.h>

typedef unsigned short u16;
typedef __attribute__((ext_vector_type(8))) short bf8v;   // 8 x bf16 (4 VGPRs)
typedef __attribute__((ext_vector_type(4))) float f4v;    // 4 x f32 acc

#define N_NODES 50000
#define N_EDGES 800000
#define ET (N_EDGES + N_NODES)
#define D1 128
#define D2 64
#define NEG 0.2f
#define EPSF 1e-16f
#define NTILES_PAD 3128
#define NP (NTILES_PAD * 16) // 50048 rows

// ---- ws layout (float offsets) ----
#define O_XL1    0           // 6,400,000 f32
#define O_XR1    6400000     // 6,400,000 f32
#define O_AH     12800000    // A planes shared by A1 (x) then A2 (h): 3 x 3,203,072
#define O_AM     16003072
#define O_AL     19206144
#define O_B1H    22409216    // 16384 f32 slots each
#define O_B1M    22425600
#define O_B1L    22441984
#define O_B2H    22458368    // 8192 f32 slots each
#define O_B2M    22466560
#define O_B2L    22474752
#define O_WF     22482944    // 1,024 f32
#define O_SRC    22483968    // 850,000 int
#define O_DST    23333968    // 850,000 int
#define O_DEG    24183968    // 50,000 int
#define O_ROWPTR 24233968    // 50,001 int
#define O_CURSOR 24283969    // 50,000 int
#define O_CSR    24333969    // 850,000 int
#define O_FLAGS  25183969    // 2 int
#define O_PART   25183971    // 196 int

// ---- Wf internal offsets ----
#define W_BL1   0
#define W_BR1   128
#define W_ATT1  256
#define W_BIAS1 384
#define W_BL2   512
#define W_BR2   576
#define W_ATT2  640
#define W_BIAS2 704

// prep_k block ranges
#define NB_CSR   3321        // (ET+255)/256
#define NB_PACKX 25024       // NP*128/256
#define NB_PREP  (NB_CSR + NB_PACKX + 128 + 64 + 1)
#define NB_SCAN  196         // ceil(50000/256)

__device__ __forceinline__ float load_f32(const void* src, int i, int isbf16) {
    if (isbf16) {
        u16 u = ((const u16*)src)[i];
        return __uint_as_float((unsigned)u << 16);
    }
    return ((const float*)src)[i];
}
__device__ __forceinline__ u16 f2b(float v) {
    __hip_bfloat16 h = __float2bfloat16(v);
    return *(u16*)&h;
}
__device__ __forceinline__ float b2f(u16 u) { return __uint_as_float((unsigned)u << 16); }

// 3-way split: v ~ hi + mid + lo, error ~2^-24 |v|
__device__ __forceinline__ void split3(float v, u16& hi, u16& mid, u16& lo) {
    hi = f2b(v);
    float r1 = v - b2f(hi);
    mid = f2b(r1);
    float r2 = r1 - b2f(mid);
    lo = f2b(r2);
}

// ---- fused init: deg=0 fill (blocks 0..195) + dtype detection (block 196) ----
__global__ void init_k(int* deg, const u16* x16, const int* ei32, int* flags) {
    int b = blockIdx.x;
    if (b < NB_SCAN) {
        int i = b * 256 + threadIdx.x;
        if (i < N_NODES) deg[i] = 0;
        return;
    }
    int lane = threadIdx.x;
    if (lane >= 64) return;
    int hits = 0;
    for (int j = lane; j < 32768; j += 64) {
        u16 u = x16[2 * j];
        if (((u >> 7) & 0xFF) == 0xFF) hits++;
    }
#pragma unroll
    for (int off = 32; off > 0; off >>= 1) hits += __shfl_xor(hits, off);
    int nz = 0;
    if (lane < 32) nz = ei32[2 * lane + 1];
#pragma unroll
    for (int off = 32; off > 0; off >>= 1) nz |= __shfl_xor(nz, off);
    if (lane == 0) { flags[0] = hits ? 0 : 1; flags[1] = nz ? 0 : 1; }
}

// canonicalize edges (+self-loops) and histogram dst degrees
__global__ void cvt_edges(const int* ei, const int* flags, int* srcA, int* dstA, int* deg) {
    int e = blockIdx.x * 256 + threadIdx.x;
    if (e >= ET) return;
    int s, d;
    if (e < N_EDGES) {
        if (flags[1]) { s = ei[2 * e]; d = ei[2 * (N_EDGES + e)]; }
        else          { s = ei[e];     d = ei[N_EDGES + e]; }
    } else {
        s = d = e - N_EDGES;
    }
    srcA[e] = s; dstA[e] = d;
    atomicAdd(&deg[d], 1);
}

// ---- 3-phase parallel exclusive scan of deg -> rowptr/cursor ----
__global__ __launch_bounds__(256) void scanA_k(const int* __restrict__ deg, int* __restrict__ part) {
    __shared__ int s[256];
    int t = threadIdx.x, i = blockIdx.x * 256 + t;
    s[t] = (i < N_NODES) ? deg[i] : 0;
    __syncthreads();
    for (int off = 128; off > 0; off >>= 1) {
        if (t < off) s[t] += s[t + off];
        __syncthreads();
    }
    if (t == 0) part[blockIdx.x] = s[0];
}

__global__ __launch_bounds__(256) void scanB_k(int* __restrict__ part) {
    __shared__ int s[256];
    int t = threadIdx.x;
    s[t] = (t < NB_SCAN) ? part[t] : 0;
    __syncthreads();
    for (int off = 1; off < 256; off <<= 1) {
        int v = (t >= off) ? s[t - off] : 0;
        __syncthreads();
        s[t] += v;
        __syncthreads();
    }
    if (t < NB_SCAN) part[t] = (t == 0) ? 0 : s[t - 1];
}

__global__ __launch_bounds__(256) void scanC_k(const int* __restrict__ deg, const int* __restrict__ part,
                                               int* __restrict__ rowptr, int* __restrict__ cursor) {
    __shared__ int s[256];
    int t = threadIdx.x, i = blockIdx.x * 256 + t;
    int v = (i < N_NODES) ? deg[i] : 0;
    s[t] = v;
    __syncthreads();
    for (int off = 1; off < 256; off <<= 1) {
        int u = (t >= off) ? s[t - off] : 0;
        __syncthreads();
        s[t] += u;
        __syncthreads();
    }
    int excl = part[blockIdx.x] + s[t] - v;
    if (i < N_NODES) { rowptr[i] = excl; cursor[i] = excl; }
    if (i == N_NODES - 1) rowptr[N_NODES] = excl + v;
}

// ---- mega prep: csr_scatter | pack_x | pack_w1 | pack_w2 | params ----
__global__ void prep_k(const int* __restrict__ srcA, const int* __restrict__ dstA,
                       int* __restrict__ cursor, int* __restrict__ csr,
                       const void* x, u16* AH, u16* AM, u16* AL,
                       const void* Wl1, const void* Wr1, u16* B1H, u16* B1M, u16* B1L,
                       const void* Wl2, const void* Wr2, u16* B2H, u16* B2M, u16* B2L,
                       const void* bl1, const void* br1, const void* att1, const void* bias1,
                       const void* bl2, const void* br2, const void* att2, const void* bias2,
                       float* Wf, const int* flags) {
    int b = blockIdx.x, t = threadIdx.x;
    int fb = flags[0];
    if (b < NB_CSR) {
        int e = b * 256 + t;
        if (e < ET) {
            int d = dstA[e];
            int idx = atomicAdd(&cursor[d], 1);
            csr[idx] = srcA[e];
        }
        return;
    }
    b -= NB_CSR;
    if (b < NB_PACKX) {
        int i = b * 256 + t;           // i < NP*128 exactly
        int r = i >> 7, k = i & 127;
        u16 hi = 0, mid = 0, lo = 0;
        if (r < N_NODES) split3(load_f32(x, r * D1 + k, fb), hi, mid, lo);
        int idx = (r >> 4) * 2048 + (k >> 3) * 128 + (r & 15) * 8 + (k & 7);
        AH[idx] = hi; AM[idx] = mid; AL[idx] = lo;
        return;
    }
    b -= NB_PACKX;
    if (b < 128) {
        int i = b * 256 + t;           // i < 32768
        int k = i >> 8, n = i & 255;
        float v = (n < 128) ? load_f32(Wl1, k * 128 + n, fb)
                            : load_f32(Wr1, k * 128 + (n - 128), fb);
        u16 hi, mid, lo; split3(v, hi, mid, lo);
        int idx = ((k >> 3) * 256 + n) * 8 + (k & 7);
        B1H[idx] = hi; B1M[idx] = mid; B1L[idx] = lo;
        return;
    }
    b -= 128;
    if (b < 64) {
        int i = b * 256 + t;           // i < 16384
        int k = i >> 7, n = i & 127;
        float v = (n < 64) ? load_f32(Wl2, k * 64 + n, fb)
                           : load_f32(Wr2, k * 64 + (n - 64), fb);
        u16 hi, mid, lo; split3(v, hi, mid, lo);
        int idx = ((k >> 3) * 128 + n) * 8 + (k & 7);
        B2H[idx] = hi; B2M[idx] = mid; B2L[idx] = lo;
        return;
    }
    // params block
    if (t < 128) {
        Wf[W_BL1 + t]   = load_f32(bl1, t, fb);
        Wf[W_BR1 + t]   = load_f32(br1, t, fb);
        Wf[W_ATT1 + t]  = load_f32(att1, t, fb);
        Wf[W_BIAS1 + t] = load_f32(bias1, t, fb);
        if (t < 64) {
            Wf[W_BL2 + t]   = load_f32(bl2, t, fb);
            Wf[W_BR2 + t]   = load_f32(br2, t, fb);
            Wf[W_ATT2 + t]  = load_f32(att2, t, fb);
            Wf[W_BIAS2 + t] = load_f32(bias2, t, fb);
        }
    }
}

// 6-term split-precision MFMA accumulate: acc += A*B with ~2^-24 relative error
#define MFMA6(acc, ah, am, al, bh, bm, bl)                                    \
    acc = __builtin_amdgcn_mfma_f32_16x16x32_bf16(ah, bl, acc, 0, 0, 0);      \
    acc = __builtin_amdgcn_mfma_f32_16x16x32_bf16(am, bm, acc, 0, 0, 0);      \
    acc = __builtin_amdgcn_mfma_f32_16x16x32_bf16(al, bh, acc, 0, 0, 0);      \
    acc = __builtin_amdgcn_mfma_f32_16x16x32_bf16(ah, bm, acc, 0, 0, 0);      \
    acc = __builtin_amdgcn_mfma_f32_16x16x32_bf16(am, bh, acc, 0, 0, 0);      \
    acc = __builtin_amdgcn_mfma_f32_16x16x32_bf16(ah, bh, acc, 0, 0, 0);

__global__ __launch_bounds__(256) void gemm1_mfma(const u16* __restrict__ AH, const u16* __restrict__ AM,
                                                  const u16* __restrict__ AL,
                                                  const u16* __restrict__ BH, const u16* __restrict__ BM,
                                                  const u16* __restrict__ BL,
                                                  const float* __restrict__ Wf,
                                                  float* __restrict__ xl, float* __restrict__ xr) {
    int w = threadIdx.x >> 6, l = threadIdx.x & 63;
    int tile = blockIdx.x * 4 + w;
    int lr = l & 15, lg = l >> 4;
    f4v acc[16];
#pragma unroll
    for (int nt = 0; nt < 16; nt++) acc[nt] = (f4v)(0.f);
    int aoff = tile * 2048 + lg * 128 + lr * 8;
#pragma unroll
    for (int ks = 0; ks < 4; ks++) {
        bf8v ah = *(const bf8v*)(AH + aoff + ks * 512);
        bf8v am = *(const bf8v*)(AM + aoff + ks * 512);
        bf8v al = *(const bf8v*)(AL + aoff + ks * 512);
        int boff = ((ks * 4 + lg) * 256 + lr) * 8;
#pragma unroll
        for (int nt = 0; nt < 16; nt++) {
            bf8v bh = *(const bf8v*)(BH + boff + nt * 128);
            bf8v bm = *(const bf8v*)(BM + boff + nt * 128);
            bf8v bl = *(const bf8v*)(BL + boff + nt * 128);
            MFMA6(acc[nt], ah, am, al, bh, bm, bl)
        }
    }
    int r0 = tile * 16 + lg * 4;
    if (r0 >= N_NODES) return;
#pragma unroll
    for (int nt = 0; nt < 16; nt++) {
        int col = nt * 16 + lr;
        float bias = (col < D1) ? Wf[W_BL1 + col] : Wf[W_BR1 + col - D1];
        float* dst = (col < D1) ? (xl + col) : (xr + col - D1);
#pragma unroll
        for (int j = 0; j < 4; j++) {
            int row = r0 + j;
            dst[(size_t)row * D1] = acc[nt][j] + bias;
        }
    }
}

__global__ __launch_bounds__(256) void gemm2_mfma(const u16* __restrict__ AH, const u16* __restrict__ AM,
                                                  const u16* __restrict__ AL,
                                                  const u16* __restrict__ BH, const u16* __restrict__ BM,
                                                  const u16* __restrict__ BL,
                                                  const float* __restrict__ Wf,
                                                  float* __restrict__ xl2, float* __restrict__ xr2) {
    int w = threadIdx.x >> 6, l = threadIdx.x & 63;
    int tile = blockIdx.x * 4 + w;
    int lr = l & 15, lg = l >> 4;
    f4v acc[8];
#pragma unroll
    for (int nt = 0; nt < 8; nt++) acc[nt] = (f4v)(0.f);
    int aoff = tile * 2048 + lg * 128 + lr * 8;
#pragma unroll
    for (int ks = 0; ks < 4; ks++) {
        bf8v ah = *(const bf8v*)(AH + aoff + ks * 512);
        bf8v am = *(const bf8v*)(AM + aoff + ks * 512);
        bf8v al = *(const bf8v*)(AL + aoff + ks * 512);
        int boff = ((ks * 4 + lg) * 128 + lr) * 8;
#pragma unroll
        for (int nt = 0; nt < 8; nt++) {
            bf8v bh = *(const bf8v*)(BH + boff + nt * 128);
            bf8v bm = *(const bf8v*)(BM + boff + nt * 128);
            bf8v bl = *(const bf8v*)(BL + boff + nt * 128);
            MFMA6(acc[nt], ah, am, al, bh, bm, bl)
        }
    }
    int r0 = tile * 16 + lg * 4;
    if (r0 >= N_NODES) return;
#pragma unroll
    for (int nt = 0; nt < 8; nt++) {
        int col = nt * 16 + lr;
        float bias = (col < D2) ? Wf[W_BL2 + col] : Wf[W_BR2 + col - D2];
        float* dst = (col < D2) ? (xl2 + col) : (xr2 + col - D2);
#pragma unroll
        for (int j = 0; j < 4; j++) {
            int row = r0 + j;
            dst[(size_t)row * D2] = acc[nt][j] + bias;
        }
    }
}

// layer-1 aggregation: 32 lanes/node (float4/lane), no-max softmax (e1 small; clamp safety),
// + bias1 + ELU -> 3-plane A2 fragments. Block 256 = 8 nodes. Grid 6250.
__global__ __launch_bounds__(256) void l1_agg(const int* __restrict__ rowptr, const int* __restrict__ csr,
                                              const float* __restrict__ xl, const float* __restrict__ xr,
                                              const float* __restrict__ Wf,
                                              u16* __restrict__ A2H, u16* __restrict__ A2M, u16* __restrict__ A2L) {
    int n = (blockIdx.x * 256 + threadIdx.x) >> 5;   // node (grid exact: 6250*8 = 50000)
    int q = threadIdx.x & 31;                        // lane group: channels 4q..4q+3, head = q>>2
    const float4* xl4 = (const float4*)xl;
    float4 xr4 = ((const float4*)(xr + (size_t)n * D1))[q];
    float4 at4 = ((const float4*)(Wf + W_ATT1))[q];
    int i0 = rowptr[n], i1 = rowptr[n + 1];
    float l = 0.f;
    float4 acc = {0.f, 0.f, 0.f, 0.f};
    for (int i = i0; i < i1; i++) {
        int s = csr[i];
        float4 a = xl4[(size_t)s * 32 + q];
        float m0 = a.x + xr4.x; m0 = fmaxf(m0, NEG * m0);
        float m1 = a.y + xr4.y; m1 = fmaxf(m1, NEG * m1);
        float m2 = a.z + xr4.z; m2 = fmaxf(m2, NEG * m2);
        float m3 = a.w + xr4.w; m3 = fmaxf(m3, NEG * m3);
        float p = m0 * at4.x + m1 * at4.y + m2 * at4.z + m3 * at4.w;
        p += __shfl_xor(p, 1);
        p += __shfl_xor(p, 2);                       // head-sum over 4 lanes
        p = fminf(p, 60.f);                          // overflow guard (e1 sigma ~3)
        float w = __expf(p);
        l += w;
        acc.x = fmaf(w, a.x, acc.x);
        acc.y = fmaf(w, a.y, acc.y);
        acc.z = fmaf(w, a.z, acc.z);
        acc.w = fmaf(w, a.w, acc.w);
    }
    float rinv = 1.f / l;                            // l > 0 (self-loop)
    float4 bi4 = ((const float4*)(Wf + W_BIAS1))[q];
    float v0 = acc.x * rinv + bi4.x; v0 = v0 > 0.f ? v0 : expm1f(v0);
    float v1 = acc.y * rinv + bi4.y; v1 = v1 > 0.f ? v1 : expm1f(v1);
    float v2 = acc.z * rinv + bi4.z; v2 = v2 > 0.f ? v2 : expm1f(v2);
    float v3 = acc.w * rinv + bi4.w; v3 = v3 > 0.f ? v3 : expm1f(v3);
    // pack: idx = (n>>4)*2048 + (k>>3)*128 + (n&15)*8 + (k&7), k = 4q+j
    int base = (n >> 4) * 2048 + (q >> 1) * 128 + (n & 15) * 8 + (q & 1) * 4;
    ushort4 h4, m4, l4;
    split3(v0, h4.x, m4.x, l4.x);
    split3(v1, h4.y, m4.y, l4.y);
    split3(v2, h4.z, m4.z, l4.z);
    split3(v3, h4.w, m4.w, l4.w);
    *(ushort4*)(A2H + base) = h4;
    *(ushort4*)(A2M + base) = m4;
    *(ushort4*)(A2L + base) = l4;
}

// layer-2 aggregation: 16 lanes/node (float4/lane), online-max softmax (e2 sigma ~16),
// + bias2 + log_softmax + argmax. Block 256 = 16 nodes. Grid 3125.
// out layout (f32): h [0,3.2M) ; log_softmax [3.2M,6.4M) ; predictions [6.4M,6.45M)
__global__ __launch_bounds__(256) void l2_agg(const int* __restrict__ rowptr, const int* __restrict__ csr,
                                              const float* __restrict__ xl, const float* __restrict__ xr,
                                              const float* __restrict__ Wf, float* __restrict__ out) {
    int n = (blockIdx.x * 256 + threadIdx.x) >> 4;   // node (grid exact: 3125*16 = 50000)
    int q = threadIdx.x & 15;                        // channels 4q..4q+3
    const float4* xl4 = (const float4*)xl;
    float4 xr4 = ((const float4*)(xr + (size_t)n * D2))[q];
    float4 at4 = ((const float4*)(Wf + W_ATT2))[q];
    int i0 = rowptr[n], i1 = rowptr[n + 1];
    float m = -1e30f, l = 0.f;
    float4 acc = {0.f, 0.f, 0.f, 0.f};
    for (int i = i0; i < i1; i++) {
        int s = csr[i];
        float4 a = xl4[(size_t)s * 16 + q];
        float m0 = a.x + xr4.x; m0 = fmaxf(m0, NEG * m0);
        float m1 = a.y + xr4.y; m1 = fmaxf(m1, NEG * m1);
        float m2 = a.z + xr4.z; m2 = fmaxf(m2, NEG * m2);
        float m3 = a.w + xr4.w; m3 = fmaxf(m3, NEG * m3);
        float p = m0 * at4.x + m1 * at4.y + m2 * at4.z + m3 * at4.w;
        p += __shfl_xor(p, 1);
        p += __shfl_xor(p, 2);
        p += __shfl_xor(p, 4);
        p += __shfl_xor(p, 8);                       // head-sum over 16 lanes
        float mn = fmaxf(m, p);
        float sc = __expf(m - mn);
        float w  = __expf(p - mn);
        l = l * sc + w;
        acc.x = fmaf(acc.x, sc, w * a.x);
        acc.y = fmaf(acc.y, sc, w * a.y);
        acc.z = fmaf(acc.z, sc, w * a.z);
        acc.w = fmaf(acc.w, sc, w * a.w);
        m = mn;
    }
    float rinv = 1.f / (l + EPSF);
    float4 bi4 = ((const float4*)(Wf + W_BIAS2))[q];
    float v0 = acc.x * rinv + bi4.x;
    float v1 = acc.y * rinv + bi4.y;
    float v2 = acc.z * rinv + bi4.z;
    float v3 = acc.w * rinv + bi4.w;
    float4 hv = {v0, v1, v2, v3};
    ((float4*)(out + (size_t)n * D2))[q] = hv;
    // log-softmax over 64 classes = 16 lanes x 4
    float mx = fmaxf(fmaxf(v0, v1), fmaxf(v2, v3));
#pragma unroll
    for (int off = 1; off < 16; off <<= 1) mx = fmaxf(mx, __shfl_xor(mx, off));
    float sum = expf(v0 - mx) + expf(v1 - mx) + expf(v2 - mx) + expf(v3 - mx);
#pragma unroll
    for (int off = 1; off < 16; off <<= 1) sum += __shfl_xor(sum, off);
    float lse = mx + logf(sum);
    float4 ls = {v0 - lse, v1 - lse, v2 - lse, v3 - lse};
    ((float4*)(out + (size_t)N_NODES * D2 + (size_t)n * D2))[q] = ls;
    // argmax, first occurrence on ties (channels 4q+j are lane-contiguous)
    float bv = v0; int bi = 4 * q;
    if (v1 > bv) { bv = v1; bi = 4 * q + 1; }
    if (v2 > bv) { bv = v2; bi = 4 * q + 2; }
    if (v3 > bv) { bv = v3; bi = 4 * q + 3; }
#pragma unroll
    for (int off = 1; off < 16; off <<= 1) {
        float ov = __shfl_xor(bv, off);
        int   oi = __shfl_xor(bi, off);
        if (ov > bv || (ov == bv && oi < bi)) { bv = ov; bi = oi; }
    }
    if (q == 0) out[(size_t)2 * N_NODES * D2 + n] = (float)bi;
}

extern "C" void kernel_launch(void* const* d_in, const int* in_sizes, int n_in,
                              void* d_out, int out_size, void* d_ws, size_t ws_size,
                              hipStream_t stream) {
    const void* x  = d_in[0];
    const int*  ei = (const int*)d_in[1];

    float* ws = (float*)d_ws;
    float* xl1    = ws + O_XL1;
    float* xr1    = ws + O_XR1;
    u16*   AH     = (u16*)(ws + O_AH);
    u16*   AM     = (u16*)(ws + O_AM);
    u16*   AL     = (u16*)(ws + O_AL);
    u16*   B1H    = (u16*)(ws + O_B1H);
    u16*   B1M    = (u16*)(ws + O_B1M);
    u16*   B1L    = (u16*)(ws + O_B1L);
    u16*   B2H    = (u16*)(ws + O_B2H);
    u16*   B2M    = (u16*)(ws + O_B2M);
    u16*   B2L    = (u16*)(ws + O_B2L);
    float* Wf     = ws + O_WF;
    int*   srcA   = (int*)(ws + O_SRC);
    int*   dstA   = (int*)(ws + O_DST);
    int*   deg    = (int*)(ws + O_DEG);
    int*   rowptr = (int*)(ws + O_ROWPTR);
    int*   cursor = (int*)(ws + O_CURSOR);
    int*   csr    = (int*)(ws + O_CSR);
    int*   flags  = (int*)(ws + O_FLAGS);
    int*   part   = (int*)(ws + O_PART);

    float* xl2 = xl1;
    float* xr2 = xl1 + 3200000;

    init_k<<<NB_SCAN + 1, 256, 0, stream>>>(deg, (const u16*)x, ei, flags);
    cvt_edges<<<NB_CSR, 256, 0, stream>>>(ei, flags, srcA, dstA, deg);
    scanA_k<<<NB_SCAN, 256, 0, stream>>>(deg, part);
    scanB_k<<<1, 256, 0, stream>>>(part);
    scanC_k<<<NB_SCAN, 256, 0, stream>>>(deg, part, rowptr, cursor);
    prep_k<<<NB_PREP, 256, 0, stream>>>(srcA, dstA, cursor, csr,
                                        x, AH, AM, AL,
                                        d_in[2], d_in[4], B1H, B1M, B1L,
                                        d_in[8], d_in[10], B2H, B2M, B2L,
                                        d_in[3], d_in[5], d_in[6], d_in[7],
                                        d_in[9], d_in[11], d_in[12], d_in[13],
                                        Wf, flags);

    gemm1_mfma<<<NTILES_PAD / 4, 256, 0, stream>>>(AH, AM, AL, B1H, B1M, B1L, Wf, xl1, xr1);
    l1_agg<<<6250, 256, 0, stream>>>(rowptr, csr, xl1, xr1, Wf, AH, AM, AL);
    gemm2_mfma<<<NTILES_PAD / 4, 256, 0, stream>>>(AH, AM, AL, B2H, B2M, B2L, Wf, xl2, xr2);
    l2_agg<<<3125, 256, 0, stream>>>(rowptr, csr, xl2, xr2, Wf, (float*)d_out);
}

// Round 9
// 318.395 us; speedup vs baseline: 34.0720x; 1.1504x over previous
//
#include <hip/hip_runtime.h>
#include <hip/hip_bf16.h>

typedef unsigned short u16;
typedef __attribute__((ext_vector_type(8))) short bf8v;   // 8 x bf16 (4 VGPRs)
typedef __attribute__((ext_vector_type(4))) float f4v;    // 4 x f32 acc

#define N_NODES 50000
#define N_EDGES 800000
#define ET (N_EDGES + N_NODES)
#define D1 128
#define D2 64
#define NEG 0.2f
#define EPSF 1e-16f
#define NTILES_PAD 3128
#define NP (NTILES_PAD * 16) // 50048 rows

// ---- ws layout (float offsets) ----
#define O_XL1    0           // 6,400,000 f32
#define O_XR1    6400000     // 6,400,000 f32
#define O_AH     12800000    // A planes shared by A1 (x) then A2 (h): 3 x 3,203,072
#define O_AM     16003072
#define O_AL     19206144
#define O_B1H    22409216    // 16384 f32 slots each
#define O_B1M    22425600
#define O_B1L    22441984
#define O_B2H    22458368    // 8192 f32 slots each
#define O_B2M    22466560
#define O_B2L    22474752
#define O_WF     22482944    // 1,024 f32
#define O_SRC    22483968    // 850,000 int
#define O_DST    23333968    // 850,000 int
#define O_DEG    24183968    // 50,000 int
#define O_ROWPTR 24233968    // 50,001 int
#define O_CURSOR 24283969    // 50,000 int
#define O_CSR    24333969    // 850,000 int
#define O_FLAGS  25183969    // 2 int
#define O_PART   25183971    // 196 int

// ---- Wf internal offsets ----
#define W_BL1   0
#define W_BR1   128
#define W_ATT1  256
#define W_BIAS1 384
#define W_BL2   512
#define W_BR2   576
#define W_ATT2  640
#define W_BIAS2 704

// prep_k block ranges
#define NB_CSR   3321        // (ET+255)/256
#define NB_PACKX 25024       // NP*128/256
#define NB_PREP  (NB_CSR + NB_PACKX + 128 + 64 + 1)
#define NB_SCAN  196         // ceil(50000/256)

__device__ __forceinline__ float load_f32(const void* src, int i, int isbf16) {
    if (isbf16) {
        u16 u = ((const u16*)src)[i];
        return __uint_as_float((unsigned)u << 16);
    }
    return ((const float*)src)[i];
}
__device__ __forceinline__ u16 f2b(float v) {
    __hip_bfloat16 h = __float2bfloat16(v);
    return *(u16*)&h;
}
__device__ __forceinline__ float b2f(u16 u) { return __uint_as_float((unsigned)u << 16); }

// 3-way split: v ~ hi + mid + lo, error ~2^-24 |v|
__device__ __forceinline__ void split3(float v, u16& hi, u16& mid, u16& lo) {
    hi = f2b(v);
    float r1 = v - b2f(hi);
    mid = f2b(r1);
    float r2 = r1 - b2f(mid);
    lo = f2b(r2);
}

// ---- fused init: deg=0 fill (blocks 0..195) + dtype detection (block 196) ----
__global__ void init_k(int* deg, const u16* x16, const int* ei32, int* flags) {
    int b = blockIdx.x;
    if (b < NB_SCAN) {
        int i = b * 256 + threadIdx.x;
        if (i < N_NODES) deg[i] = 0;
        return;
    }
    int lane = threadIdx.x;
    if (lane >= 64) return;
    int hits = 0;
    for (int j = lane; j < 32768; j += 64) {
        u16 u = x16[2 * j];
        if (((u >> 7) & 0xFF) == 0xFF) hits++;
    }
#pragma unroll
    for (int off = 32; off > 0; off >>= 1) hits += __shfl_xor(hits, off);
    int nz = 0;
    if (lane < 32) nz = ei32[2 * lane + 1];
#pragma unroll
    for (int off = 32; off > 0; off >>= 1) nz |= __shfl_xor(nz, off);
    if (lane == 0) { flags[0] = hits ? 0 : 1; flags[1] = nz ? 0 : 1; }
}

// canonicalize edges (+self-loops) and histogram dst degrees
__global__ void cvt_edges(const int* ei, const int* flags, int* srcA, int* dstA, int* deg) {
    int e = blockIdx.x * 256 + threadIdx.x;
    if (e >= ET) return;
    int s, d;
    if (e < N_EDGES) {
        if (flags[1]) { s = ei[2 * e]; d = ei[2 * (N_EDGES + e)]; }
        else          { s = ei[e];     d = ei[N_EDGES + e]; }
    } else {
        s = d = e - N_EDGES;
    }
    srcA[e] = s; dstA[e] = d;
    atomicAdd(&deg[d], 1);
}

// ---- 3-phase parallel exclusive scan of deg -> rowptr/cursor ----
__global__ __launch_bounds__(256) void scanA_k(const int* __restrict__ deg, int* __restrict__ part) {
    __shared__ int s[256];
    int t = threadIdx.x, i = blockIdx.x * 256 + t;
    s[t] = (i < N_NODES) ? deg[i] : 0;
    __syncthreads();
    for (int off = 128; off > 0; off >>= 1) {
        if (t < off) s[t] += s[t + off];
        __syncthreads();
    }
    if (t == 0) part[blockIdx.x] = s[0];
}

__global__ __launch_bounds__(256) void scanB_k(int* __restrict__ part) {
    __shared__ int s[256];
    int t = threadIdx.x;
    s[t] = (t < NB_SCAN) ? part[t] : 0;
    __syncthreads();
    for (int off = 1; off < 256; off <<= 1) {
        int v = (t >= off) ? s[t - off] : 0;
        __syncthreads();
        s[t] += v;
        __syncthreads();
    }
    if (t < NB_SCAN) part[t] = (t == 0) ? 0 : s[t - 1];
}

__global__ __launch_bounds__(256) void scanC_k(const int* __restrict__ deg, const int* __restrict__ part,
                                               int* __restrict__ rowptr, int* __restrict__ cursor) {
    __shared__ int s[256];
    int t = threadIdx.x, i = blockIdx.x * 256 + t;
    int v = (i < N_NODES) ? deg[i] : 0;
    s[t] = v;
    __syncthreads();
    for (int off = 1; off < 256; off <<= 1) {
        int u = (t >= off) ? s[t - off] : 0;
        __syncthreads();
        s[t] += u;
        __syncthreads();
    }
    int excl = part[blockIdx.x] + s[t] - v;
    if (i < N_NODES) { rowptr[i] = excl; cursor[i] = excl; }
    if (i == N_NODES - 1) rowptr[N_NODES] = excl + v;
}

// ---- mega prep: csr_scatter | pack_x | pack_w1 | pack_w2 | params ----
__global__ void prep_k(const int* __restrict__ srcA, const int* __restrict__ dstA,
                       int* __restrict__ cursor, int* __restrict__ csr,
                       const void* x, u16* AH, u16* AM, u16* AL,
                       const void* Wl1, const void* Wr1, u16* B1H, u16* B1M, u16* B1L,
                       const void* Wl2, const void* Wr2, u16* B2H, u16* B2M, u16* B2L,
                       const void* bl1, const void* br1, const void* att1, const void* bias1,
                       const void* bl2, const void* br2, const void* att2, const void* bias2,
                       float* Wf, const int* flags) {
    int b = blockIdx.x, t = threadIdx.x;
    int fb = flags[0];
    if (b < NB_CSR) {
        int e = b * 256 + t;
        if (e < ET) {
            int d = dstA[e];
            int idx = atomicAdd(&cursor[d], 1);
            csr[idx] = srcA[e];
        }
        return;
    }
    b -= NB_CSR;
    if (b < NB_PACKX) {
        int i = b * 256 + t;           // i < NP*128 exactly
        int r = i >> 7, k = i & 127;
        u16 hi = 0, mid = 0, lo = 0;
        if (r < N_NODES) split3(load_f32(x, r * D1 + k, fb), hi, mid, lo);
        int idx = (r >> 4) * 2048 + (k >> 3) * 128 + (r & 15) * 8 + (k & 7);
        AH[idx] = hi; AM[idx] = mid; AL[idx] = lo;
        return;
    }
    b -= NB_PACKX;
    if (b < 128) {
        int i = b * 256 + t;           // i < 32768
        int k = i >> 8, n = i & 255;
        float v = (n < 128) ? load_f32(Wl1, k * 128 + n, fb)
                            : load_f32(Wr1, k * 128 + (n - 128), fb);
        u16 hi, mid, lo; split3(v, hi, mid, lo);
        int idx = ((k >> 3) * 256 + n) * 8 + (k & 7);
        B1H[idx] = hi; B1M[idx] = mid; B1L[idx] = lo;
        return;
    }
    b -= 128;
    if (b < 64) {
        int i = b * 256 + t;           // i < 16384
        int k = i >> 7, n = i & 127;
        float v = (n < 64) ? load_f32(Wl2, k * 64 + n, fb)
                           : load_f32(Wr2, k * 64 + (n - 64), fb);
        u16 hi, mid, lo; split3(v, hi, mid, lo);
        int idx = ((k >> 3) * 128 + n) * 8 + (k & 7);
        B2H[idx] = hi; B2M[idx] = mid; B2L[idx] = lo;
        return;
    }
    // params block
    if (t < 128) {
        Wf[W_BL1 + t]   = load_f32(bl1, t, fb);
        Wf[W_BR1 + t]   = load_f32(br1, t, fb);
        Wf[W_ATT1 + t]  = load_f32(att1, t, fb);
        Wf[W_BIAS1 + t] = load_f32(bias1, t, fb);
        if (t < 64) {
            Wf[W_BL2 + t]   = load_f32(bl2, t, fb);
            Wf[W_BR2 + t]   = load_f32(br2, t, fb);
            Wf[W_ATT2 + t]  = load_f32(att2, t, fb);
            Wf[W_BIAS2 + t] = load_f32(bias2, t, fb);
        }
    }
}

// 6-term split-precision MFMA accumulate: acc += A*B with ~2^-24 relative error
#define MFMA6(acc, ah, am, al, bh, bm, bl)                                    \
    acc = __builtin_amdgcn_mfma_f32_16x16x32_bf16(ah, bl, acc, 0, 0, 0);      \
    acc = __builtin_amdgcn_mfma_f32_16x16x32_bf16(am, bm, acc, 0, 0, 0);      \
    acc = __builtin_amdgcn_mfma_f32_16x16x32_bf16(al, bh, acc, 0, 0, 0);      \
    acc = __builtin_amdgcn_mfma_f32_16x16x32_bf16(ah, bm, acc, 0, 0, 0);      \
    acc = __builtin_amdgcn_mfma_f32_16x16x32_bf16(am, bh, acc, 0, 0, 0);      \
    acc = __builtin_amdgcn_mfma_f32_16x16x32_bf16(ah, bh, acc, 0, 0, 0);

// MFMA GEMM 1: wave = 16 rows x 64 cols (col chunk = blockIdx.y). Grid (782, 4) x 256 thr.
__global__ __launch_bounds__(256) void gemm1_mfma(const u16* __restrict__ AH, const u16* __restrict__ AM,
                                                  const u16* __restrict__ AL,
                                                  const u16* __restrict__ BH, const u16* __restrict__ BM,
                                                  const u16* __restrict__ BL,
                                                  const float* __restrict__ Wf,
                                                  float* __restrict__ xl, float* __restrict__ xr) {
    int w = threadIdx.x >> 6, l = threadIdx.x & 63;
    int tile = blockIdx.x * 4 + w;
    int cb = blockIdx.y << 6;                 // col base (0,64,128,192)
    int lr = l & 15, lg = l >> 4;
    f4v acc[4];
#pragma unroll
    for (int nt = 0; nt < 4; nt++) acc[nt] = (f4v)(0.f);
    int aoff = tile * 2048 + lg * 128 + lr * 8;
#pragma unroll
    for (int ks = 0; ks < 4; ks++) {
        bf8v ah = *(const bf8v*)(AH + aoff + ks * 512);
        bf8v am = *(const bf8v*)(AM + aoff + ks * 512);
        bf8v al = *(const bf8v*)(AL + aoff + ks * 512);
        int boff = ((ks * 4 + lg) * 256 + cb + lr) * 8;
#pragma unroll
        for (int nt = 0; nt < 4; nt++) {
            bf8v bh = *(const bf8v*)(BH + boff + nt * 128);
            bf8v bm = *(const bf8v*)(BM + boff + nt * 128);
            bf8v bl = *(const bf8v*)(BL + boff + nt * 128);
            MFMA6(acc[nt], ah, am, al, bh, bm, bl)
        }
    }
    int r0 = tile * 16 + lg * 4;
    if (r0 >= N_NODES) return;
#pragma unroll
    for (int nt = 0; nt < 4; nt++) {
        int col = cb + nt * 16 + lr;
        float bias = (col < D1) ? Wf[W_BL1 + col] : Wf[W_BR1 + col - D1];
        float* dst = (col < D1) ? (xl + col) : (xr + col - D1);
#pragma unroll
        for (int j = 0; j < 4; j++) {
            int row = r0 + j;
            dst[(size_t)row * D1] = acc[nt][j] + bias;
        }
    }
}

// MFMA GEMM 2: wave = 16 rows x 64 cols. Grid (782, 2) x 256 thr.
__global__ __launch_bounds__(256) void gemm2_mfma(const u16* __restrict__ AH, const u16* __restrict__ AM,
                                                  const u16* __restrict__ AL,
                                                  const u16* __restrict__ BH, const u16* __restrict__ BM,
                                                  const u16* __restrict__ BL,
                                                  const float* __restrict__ Wf,
                                                  float* __restrict__ xl2, float* __restrict__ xr2) {
    int w = threadIdx.x >> 6, l = threadIdx.x & 63;
    int tile = blockIdx.x * 4 + w;
    int cb = blockIdx.y << 6;                 // col base (0,64)
    int lr = l & 15, lg = l >> 4;
    f4v acc[4];
#pragma unroll
    for (int nt = 0; nt < 4; nt++) acc[nt] = (f4v)(0.f);
    int aoff = tile * 2048 + lg * 128 + lr * 8;
#pragma unroll
    for (int ks = 0; ks < 4; ks++) {
        bf8v ah = *(const bf8v*)(AH + aoff + ks * 512);
        bf8v am = *(const bf8v*)(AM + aoff + ks * 512);
        bf8v al = *(const bf8v*)(AL + aoff + ks * 512);
        int boff = ((ks * 4 + lg) * 128 + cb + lr) * 8;
#pragma unroll
        for (int nt = 0; nt < 4; nt++) {
            bf8v bh = *(const bf8v*)(BH + boff + nt * 128);
            bf8v bm = *(const bf8v*)(BM + boff + nt * 128);
            bf8v bl = *(const bf8v*)(BL + boff + nt * 128);
            MFMA6(acc[nt], ah, am, al, bh, bm, bl)
        }
    }
    int r0 = tile * 16 + lg * 4;
    if (r0 >= N_NODES) return;
#pragma unroll
    for (int nt = 0; nt < 4; nt++) {
        int col = cb + nt * 16 + lr;
        float bias = (col < D2) ? Wf[W_BL2 + col] : Wf[W_BR2 + col - D2];
        float* dst = (col < D2) ? (xl2 + col) : (xr2 + col - D2);
#pragma unroll
        for (int j = 0; j < 4; j++) {
            int row = r0 + j;
            dst[(size_t)row * D2] = acc[nt][j] + bias;
        }
    }
}

// layer-1 aggregation: 32 lanes/node (float4/lane), no-max softmax (e1 small; clamp safety),
// + bias1 + ELU -> 3-plane A2 fragments. Block 256 = 8 nodes. Grid 6250.
__global__ __launch_bounds__(256) void l1_agg(const int* __restrict__ rowptr, const int* __restrict__ csr,
                                              const float* __restrict__ xl, const float* __restrict__ xr,
                                              const float* __restrict__ Wf,
                                              u16* __restrict__ A2H, u16* __restrict__ A2M, u16* __restrict__ A2L) {
    int n = (blockIdx.x * 256 + threadIdx.x) >> 5;   // node (grid exact: 6250*8 = 50000)
    int q = threadIdx.x & 31;                        // lane group: channels 4q..4q+3, head = q>>2
    const float4* xl4 = (const float4*)xl;
    float4 xr4 = ((const float4*)(xr + (size_t)n * D1))[q];
    float4 at4 = ((const float4*)(Wf + W_ATT1))[q];
    int i0 = rowptr[n], i1 = rowptr[n + 1];
    float l = 0.f;
    float4 acc = {0.f, 0.f, 0.f, 0.f};
    for (int i = i0; i < i1; i++) {
        int s = csr[i];
        float4 a = xl4[(size_t)s * 32 + q];
        float m0 = a.x + xr4.x; m0 = fmaxf(m0, NEG * m0);
        float m1 = a.y + xr4.y; m1 = fmaxf(m1, NEG * m1);
        float m2 = a.z + xr4.z; m2 = fmaxf(m2, NEG * m2);
        float m3 = a.w + xr4.w; m3 = fmaxf(m3, NEG * m3);
        float p = m0 * at4.x + m1 * at4.y + m2 * at4.z + m3 * at4.w;
        p += __shfl_xor(p, 1);
        p += __shfl_xor(p, 2);                       // head-sum over 4 lanes
        p = fminf(p, 60.f);                          // overflow guard (e1 sigma ~3)
        float w = __expf(p);
        l += w;
        acc.x = fmaf(w, a.x, acc.x);
        acc.y = fmaf(w, a.y, acc.y);
        acc.z = fmaf(w, a.z, acc.z);
        acc.w = fmaf(w, a.w, acc.w);
    }
    float rinv = 1.f / l;                            // l > 0 (self-loop)
    float4 bi4 = ((const float4*)(Wf + W_BIAS1))[q];
    float v0 = acc.x * rinv + bi4.x; v0 = v0 > 0.f ? v0 : expm1f(v0);
    float v1 = acc.y * rinv + bi4.y; v1 = v1 > 0.f ? v1 : expm1f(v1);
    float v2 = acc.z * rinv + bi4.z; v2 = v2 > 0.f ? v2 : expm1f(v2);
    float v3 = acc.w * rinv + bi4.w; v3 = v3 > 0.f ? v3 : expm1f(v3);
    // pack: idx = (n>>4)*2048 + (k>>3)*128 + (n&15)*8 + (k&7), k = 4q+j
    int base = (n >> 4) * 2048 + (q >> 1) * 128 + (n & 15) * 8 + (q & 1) * 4;
    ushort4 h4, m4, l4;
    split3(v0, h4.x, m4.x, l4.x);
    split3(v1, h4.y, m4.y, l4.y);
    split3(v2, h4.z, m4.z, l4.z);
    split3(v3, h4.w, m4.w, l4.w);
    *(ushort4*)(A2H + base) = h4;
    *(ushort4*)(A2M + base) = m4;
    *(ushort4*)(A2L + base) = l4;
}

// layer-2 aggregation: 16 lanes/node (float4/lane), online-max softmax,
// + bias2 + log_softmax + argmax. Block 256 = 16 nodes. Grid 3125.
// out layout (f32): h [0,3.2M) ; log_softmax [3.2M,6.4M) ; predictions [6.4M,6.45M)
__global__ __launch_bounds__(256) void l2_agg(const int* __restrict__ rowptr, const int* __restrict__ csr,
                                              const float* __restrict__ xl, const float* __restrict__ xr,
                                              const float* __restrict__ Wf, float* __restrict__ out) {
    int n = (blockIdx.x * 256 + threadIdx.x) >> 4;   // node (grid exact: 3125*16 = 50000)
    int q = threadIdx.x & 15;                        // channels 4q..4q+3
    const float4* xl4 = (const float4*)xl;
    float4 xr4 = ((const float4*)(xr + (size_t)n * D2))[q];
    float4 at4 = ((const float4*)(Wf + W_ATT2))[q];
    int i0 = rowptr[n], i1 = rowptr[n + 1];
    float m = -1e30f, l = 0.f;
    float4 acc = {0.f, 0.f, 0.f, 0.f};
    for (int i = i0; i < i1; i++) {
        int s = csr[i];
        float4 a = xl4[(size_t)s * 16 + q];
        float m0 = a.x + xr4.x; m0 = fmaxf(m0, NEG * m0);
        float m1 = a.y + xr4.y; m1 = fmaxf(m1, NEG * m1);
        float m2 = a.z + xr4.z; m2 = fmaxf(m2, NEG * m2);
        float m3 = a.w + xr4.w; m3 = fmaxf(m3, NEG * m3);
        float p = m0 * at4.x + m1 * at4.y + m2 * at4.z + m3 * at4.w;
        p += __shfl_xor(p, 1);
        p += __shfl_xor(p, 2);
        p += __shfl_xor(p, 4);
        p += __shfl_xor(p, 8);                       // head-sum over 16 lanes
        float mn = fmaxf(m, p);
        float sc = __expf(m - mn);
        float w  = __expf(p - mn);
        l = l * sc + w;
        acc.x = fmaf(acc.x, sc, w * a.x);
        acc.y = fmaf(acc.y, sc, w * a.y);
        acc.z = fmaf(acc.z, sc, w * a.z);
        acc.w = fmaf(acc.w, sc, w * a.w);
        m = mn;
    }
    float rinv = 1.f / (l + EPSF);
    float4 bi4 = ((const float4*)(Wf + W_BIAS2))[q];
    float v0 = acc.x * rinv + bi4.x;
    float v1 = acc.y * rinv + bi4.y;
    float v2 = acc.z * rinv + bi4.z;
    float v3 = acc.w * rinv + bi4.w;
    float4 hv = {v0, v1, v2, v3};
    ((float4*)(out + (size_t)n * D2))[q] = hv;
    // log-softmax over 64 classes = 16 lanes x 4
    float mx = fmaxf(fmaxf(v0, v1), fmaxf(v2, v3));
#pragma unroll
    for (int off = 1; off < 16; off <<= 1) mx = fmaxf(mx, __shfl_xor(mx, off));
    float sum = expf(v0 - mx) + expf(v1 - mx) + expf(v2 - mx) + expf(v3 - mx);
#pragma unroll
    for (int off = 1; off < 16; off <<= 1) sum += __shfl_xor(sum, off);
    float lse = mx + logf(sum);
    float4 ls = {v0 - lse, v1 - lse, v2 - lse, v3 - lse};
    ((float4*)(out + (size_t)N_NODES * D2 + (size_t)n * D2))[q] = ls;
    // argmax, first occurrence on ties (channels 4q+j are lane-contiguous)
    float bv = v0; int bi = 4 * q;
    if (v1 > bv) { bv = v1; bi = 4 * q + 1; }
    if (v2 > bv) { bv = v2; bi = 4 * q + 2; }
    if (v3 > bv) { bv = v3; bi = 4 * q + 3; }
#pragma unroll
    for (int off = 1; off < 16; off <<= 1) {
        float ov = __shfl_xor(bv, off);
        int   oi = __shfl_xor(bi, off);
        if (ov > bv || (ov == bv && oi < bi)) { bv = ov; bi = oi; }
    }
    if (q == 0) out[(size_t)2 * N_NODES * D2 + n] = (float)bi;
}

extern "C" void kernel_launch(void* const* d_in, const int* in_sizes, int n_in,
                              void* d_out, int out_size, void* d_ws, size_t ws_size,
                              hipStream_t stream) {
    const void* x  = d_in[0];
    const int*  ei = (const int*)d_in[1];

    float* ws = (float*)d_ws;
    float* xl1    = ws + O_XL1;
    float* xr1    = ws + O_XR1;
    u16*   AH     = (u16*)(ws + O_AH);
    u16*   AM     = (u16*)(ws + O_AM);
    u16*   AL     = (u16*)(ws + O_AL);
    u16*   B1H    = (u16*)(ws + O_B1H);
    u16*   B1M    = (u16*)(ws + O_B1M);
    u16*   B1L    = (u16*)(ws + O_B1L);
    u16*   B2H    = (u16*)(ws + O_B2H);
    u16*   B2M    = (u16*)(ws + O_B2M);
    u16*   B2L    = (u16*)(ws + O_B2L);
    float* Wf     = ws + O_WF;
    int*   srcA   = (int*)(ws + O_SRC);
    int*   dstA   = (int*)(ws + O_DST);
    int*   deg    = (int*)(ws + O_DEG);
    int*   rowptr = (int*)(ws + O_ROWPTR);
    int*   cursor = (int*)(ws + O_CURSOR);
    int*   csr    = (int*)(ws + O_CSR);
    int*   flags  = (int*)(ws + O_FLAGS);
    int*   part   = (int*)(ws + O_PART);

    float* xl2 = xl1;
    float* xr2 = xl1 + 3200000;

    init_k<<<NB_SCAN + 1, 256, 0, stream>>>(deg, (const u16*)x, ei, flags);
    cvt_edges<<<NB_CSR, 256, 0, stream>>>(ei, flags, srcA, dstA, deg);
    scanA_k<<<NB_SCAN, 256, 0, stream>>>(deg, part);
    scanB_k<<<1, 256, 0, stream>>>(part);
    scanC_k<<<NB_SCAN, 256, 0, stream>>>(deg, part, rowptr, cursor);
    prep_k<<<NB_PREP, 256, 0, stream>>>(srcA, dstA, cursor, csr,
                                        x, AH, AM, AL,
                                        d_in[2], d_in[4], B1H, B1M, B1L,
                                        d_in[8], d_in[10], B2H, B2M, B2L,
                                        d_in[3], d_in[5], d_in[6], d_in[7],
                                        d_in[9], d_in[11], d_in[12], d_in[13],
                                        Wf, flags);

    gemm1_mfma<<<dim3(NTILES_PAD / 4, 4), 256, 0, stream>>>(AH, AM, AL, B1H, B1M, B1L, Wf, xl1, xr1);
    l1_agg<<<6250, 256, 0, stream>>>(rowptr, csr, xl1, xr1, Wf, AH, AM, AL);
    gemm2_mfma<<<dim3(NTILES_PAD / 4, 2), 256, 0, stream>>>(AH, AM, AL, B2H, B2M, B2L, Wf, xl2, xr2);
    l2_agg<<<3125, 256, 0, stream>>>(rowptr, csr, xl2, xr2, Wf, (float*)d_out);
}

// Round 10
// 289.077 us; speedup vs baseline: 37.5277x; 1.1014x over previous
//
#include <hip/hip_runtime.h>
#include <hip/hip_bf16.h>

typedef unsigned short u16;
typedef __attribute__((ext_vector_type(8))) short bf8v;   // 8 x bf16 (4 VGPRs)
typedef __attribute__((ext_vector_type(4))) float f4v;    // 4 x f32 acc

#define N_NODES 50000
#define N_EDGES 800000
#define ET (N_EDGES + N_NODES)
#define D1 128
#define D2 64
#define NEG 0.2f
#define EPSF 1e-16f
#define NTILES_PAD 3128
#define NP (NTILES_PAD * 16) // 50048 rows

// ---- ws layout (float offsets) ----
#define O_XL1    0           // 6,400,000 f32
#define O_XR1    6400000     // 6,400,000 f32
#define O_AH     12800000    // A planes shared by A1 (x) then A2 (h): 3 x 3,203,072
#define O_AM     16003072
#define O_AL     19206144
#define O_B1H    22409216    // 16384 f32 slots each
#define O_B1M    22425600
#define O_B1L    22441984
#define O_B2H    22458368    // 8192 f32 slots each
#define O_B2M    22466560
#define O_B2L    22474752
#define O_WF     22482944    // 1,024 f32
#define O_SRC    22483968    // 850,000 u16 = 425,000 f32 slots
#define O_DST    22908968    // 850,000 u16
#define O_DEG    23333968    // 50,000 int
#define O_ROWPTR 23383968    // 50,001 int
#define O_CURSOR 23433969    // 50,000 int
#define O_CSR    23483969    // 850,000 u16
#define O_FLAGS  23908969    // 2 int
#define O_PART   23908971    // 196 int

// ---- Wf internal offsets ----
#define W_BL1   0
#define W_BR1   128
#define W_ATT1  256
#define W_BIAS1 384
#define W_BL2   512
#define W_BR2   576
#define W_ATT2  640
#define W_BIAS2 704

#define NB_SCAN  196         // ceil(50000/256)
#define NB_CVT   3321        // (ET+255)/256
#define NB_PACKX 25024       // NP*128/256
#define NB_PREP1 (NB_CVT + NB_PACKX + 128 + 64 + 1)
#define NB_G1    3128        // 782*4 gemm1 blocks
#define NB_G1S   (NB_G1 + NB_CVT)

__device__ __forceinline__ float load_f32(const void* src, int i, int isbf16) {
    if (isbf16) {
        u16 u = ((const u16*)src)[i];
        return __uint_as_float((unsigned)u << 16);
    }
    return ((const float*)src)[i];
}
__device__ __forceinline__ u16 f2b(float v) {
    __hip_bfloat16 h = __float2bfloat16(v);
    return *(u16*)&h;
}
__device__ __forceinline__ float b2f(u16 u) { return __uint_as_float((unsigned)u << 16); }

// 3-way split: v ~ hi + mid + lo, error ~2^-24 |v|
__device__ __forceinline__ void split3(float v, u16& hi, u16& mid, u16& lo) {
    hi = f2b(v);
    float r1 = v - b2f(hi);
    mid = f2b(r1);
    float r2 = r1 - b2f(mid);
    lo = f2b(r2);
}

// ---- fused init: deg=0 fill (blocks 0..195) + dtype detection (block 196) ----
__global__ void init_k(int* deg, const u16* x16, const int* ei32, int* flags) {
    int b = blockIdx.x;
    if (b < NB_SCAN) {
        int i = b * 256 + threadIdx.x;
        if (i < N_NODES) deg[i] = 0;
        return;
    }
    int lane = threadIdx.x;
    if (lane >= 64) return;
    int hits = 0;
    for (int j = lane; j < 32768; j += 64) {
        u16 u = x16[2 * j];
        if (((u >> 7) & 0xFF) == 0xFF) hits++;
    }
#pragma unroll
    for (int off = 32; off > 0; off >>= 1) hits += __shfl_xor(hits, off);
    int nz = 0;
    if (lane < 32) nz = ei32[2 * lane + 1];
#pragma unroll
    for (int off = 32; off > 0; off >>= 1) nz |= __shfl_xor(nz, off);
    if (lane == 0) { flags[0] = hits ? 0 : 1; flags[1] = nz ? 0 : 1; }
}

// ---- mega prep 1: cvt_edges | pack_x | pack_w1 | pack_w2 | params ----
__global__ void prep1_k(const int* __restrict__ ei, u16* __restrict__ srcA, u16* __restrict__ dstA,
                        int* __restrict__ deg,
                        const void* x, u16* AH, u16* AM, u16* AL,
                        const void* Wl1, const void* Wr1, u16* B1H, u16* B1M, u16* B1L,
                        const void* Wl2, const void* Wr2, u16* B2H, u16* B2M, u16* B2L,
                        const void* bl1, const void* br1, const void* att1, const void* bias1,
                        const void* bl2, const void* br2, const void* att2, const void* bias2,
                        float* Wf, const int* flags) {
    int b = blockIdx.x, t = threadIdx.x;
    int fb = flags[0];
    if (b < NB_CVT) {
        int e = b * 256 + t;
        if (e < ET) {
            int s, d;
            if (e < N_EDGES) {
                if (flags[1]) { s = ei[2 * e]; d = ei[2 * (N_EDGES + e)]; }
                else          { s = ei[e];     d = ei[N_EDGES + e]; }
            } else {
                s = d = e - N_EDGES;
            }
            srcA[e] = (u16)s; dstA[e] = (u16)d;
            atomicAdd(&deg[d], 1);
        }
        return;
    }
    b -= NB_CVT;
    if (b < NB_PACKX) {
        int i = b * 256 + t;           // i < NP*128 exactly
        int r = i >> 7, k = i & 127;
        u16 hi = 0, mid = 0, lo = 0;
        if (r < N_NODES) split3(load_f32(x, r * D1 + k, fb), hi, mid, lo);
        int idx = (r >> 4) * 2048 + (k >> 3) * 128 + (r & 15) * 8 + (k & 7);
        AH[idx] = hi; AM[idx] = mid; AL[idx] = lo;
        return;
    }
    b -= NB_PACKX;
    if (b < 128) {
        int i = b * 256 + t;           // i < 32768
        int k = i >> 8, n = i & 255;
        float v = (n < 128) ? load_f32(Wl1, k * 128 + n, fb)
                            : load_f32(Wr1, k * 128 + (n - 128), fb);
        u16 hi, mid, lo; split3(v, hi, mid, lo);
        int idx = ((k >> 3) * 256 + n) * 8 + (k & 7);
        B1H[idx] = hi; B1M[idx] = mid; B1L[idx] = lo;
        return;
    }
    b -= 128;
    if (b < 64) {
        int i = b * 256 + t;           // i < 16384
        int k = i >> 7, n = i & 127;
        float v = (n < 64) ? load_f32(Wl2, k * 64 + n, fb)
                           : load_f32(Wr2, k * 64 + (n - 64), fb);
        u16 hi, mid, lo; split3(v, hi, mid, lo);
        int idx = ((k >> 3) * 128 + n) * 8 + (k & 7);
        B2H[idx] = hi; B2M[idx] = mid; B2L[idx] = lo;
        return;
    }
    if (t < 128) {
        Wf[W_BL1 + t]   = load_f32(bl1, t, fb);
        Wf[W_BR1 + t]   = load_f32(br1, t, fb);
        Wf[W_ATT1 + t]  = load_f32(att1, t, fb);
        Wf[W_BIAS1 + t] = load_f32(bias1, t, fb);
        if (t < 64) {
            Wf[W_BL2 + t]   = load_f32(bl2, t, fb);
            Wf[W_BR2 + t]   = load_f32(br2, t, fb);
            Wf[W_ATT2 + t]  = load_f32(att2, t, fb);
            Wf[W_BIAS2 + t] = load_f32(bias2, t, fb);
        }
    }
}

// ---- 3-phase parallel exclusive scan of deg -> rowptr/cursor ----
__global__ __launch_bounds__(256) void scanA_k(const int* __restrict__ deg, int* __restrict__ part) {
    __shared__ int s[256];
    int t = threadIdx.x, i = blockIdx.x * 256 + t;
    s[t] = (i < N_NODES) ? deg[i] : 0;
    __syncthreads();
    for (int off = 128; off > 0; off >>= 1) {
        if (t < off) s[t] += s[t + off];
        __syncthreads();
    }
    if (t == 0) part[blockIdx.x] = s[0];
}

__global__ __launch_bounds__(256) void scanB_k(int* __restrict__ part) {
    __shared__ int s[256];
    int t = threadIdx.x;
    s[t] = (t < NB_SCAN) ? part[t] : 0;
    __syncthreads();
    for (int off = 1; off < 256; off <<= 1) {
        int v = (t >= off) ? s[t - off] : 0;
        __syncthreads();
        s[t] += v;
        __syncthreads();
    }
    if (t < NB_SCAN) part[t] = (t == 0) ? 0 : s[t - 1];
}

__global__ __launch_bounds__(256) void scanC_k(const int* __restrict__ deg, const int* __restrict__ part,
                                               int* __restrict__ rowptr, int* __restrict__ cursor) {
    __shared__ int s[256];
    int t = threadIdx.x, i = blockIdx.x * 256 + t;
    int v = (i < N_NODES) ? deg[i] : 0;
    s[t] = v;
    __syncthreads();
    for (int off = 1; off < 256; off <<= 1) {
        int u = (t >= off) ? s[t - off] : 0;
        __syncthreads();
        s[t] += u;
        __syncthreads();
    }
    int excl = part[blockIdx.x] + s[t] - v;
    if (i < N_NODES) { rowptr[i] = excl; cursor[i] = excl; }
    if (i == N_NODES - 1) rowptr[N_NODES] = excl + v;
}

// 6-term split-precision MFMA accumulate: acc += A*B with ~2^-24 relative error
#define MFMA6(acc, ah, am, al, bh, bm, bl)                                    \
    acc = __builtin_amdgcn_mfma_f32_16x16x32_bf16(ah, bl, acc, 0, 0, 0);      \
    acc = __builtin_amdgcn_mfma_f32_16x16x32_bf16(am, bm, acc, 0, 0, 0);      \
    acc = __builtin_amdgcn_mfma_f32_16x16x32_bf16(al, bh, acc, 0, 0, 0);      \
    acc = __builtin_amdgcn_mfma_f32_16x16x32_bf16(ah, bm, acc, 0, 0, 0);      \
    acc = __builtin_amdgcn_mfma_f32_16x16x32_bf16(am, bh, acc, 0, 0, 0);      \
    acc = __builtin_amdgcn_mfma_f32_16x16x32_bf16(ah, bh, acc, 0, 0, 0);

// ---- fused: gemm1 (blocks [0,NB_G1)) | csr scatter (blocks [NB_G1,NB_G1S)) ----
// gemm1: wave = 16 rows x 64 cols. MFMA-bound blocks overlap with atomic/memory-bound scatter.
__global__ __launch_bounds__(256) void g1s_k(const u16* __restrict__ AH, const u16* __restrict__ AM,
                                             const u16* __restrict__ AL,
                                             const u16* __restrict__ BH, const u16* __restrict__ BM,
                                             const u16* __restrict__ BL,
                                             const float* __restrict__ Wf,
                                             float* __restrict__ xl, float* __restrict__ xr,
                                             const u16* __restrict__ srcA, const u16* __restrict__ dstA,
                                             int* __restrict__ cursor, u16* __restrict__ csr) {
    int b = blockIdx.x;
    if (b < NB_G1) {
        int w = threadIdx.x >> 6, l = threadIdx.x & 63;
        int tile = (b >> 2) * 4 + w;
        int cb = (b & 3) << 6;                 // col base (0,64,128,192)
        int lr = l & 15, lg = l >> 4;
        f4v acc[4];
#pragma unroll
        for (int nt = 0; nt < 4; nt++) acc[nt] = (f4v)(0.f);
        int aoff = tile * 2048 + lg * 128 + lr * 8;
#pragma unroll
        for (int ks = 0; ks < 4; ks++) {
            bf8v ah = *(const bf8v*)(AH + aoff + ks * 512);
            bf8v am = *(const bf8v*)(AM + aoff + ks * 512);
            bf8v al = *(const bf8v*)(AL + aoff + ks * 512);
            int boff = ((ks * 4 + lg) * 256 + cb + lr) * 8;
#pragma unroll
            for (int nt = 0; nt < 4; nt++) {
                bf8v bh = *(const bf8v*)(BH + boff + nt * 128);
                bf8v bm = *(const bf8v*)(BM + boff + nt * 128);
                bf8v bl = *(const bf8v*)(BL + boff + nt * 128);
                MFMA6(acc[nt], ah, am, al, bh, bm, bl)
            }
        }
        int r0 = tile * 16 + lg * 4;
        if (r0 >= N_NODES) return;
#pragma unroll
        for (int nt = 0; nt < 4; nt++) {
            int col = cb + nt * 16 + lr;
            float bias = (col < D1) ? Wf[W_BL1 + col] : Wf[W_BR1 + col - D1];
            float* dst = (col < D1) ? (xl + col) : (xr + col - D1);
#pragma unroll
            for (int j = 0; j < 4; j++) {
                int row = r0 + j;
                dst[(size_t)row * D1] = acc[nt][j] + bias;
            }
        }
        return;
    }
    int e = (b - NB_G1) * 256 + threadIdx.x;
    if (e < ET) {
        int d = dstA[e];
        int idx = atomicAdd(&cursor[d], 1);
        csr[idx] = srcA[e];
    }
}

// MFMA GEMM 2: wave = 16 rows x 64 cols. Grid (782, 2) x 256 thr.
__global__ __launch_bounds__(256) void gemm2_mfma(const u16* __restrict__ AH, const u16* __restrict__ AM,
                                                  const u16* __restrict__ AL,
                                                  const u16* __restrict__ BH, const u16* __restrict__ BM,
                                                  const u16* __restrict__ BL,
                                                  const float* __restrict__ Wf,
                                                  float* __restrict__ xl2, float* __restrict__ xr2) {
    int w = threadIdx.x >> 6, l = threadIdx.x & 63;
    int tile = blockIdx.x * 4 + w;
    int cb = blockIdx.y << 6;                 // col base (0,64)
    int lr = l & 15, lg = l >> 4;
    f4v acc[4];
#pragma unroll
    for (int nt = 0; nt < 4; nt++) acc[nt] = (f4v)(0.f);
    int aoff = tile * 2048 + lg * 128 + lr * 8;
#pragma unroll
    for (int ks = 0; ks < 4; ks++) {
        bf8v ah = *(const bf8v*)(AH + aoff + ks * 512);
        bf8v am = *(const bf8v*)(AM + aoff + ks * 512);
        bf8v al = *(const bf8v*)(AL + aoff + ks * 512);
        int boff = ((ks * 4 + lg) * 128 + cb + lr) * 8;
#pragma unroll
        for (int nt = 0; nt < 4; nt++) {
            bf8v bh = *(const bf8v*)(BH + boff + nt * 128);
            bf8v bm = *(const bf8v*)(BM + boff + nt * 128);
            bf8v bl = *(const bf8v*)(BL + boff + nt * 128);
            MFMA6(acc[nt], ah, am, al, bh, bm, bl)
        }
    }
    int r0 = tile * 16 + lg * 4;
    if (r0 >= N_NODES) return;
#pragma unroll
    for (int nt = 0; nt < 4; nt++) {
        int col = cb + nt * 16 + lr;
        float bias = (col < D2) ? Wf[W_BL2 + col] : Wf[W_BR2 + col - D2];
        float* dst = (col < D2) ? (xl2 + col) : (xr2 + col - D2);
#pragma unroll
        for (int j = 0; j < 4; j++) {
            int row = r0 + j;
            dst[(size_t)row * D2] = acc[nt][j] + bias;
        }
    }
}

// layer-1 aggregation: 32 lanes/node (float4/lane), no-max softmax (clamp +-60),
// 1-deep gather prefetch, + bias1 + ELU -> 3-plane A2 fragments. Grid 6250 x 256.
#define L1STEP(a)                                                              \
    {                                                                          \
        float m0 = a.x + xr4.x; m0 = fmaxf(m0, NEG * m0);                      \
        float m1 = a.y + xr4.y; m1 = fmaxf(m1, NEG * m1);                      \
        float m2 = a.z + xr4.z; m2 = fmaxf(m2, NEG * m2);                      \
        float m3 = a.w + xr4.w; m3 = fmaxf(m3, NEG * m3);                      \
        float p = m0 * at4.x + m1 * at4.y + m2 * at4.z + m3 * at4.w;           \
        p += __shfl_xor(p, 1);                                                 \
        p += __shfl_xor(p, 2);                                                 \
        p = fminf(fmaxf(p, -60.f), 60.f);                                      \
        float wgt = __expf(p);                                                 \
        l += wgt;                                                              \
        acc.x = fmaf(wgt, a.x, acc.x);                                         \
        acc.y = fmaf(wgt, a.y, acc.y);                                         \
        acc.z = fmaf(wgt, a.z, acc.z);                                         \
        acc.w = fmaf(wgt, a.w, acc.w);                                         \
    }

__global__ __launch_bounds__(256) void l1_agg(const int* __restrict__ rowptr, const u16* __restrict__ csr,
                                              const float* __restrict__ xl, const float* __restrict__ xr,
                                              const float* __restrict__ Wf,
                                              u16* __restrict__ A2H, u16* __restrict__ A2M, u16* __restrict__ A2L) {
    int n = (blockIdx.x * 256 + threadIdx.x) >> 5;   // node (grid exact: 6250*8 = 50000)
    int q = threadIdx.x & 31;                        // channels 4q..4q+3, head = q>>2
    const float4* xl4 = (const float4*)xl;
    float4 xr4 = ((const float4*)(xr + (size_t)n * D1))[q];
    float4 at4 = ((const float4*)(Wf + W_ATT1))[q];
    int i0 = rowptr[n], i1 = rowptr[n + 1];
    float l = 0.f;
    float4 acc = {0.f, 0.f, 0.f, 0.f};
    float4 a = xl4[(size_t)csr[i0] * 32 + q];        // deg >= 1 (self-loop)
    for (int i = i0 + 1; i < i1; i++) {
        float4 an = xl4[(size_t)csr[i] * 32 + q];    // prefetch next row
        L1STEP(a)
        a = an;
    }
    L1STEP(a)
    float rinv = 1.f / l;
    float4 bi4 = ((const float4*)(Wf + W_BIAS1))[q];
    float v0 = acc.x * rinv + bi4.x; v0 = v0 > 0.f ? v0 : expm1f(v0);
    float v1 = acc.y * rinv + bi4.y; v1 = v1 > 0.f ? v1 : expm1f(v1);
    float v2 = acc.z * rinv + bi4.z; v2 = v2 > 0.f ? v2 : expm1f(v2);
    float v3 = acc.w * rinv + bi4.w; v3 = v3 > 0.f ? v3 : expm1f(v3);
    int base = (n >> 4) * 2048 + (q >> 1) * 128 + (n & 15) * 8 + (q & 1) * 4;
    ushort4 h4, m4, l4;
    split3(v0, h4.x, m4.x, l4.x);
    split3(v1, h4.y, m4.y, l4.y);
    split3(v2, h4.z, m4.z, l4.z);
    split3(v3, h4.w, m4.w, l4.w);
    *(ushort4*)(A2H + base) = h4;
    *(ushort4*)(A2M + base) = m4;
    *(ushort4*)(A2L + base) = l4;
}

// layer-2 aggregation: 16 lanes/node, no-max softmax (clamp +-80; e2 sigma ~8, 11-sigma to underflow),
// 1-deep prefetch, + bias2 + log_softmax + argmax. Grid 3125 x 256.
#define L2STEP(a)                                                              \
    {                                                                          \
        float m0 = a.x + xr4.x; m0 = fmaxf(m0, NEG * m0);                      \
        float m1 = a.y + xr4.y; m1 = fmaxf(m1, NEG * m1);                      \
        float m2 = a.z + xr4.z; m2 = fmaxf(m2, NEG * m2);                      \
        float m3 = a.w + xr4.w; m3 = fmaxf(m3, NEG * m3);                      \
        float p = m0 * at4.x + m1 * at4.y + m2 * at4.z + m3 * at4.w;           \
        p += __shfl_xor(p, 1);                                                 \
        p += __shfl_xor(p, 2);                                                 \
        p += __shfl_xor(p, 4);                                                 \
        p += __shfl_xor(p, 8);                                                 \
        p = fminf(fmaxf(p, -80.f), 80.f);                                      \
        float wgt = __expf(p);                                                 \
        l += wgt;                                                              \
        acc.x = fmaf(wgt, a.x, acc.x);                                         \
        acc.y = fmaf(wgt, a.y, acc.y);                                         \
        acc.z = fmaf(wgt, a.z, acc.z);                                         \
        acc.w = fmaf(wgt, a.w, acc.w);                                         \
    }

__global__ __launch_bounds__(256) void l2_agg(const int* __restrict__ rowptr, const u16* __restrict__ csr,
                                              const float* __restrict__ xl, const float* __restrict__ xr,
                                              const float* __restrict__ Wf, float* __restrict__ out) {
    int n = (blockIdx.x * 256 + threadIdx.x) >> 4;   // node (grid exact: 3125*16 = 50000)
    int q = threadIdx.x & 15;                        // channels 4q..4q+3
    const float4* xl4 = (const float4*)xl;
    float4 xr4 = ((const float4*)(xr + (size_t)n * D2))[q];
    float4 at4 = ((const float4*)(Wf + W_ATT2))[q];
    int i0 = rowptr[n], i1 = rowptr[n + 1];
    float l = 0.f;
    float4 acc = {0.f, 0.f, 0.f, 0.f};
    float4 a = xl4[(size_t)csr[i0] * 16 + q];
    for (int i = i0 + 1; i < i1; i++) {
        float4 an = xl4[(size_t)csr[i] * 16 + q];
        L2STEP(a)
        a = an;
    }
    L2STEP(a)
    float rinv = 1.f / (l + EPSF);
    float4 bi4 = ((const float4*)(Wf + W_BIAS2))[q];
    float v0 = acc.x * rinv + bi4.x;
    float v1 = acc.y * rinv + bi4.y;
    float v2 = acc.z * rinv + bi4.z;
    float v3 = acc.w * rinv + bi4.w;
    float4 hv = {v0, v1, v2, v3};
    ((float4*)(out + (size_t)n * D2))[q] = hv;
    // log-softmax over 64 classes = 16 lanes x 4
    float mx = fmaxf(fmaxf(v0, v1), fmaxf(v2, v3));
#pragma unroll
    for (int off = 1; off < 16; off <<= 1) mx = fmaxf(mx, __shfl_xor(mx, off));
    float sum = expf(v0 - mx) + expf(v1 - mx) + expf(v2 - mx) + expf(v3 - mx);
#pragma unroll
    for (int off = 1; off < 16; off <<= 1) sum += __shfl_xor(sum, off);
    float lse = mx + logf(sum);
    float4 ls = {v0 - lse, v1 - lse, v2 - lse, v3 - lse};
    ((float4*)(out + (size_t)N_NODES * D2 + (size_t)n * D2))[q] = ls;
    // argmax, first occurrence on ties (channels 4q+j are lane-contiguous)
    float bv = v0; int bi = 4 * q;
    if (v1 > bv) { bv = v1; bi = 4 * q + 1; }
    if (v2 > bv) { bv = v2; bi = 4 * q + 2; }
    if (v3 > bv) { bv = v3; bi = 4 * q + 3; }
#pragma unroll
    for (int off = 1; off < 16; off <<= 1) {
        float ov = __shfl_xor(bv, off);
        int   oi = __shfl_xor(bi, off);
        if (ov > bv || (ov == bv && oi < bi)) { bv = ov; bi = oi; }
    }
    if (q == 0) out[(size_t)2 * N_NODES * D2 + n] = (float)bi;
}

extern "C" void kernel_launch(void* const* d_in, const int* in_sizes, int n_in,
                              void* d_out, int out_size, void* d_ws, size_t ws_size,
                              hipStream_t stream) {
    const void* x  = d_in[0];
    const int*  ei = (const int*)d_in[1];

    float* ws = (float*)d_ws;
    float* xl1    = ws + O_XL1;
    float* xr1    = ws + O_XR1;
    u16*   AH     = (u16*)(ws + O_AH);
    u16*   AM     = (u16*)(ws + O_AM);
    u16*   AL     = (u16*)(ws + O_AL);
    u16*   B1H    = (u16*)(ws + O_B1H);
    u16*   B1M    = (u16*)(ws + O_B1M);
    u16*   B1L    = (u16*)(ws + O_B1L);
    u16*   B2H    = (u16*)(ws + O_B2H);
    u16*   B2M    = (u16*)(ws + O_B2M);
    u16*   B2L    = (u16*)(ws + O_B2L);
    float* Wf     = ws + O_WF;
    u16*   srcA   = (u16*)(ws + O_SRC);
    u16*   dstA   = (u16*)(ws + O_DST);
    int*   deg    = (int*)(ws + O_DEG);
    int*   rowptr = (int*)(ws + O_ROWPTR);
    int*   cursor = (int*)(ws + O_CURSOR);
    u16*   csr    = (u16*)(ws + O_CSR);
    int*   flags  = (int*)(ws + O_FLAGS);
    int*   part   = (int*)(ws + O_PART);

    float* xl2 = xl1;
    float* xr2 = xl1 + 3200000;

    init_k<<<NB_SCAN + 1, 256, 0, stream>>>(deg, (const u16*)x, ei, flags);
    prep1_k<<<NB_PREP1, 256, 0, stream>>>(ei, srcA, dstA, deg,
                                          x, AH, AM, AL,
                                          d_in[2], d_in[4], B1H, B1M, B1L,
                                          d_in[8], d_in[10], B2H, B2M, B2L,
                                          d_in[3], d_in[5], d_in[6], d_in[7],
                                          d_in[9], d_in[11], d_in[12], d_in[13],
                                          Wf, flags);
    scanA_k<<<NB_SCAN, 256, 0, stream>>>(deg, part);
    scanB_k<<<1, 256, 0, stream>>>(part);
    scanC_k<<<NB_SCAN, 256, 0, stream>>>(deg, part, rowptr, cursor);

    g1s_k<<<NB_G1S, 256, 0, stream>>>(AH, AM, AL, B1H, B1M, B1L, Wf, xl1, xr1,
                                      srcA, dstA, cursor, csr);
    l1_agg<<<6250, 256, 0, stream>>>(rowptr, csr, xl1, xr1, Wf, AH, AM, AL);
    gemm2_mfma<<<dim3(NTILES_PAD / 4, 2), 256, 0, stream>>>(AH, AM, AL, B2H, B2M, B2L, Wf, xl2, xr2);
    l2_agg<<<3125, 256, 0, stream>>>(rowptr, csr, xl2, xr2, Wf, (float*)d_out);
}

// Round 11
// 286.247 us; speedup vs baseline: 37.8987x; 1.0099x over previous
//
#include <hip/hip_runtime.h>
#include <hip/hip_bf16.h>

typedef unsigned short u16;
typedef __attribute__((ext_vector_type(8))) short bf8v;   // 8 x bf16 (4 VGPRs)
typedef __attribute__((ext_vector_type(4))) float f4v;    // 4 x f32 acc

#define N_NODES 50000
#define N_EDGES 800000
#define ET (N_EDGES + N_NODES)
#define D1 128
#define D2 64
#define NEG 0.2f
#define EPSF 1e-16f
#define NTILES_PAD 3128
#define NP (NTILES_PAD * 16) // 50048 rows

// ---- ws layout (float offsets) ----
#define O_XL1    0           // 6,400,000 f32
#define O_XR1    6400000     // 6,400,000 f32
#define O_AH     12800000    // A planes shared by A1 (x) then A2 (h): 3 x 3,203,072
#define O_AM     16003072
#define O_AL     19206144
#define O_B1H    22409216    // 16384 f32 slots each
#define O_B1M    22425600
#define O_B1L    22441984
#define O_B2H    22458368    // 8192 f32 slots each
#define O_B2M    22466560
#define O_B2L    22474752
#define O_WF     22482944    // 1,024 f32
#define O_SRC    22483968    // 850,000 u16 = 425,000 f32 slots
#define O_DST    22908968    // 850,000 u16
#define O_DEG    23333968    // 50,000 int
#define O_ROWPTR 23383968    // 50,001 int
#define O_CURSOR 23433969    // 50,000 int
#define O_CSR    23483969    // 850,000 u16
#define O_FLAGS  23908969    // 2 int
#define O_PART   23908971    // 196 int

// ---- Wf internal offsets ----
#define W_BL1   0
#define W_BR1   128
#define W_ATT1  256
#define W_BIAS1 384
#define W_BL2   512
#define W_BR2   576
#define W_ATT2  640
#define W_BIAS2 704

#define NB_SCAN  196         // ceil(50000/256)
#define NB_CVT   3321        // (ET+255)/256
#define NB_PACKX 3128        // NP*128/8/256  (8 u16 per thread per plane)
#define NB_PWS   (NB_CVT + NB_PACKX + 128 + 64 + 1)

__device__ __forceinline__ float load_f32(const void* src, int i, int isbf16) {
    if (isbf16) {
        u16 u = ((const u16*)src)[i];
        return __uint_as_float((unsigned)u << 16);
    }
    return ((const float*)src)[i];
}
__device__ __forceinline__ u16 f2b(float v) {
    __hip_bfloat16 h = __float2bfloat16(v);
    return *(u16*)&h;
}
__device__ __forceinline__ float b2f(u16 u) { return __uint_as_float((unsigned)u << 16); }

// 3-way split: v ~ hi + mid + lo, error ~2^-24 |v|
__device__ __forceinline__ void split3(float v, u16& hi, u16& mid, u16& lo) {
    hi = f2b(v);
    float r1 = v - b2f(hi);
    mid = f2b(r1);
    float r2 = r1 - b2f(mid);
    lo = f2b(r2);
}

// ---- fused init: deg=0 fill (blocks 0..195) + dtype detection (block 196) ----
__global__ void init_k(int* deg, const u16* x16, const int* ei32, int* flags) {
    int b = blockIdx.x;
    if (b < NB_SCAN) {
        int i = b * 256 + threadIdx.x;
        if (i < N_NODES) deg[i] = 0;
        return;
    }
    int lane = threadIdx.x;
    if (lane >= 64) return;
    int hits = 0;
    for (int j = lane; j < 32768; j += 64) {
        u16 u = x16[2 * j];
        if (((u >> 7) & 0xFF) == 0xFF) hits++;
    }
#pragma unroll
    for (int off = 32; off > 0; off >>= 1) hits += __shfl_xor(hits, off);
    int nz = 0;
    if (lane < 32) nz = ei32[2 * lane + 1];
#pragma unroll
    for (int off = 32; off > 0; off >>= 1) nz |= __shfl_xor(nz, off);
    if (lane == 0) { flags[0] = hits ? 0 : 1; flags[1] = nz ? 0 : 1; }
}

// ---- canonicalize edges (+self-loops) and histogram dst degrees ----
__global__ void cvt_k(const int* __restrict__ ei, const int* __restrict__ flags,
                      u16* __restrict__ srcA, u16* __restrict__ dstA, int* __restrict__ deg) {
    int e = blockIdx.x * 256 + threadIdx.x;
    if (e >= ET) return;
    int s, d;
    if (e < N_EDGES) {
        if (flags[1]) { s = ei[2 * e]; d = ei[2 * (N_EDGES + e)]; }
        else          { s = ei[e];     d = ei[N_EDGES + e]; }
    } else {
        s = d = e - N_EDGES;
    }
    srcA[e] = (u16)s; dstA[e] = (u16)d;
    atomicAdd(&deg[d], 1);
}

// ---- 3-phase parallel exclusive scan of deg -> rowptr/cursor ----
__global__ __launch_bounds__(256) void scanA_k(const int* __restrict__ deg, int* __restrict__ part) {
    __shared__ int s[256];
    int t = threadIdx.x, i = blockIdx.x * 256 + t;
    s[t] = (i < N_NODES) ? deg[i] : 0;
    __syncthreads();
    for (int off = 128; off > 0; off >>= 1) {
        if (t < off) s[t] += s[t + off];
        __syncthreads();
    }
    if (t == 0) part[blockIdx.x] = s[0];
}

__global__ __launch_bounds__(256) void scanB_k(int* __restrict__ part) {
    __shared__ int s[256];
    int t = threadIdx.x;
    s[t] = (t < NB_SCAN) ? part[t] : 0;
    __syncthreads();
    for (int off = 1; off < 256; off <<= 1) {
        int v = (t >= off) ? s[t - off] : 0;
        __syncthreads();
        s[t] += v;
        __syncthreads();
    }
    if (t < NB_SCAN) part[t] = (t == 0) ? 0 : s[t - 1];
}

__global__ __launch_bounds__(256) void scanC_k(const int* __restrict__ deg, const int* __restrict__ part,
                                               int* __restrict__ rowptr, int* __restrict__ cursor) {
    __shared__ int s[256];
    int t = threadIdx.x, i = blockIdx.x * 256 + t;
    int v = (i < N_NODES) ? deg[i] : 0;
    s[t] = v;
    __syncthreads();
    for (int off = 1; off < 256; off <<= 1) {
        int u = (t >= off) ? s[t - off] : 0;
        __syncthreads();
        s[t] += u;
        __syncthreads();
    }
    int excl = part[blockIdx.x] + s[t] - v;
    if (i < N_NODES) { rowptr[i] = excl; cursor[i] = excl; }
    if (i == N_NODES - 1) rowptr[N_NODES] = excl + v;
}

// ---- pws: csr scatter (atomic/latency) || pack_x (streaming) || pack_w || params ----
// pack_x: output-contiguous mapping — thread owns 8 consecutive output u16 per plane.
// j = i*8; tile=j>>11; jj=j&2047; r=tile*16+((jj>>3)&15); k=(jj>>7)*8+(jj&7).
__global__ void pws_k(const u16* __restrict__ srcA, const u16* __restrict__ dstA,
                      int* __restrict__ cursor, u16* __restrict__ csr,
                      const void* x, u16* AH, u16* AM, u16* AL,
                      const void* Wl1, const void* Wr1, u16* B1H, u16* B1M, u16* B1L,
                      const void* Wl2, const void* Wr2, u16* B2H, u16* B2M, u16* B2L,
                      const void* bl1, const void* br1, const void* att1, const void* bias1,
                      const void* bl2, const void* br2, const void* att2, const void* bias2,
                      float* Wf, const int* flags) {
    int b = blockIdx.x, t = threadIdx.x;
    int fb = flags[0];
    if (b < NB_CVT) {
        int e = b * 256 + t;
        if (e < ET) {
            int d = dstA[e];
            int idx = atomicAdd(&cursor[d], 1);
            csr[idx] = srcA[e];
        }
        return;
    }
    b -= NB_CVT;
    if (b < NB_PACKX) {
        int i = b * 256 + t;            // i < 800768 exactly
        int j = i * 8;                  // output u16 index
        int tile = j >> 11;
        int jj = j & 2047;
        int r = tile * 16 + ((jj >> 3) & 15);
        int k0 = (jj >> 7) * 8;
        uint4 H = {0, 0, 0, 0}, M = {0, 0, 0, 0}, L = {0, 0, 0, 0};
        u16* Hp = (u16*)&H; u16* Mp = (u16*)&M; u16* Lp = (u16*)&L;
        if (r < N_NODES) {
            if (fb) {
                H = *(const uint4*)((const u16*)x + r * D1 + k0);   // exact bf16: mid=lo=0
            } else {
                float4 xa = *(const float4*)((const float*)x + r * D1 + k0);
                float4 xb = *(const float4*)((const float*)x + r * D1 + k0 + 4);
                float vv[8] = {xa.x, xa.y, xa.z, xa.w, xb.x, xb.y, xb.z, xb.w};
#pragma unroll
                for (int e2 = 0; e2 < 8; e2++) split3(vv[e2], Hp[e2], Mp[e2], Lp[e2]);
            }
        }
        *(uint4*)(AH + j) = H;
        *(uint4*)(AM + j) = M;
        *(uint4*)(AL + j) = L;
        return;
    }
    b -= NB_PACKX;
    if (b < 128) {
        int i = b * 256 + t;           // i < 32768
        int k = i >> 8, n = i & 255;
        float v = (n < 128) ? load_f32(Wl1, k * 128 + n, fb)
                            : load_f32(Wr1, k * 128 + (n - 128), fb);
        u16 hi, mid, lo; split3(v, hi, mid, lo);
        int idx = ((k >> 3) * 256 + n) * 8 + (k & 7);
        B1H[idx] = hi; B1M[idx] = mid; B1L[idx] = lo;
        return;
    }
    b -= 128;
    if (b < 64) {
        int i = b * 256 + t;           // i < 16384
        int k = i >> 7, n = i & 127;
        float v = (n < 64) ? load_f32(Wl2, k * 64 + n, fb)
                           : load_f32(Wr2, k * 64 + (n - 64), fb);
        u16 hi, mid, lo; split3(v, hi, mid, lo);
        int idx = ((k >> 3) * 128 + n) * 8 + (k & 7);
        B2H[idx] = hi; B2M[idx] = mid; B2L[idx] = lo;
        return;
    }
    if (t < 128) {
        Wf[W_BL1 + t]   = load_f32(bl1, t, fb);
        Wf[W_BR1 + t]   = load_f32(br1, t, fb);
        Wf[W_ATT1 + t]  = load_f32(att1, t, fb);
        Wf[W_BIAS1 + t] = load_f32(bias1, t, fb);
        if (t < 64) {
            Wf[W_BL2 + t]   = load_f32(bl2, t, fb);
            Wf[W_BR2 + t]   = load_f32(br2, t, fb);
            Wf[W_ATT2 + t]  = load_f32(att2, t, fb);
            Wf[W_BIAS2 + t] = load_f32(bias2, t, fb);
        }
    }
}

// 6-term split-precision MFMA accumulate: acc += A*B with ~2^-24 relative error
#define MFMA6(acc, ah, am, al, bh, bm, bl)                                    \
    acc = __builtin_amdgcn_mfma_f32_16x16x32_bf16(ah, bl, acc, 0, 0, 0);      \
    acc = __builtin_amdgcn_mfma_f32_16x16x32_bf16(am, bm, acc, 0, 0, 0);      \
    acc = __builtin_amdgcn_mfma_f32_16x16x32_bf16(al, bh, acc, 0, 0, 0);      \
    acc = __builtin_amdgcn_mfma_f32_16x16x32_bf16(ah, bm, acc, 0, 0, 0);      \
    acc = __builtin_amdgcn_mfma_f32_16x16x32_bf16(am, bh, acc, 0, 0, 0);      \
    acc = __builtin_amdgcn_mfma_f32_16x16x32_bf16(ah, bh, acc, 0, 0, 0);

// MFMA GEMM 1: wave = 16 rows x 64 cols (col chunk = blockIdx.y). Grid (782, 4) x 256 thr.
__global__ __launch_bounds__(256) void gemm1_mfma(const u16* __restrict__ AH, const u16* __restrict__ AM,
                                                  const u16* __restrict__ AL,
                                                  const u16* __restrict__ BH, const u16* __restrict__ BM,
                                                  const u16* __restrict__ BL,
                                                  const float* __restrict__ Wf,
                                                  float* __restrict__ xl, float* __restrict__ xr) {
    int w = threadIdx.x >> 6, l = threadIdx.x & 63;
    int tile = blockIdx.x * 4 + w;
    int cb = blockIdx.y << 6;                 // col base (0,64,128,192)
    int lr = l & 15, lg = l >> 4;
    f4v acc[4];
#pragma unroll
    for (int nt = 0; nt < 4; nt++) acc[nt] = (f4v)(0.f);
    int aoff = tile * 2048 + lg * 128 + lr * 8;
#pragma unroll
    for (int ks = 0; ks < 4; ks++) {
        bf8v ah = *(const bf8v*)(AH + aoff + ks * 512);
        bf8v am = *(const bf8v*)(AM + aoff + ks * 512);
        bf8v al = *(const bf8v*)(AL + aoff + ks * 512);
        int boff = ((ks * 4 + lg) * 256 + cb + lr) * 8;
#pragma unroll
        for (int nt = 0; nt < 4; nt++) {
            bf8v bh = *(const bf8v*)(BH + boff + nt * 128);
            bf8v bm = *(const bf8v*)(BM + boff + nt * 128);
            bf8v bl = *(const bf8v*)(BL + boff + nt * 128);
            MFMA6(acc[nt], ah, am, al, bh, bm, bl)
        }
    }
    int r0 = tile * 16 + lg * 4;
    if (r0 >= N_NODES) return;
#pragma unroll
    for (int nt = 0; nt < 4; nt++) {
        int col = cb + nt * 16 + lr;
        float bias = (col < D1) ? Wf[W_BL1 + col] : Wf[W_BR1 + col - D1];
        float* dst = (col < D1) ? (xl + col) : (xr + col - D1);
#pragma unroll
        for (int j = 0; j < 4; j++) {
            int row = r0 + j;
            dst[(size_t)row * D1] = acc[nt][j] + bias;
        }
    }
}

// MFMA GEMM 2: wave = 16 rows x 64 cols. Grid (782, 2) x 256 thr.
__global__ __launch_bounds__(256) void gemm2_mfma(const u16* __restrict__ AH, const u16* __restrict__ AM,
                                                  const u16* __restrict__ AL,
                                                  const u16* __restrict__ BH, const u16* __restrict__ BM,
                                                  const u16* __restrict__ BL,
                                                  const float* __restrict__ Wf,
                                                  float* __restrict__ xl2, float* __restrict__ xr2) {
    int w = threadIdx.x >> 6, l = threadIdx.x & 63;
    int tile = blockIdx.x * 4 + w;
    int cb = blockIdx.y << 6;                 // col base (0,64)
    int lr = l & 15, lg = l >> 4;
    f4v acc[4];
#pragma unroll
    for (int nt = 0; nt < 4; nt++) acc[nt] = (f4v)(0.f);
    int aoff = tile * 2048 + lg * 128 + lr * 8;
#pragma unroll
    for (int ks = 0; ks < 4; ks++) {
        bf8v ah = *(const bf8v*)(AH + aoff + ks * 512);
        bf8v am = *(const bf8v*)(AM + aoff + ks * 512);
        bf8v al = *(const bf8v*)(AL + aoff + ks * 512);
        int boff = ((ks * 4 + lg) * 128 + cb + lr) * 8;
#pragma unroll
        for (int nt = 0; nt < 4; nt++) {
            bf8v bh = *(const bf8v*)(BH + boff + nt * 128);
            bf8v bm = *(const bf8v*)(BM + boff + nt * 128);
            bf8v bl = *(const bf8v*)(BL + boff + nt * 128);
            MFMA6(acc[nt], ah, am, al, bh, bm, bl)
        }
    }
    int r0 = tile * 16 + lg * 4;
    if (r0 >= N_NODES) return;
#pragma unroll
    for (int nt = 0; nt < 4; nt++) {
        int col = cb + nt * 16 + lr;
        float bias = (col < D2) ? Wf[W_BL2 + col] : Wf[W_BR2 + col - D2];
        float* dst = (col < D2) ? (xl2 + col) : (xr2 + col - D2);
#pragma unroll
        for (int j = 0; j < 4; j++) {
            int row = r0 + j;
            dst[(size_t)row * D2] = acc[nt][j] + bias;
        }
    }
}

// layer-1 aggregation: 32 lanes/node (float4/lane), no-max softmax (clamp +-60),
// 1-deep gather prefetch, + bias1 + ELU -> 3-plane A2 fragments. Grid 6250 x 256.
#define L1STEP(a)                                                              \
    {                                                                          \
        float m0 = a.x + xr4.x; m0 = fmaxf(m0, NEG * m0);                      \
        float m1 = a.y + xr4.y; m1 = fmaxf(m1, NEG * m1);                      \
        float m2 = a.z + xr4.z; m2 = fmaxf(m2, NEG * m2);                      \
        float m3 = a.w + xr4.w; m3 = fmaxf(m3, NEG * m3);                      \
        float p = m0 * at4.x + m1 * at4.y + m2 * at4.z + m3 * at4.w;           \
        p += __shfl_xor(p, 1);                                                 \
        p += __shfl_xor(p, 2);                                                 \
        p = fminf(fmaxf(p, -60.f), 60.f);                                      \
        float wgt = __expf(p);                                                 \
        l += wgt;                                                              \
        acc.x = fmaf(wgt, a.x, acc.x);                                         \
        acc.y = fmaf(wgt, a.y, acc.y);                                         \
        acc.z = fmaf(wgt, a.z, acc.z);                                         \
        acc.w = fmaf(wgt, a.w, acc.w);                                         \
    }

__global__ __launch_bounds__(256) void l1_agg(const int* __restrict__ rowptr, const u16* __restrict__ csr,
                                              const float* __restrict__ xl, const float* __restrict__ xr,
                                              const float* __restrict__ Wf,
                                              u16* __restrict__ A2H, u16* __restrict__ A2M, u16* __restrict__ A2L) {
    int n = (blockIdx.x * 256 + threadIdx.x) >> 5;   // node (grid exact: 6250*8 = 50000)
    int q = threadIdx.x & 31;                        // channels 4q..4q+3, head = q>>2
    const float4* xl4 = (const float4*)xl;
    float4 xr4 = ((const float4*)(xr + (size_t)n * D1))[q];
    float4 at4 = ((const float4*)(Wf + W_ATT1))[q];
    int i0 = rowptr[n], i1 = rowptr[n + 1];
    float l = 0.f;
    float4 acc = {0.f, 0.f, 0.f, 0.f};
    float4 a = xl4[(size_t)csr[i0] * 32 + q];        // deg >= 1 (self-loop)
    for (int i = i0 + 1; i < i1; i++) {
        float4 an = xl4[(size_t)csr[i] * 32 + q];    // prefetch next row
        L1STEP(a)
        a = an;
    }
    L1STEP(a)
    float rinv = 1.f / l;
    float4 bi4 = ((const float4*)(Wf + W_BIAS1))[q];
    float v0 = acc.x * rinv + bi4.x; v0 = v0 > 0.f ? v0 : expm1f(v0);
    float v1 = acc.y * rinv + bi4.y; v1 = v1 > 0.f ? v1 : expm1f(v1);
    float v2 = acc.z * rinv + bi4.z; v2 = v2 > 0.f ? v2 : expm1f(v2);
    float v3 = acc.w * rinv + bi4.w; v3 = v3 > 0.f ? v3 : expm1f(v3);
    int base = (n >> 4) * 2048 + (q >> 1) * 128 + (n & 15) * 8 + (q & 1) * 4;
    ushort4 h4, m4, l4;
    split3(v0, h4.x, m4.x, l4.x);
    split3(v1, h4.y, m4.y, l4.y);
    split3(v2, h4.z, m4.z, l4.z);
    split3(v3, h4.w, m4.w, l4.w);
    *(ushort4*)(A2H + base) = h4;
    *(ushort4*)(A2M + base) = m4;
    *(ushort4*)(A2L + base) = l4;
}

// layer-2 aggregation: 16 lanes/node, no-max softmax (clamp +-80),
// 1-deep prefetch, + bias2 + log_softmax + argmax. Grid 3125 x 256.
#define L2STEP(a)                                                              \
    {                                                                          \
        float m0 = a.x + xr4.x; m0 = fmaxf(m0, NEG * m0);                      \
        float m1 = a.y + xr4.y; m1 = fmaxf(m1, NEG * m1);                      \
        float m2 = a.z + xr4.z; m2 = fmaxf(m2, NEG * m2);                      \
        float m3 = a.w + xr4.w; m3 = fmaxf(m3, NEG * m3);                      \
        float p = m0 * at4.x + m1 * at4.y + m2 * at4.z + m3 * at4.w;           \
        p += __shfl_xor(p, 1);                                                 \
        p += __shfl_xor(p, 2);                                                 \
        p += __shfl_xor(p, 4);                                                 \
        p += __shfl_xor(p, 8);                                                 \
        p = fminf(fmaxf(p, -80.f), 80.f);                                      \
        float wgt = __expf(p);                                                 \
        l += wgt;                                                              \
        acc.x = fmaf(wgt, a.x, acc.x);                                         \
        acc.y = fmaf(wgt, a.y, acc.y);                                         \
        acc.z = fmaf(wgt, a.z, acc.z);                                         \
        acc.w = fmaf(wgt, a.w, acc.w);                                         \
    }

__global__ __launch_bounds__(256) void l2_agg(const int* __restrict__ rowptr, const u16* __restrict__ csr,
                                              const float* __restrict__ xl, const float* __restrict__ xr,
                                              const float* __restrict__ Wf, float* __restrict__ out) {
    int n = (blockIdx.x * 256 + threadIdx.x) >> 4;   // node (grid exact: 3125*16 = 50000)
    int q = threadIdx.x & 15;                        // channels 4q..4q+3
    const float4* xl4 = (const float4*)xl;
    float4 xr4 = ((const float4*)(xr + (size_t)n * D2))[q];
    float4 at4 = ((const float4*)(Wf + W_ATT2))[q];
    int i0 = rowptr[n], i1 = rowptr[n + 1];
    float l = 0.f;
    float4 acc = {0.f, 0.f, 0.f, 0.f};
    float4 a = xl4[(size_t)csr[i0] * 16 + q];
    for (int i = i0 + 1; i < i1; i++) {
        float4 an = xl4[(size_t)csr[i] * 16 + q];
        L2STEP(a)
        a = an;
    }
    L2STEP(a)
    float rinv = 1.f / (l + EPSF);
    float4 bi4 = ((const float4*)(Wf + W_BIAS2))[q];
    float v0 = acc.x * rinv + bi4.x;
    float v1 = acc.y * rinv + bi4.y;
    float v2 = acc.z * rinv + bi4.z;
    float v3 = acc.w * rinv + bi4.w;
    float4 hv = {v0, v1, v2, v3};
    ((float4*)(out + (size_t)n * D2))[q] = hv;
    // log-softmax over 64 classes = 16 lanes x 4
    float mx = fmaxf(fmaxf(v0, v1), fmaxf(v2, v3));
#pragma unroll
    for (int off = 1; off < 16; off <<= 1) mx = fmaxf(mx, __shfl_xor(mx, off));
    float sum = expf(v0 - mx) + expf(v1 - mx) + expf(v2 - mx) + expf(v3 - mx);
#pragma unroll
    for (int off = 1; off < 16; off <<= 1) sum += __shfl_xor(sum, off);
    float lse = mx + logf(sum);
    float4 ls = {v0 - lse, v1 - lse, v2 - lse, v3 - lse};
    ((float4*)(out + (size_t)N_NODES * D2 + (size_t)n * D2))[q] = ls;
    // argmax, first occurrence on ties (channels 4q+j are lane-contiguous)
    float bv = v0; int bi = 4 * q;
    if (v1 > bv) { bv = v1; bi = 4 * q + 1; }
    if (v2 > bv) { bv = v2; bi = 4 * q + 2; }
    if (v3 > bv) { bv = v3; bi = 4 * q + 3; }
#pragma unroll
    for (int off = 1; off < 16; off <<= 1) {
        float ov = __shfl_xor(bv, off);
        int   oi = __shfl_xor(bi, off);
        if (ov > bv || (ov == bv && oi < bi)) { bv = ov; bi = oi; }
    }
    if (q == 0) out[(size_t)2 * N_NODES * D2 + n] = (float)bi;
}

extern "C" void kernel_launch(void* const* d_in, const int* in_sizes, int n_in,
                              void* d_out, int out_size, void* d_ws, size_t ws_size,
                              hipStream_t stream) {
    const void* x  = d_in[0];
    const int*  ei = (const int*)d_in[1];

    float* ws = (float*)d_ws;
    float* xl1    = ws + O_XL1;
    float* xr1    = ws + O_XR1;
    u16*   AH     = (u16*)(ws + O_AH);
    u16*   AM     = (u16*)(ws + O_AM);
    u16*   AL     = (u16*)(ws + O_AL);
    u16*   B1H    = (u16*)(ws + O_B1H);
    u16*   B1M    = (u16*)(ws + O_B1M);
    u16*   B1L    = (u16*)(ws + O_B1L);
    u16*   B2H    = (u16*)(ws + O_B2H);
    u16*   B2M    = (u16*)(ws + O_B2M);
    u16*   B2L    = (u16*)(ws + O_B2L);
    float* Wf     = ws + O_WF;
    u16*   srcA   = (u16*)(ws + O_SRC);
    u16*   dstA   = (u16*)(ws + O_DST);
    int*   deg    = (int*)(ws + O_DEG);
    int*   rowptr = (int*)(ws + O_ROWPTR);
    int*   cursor = (int*)(ws + O_CURSOR);
    u16*   csr    = (u16*)(ws + O_CSR);
    int*   flags  = (int*)(ws + O_FLAGS);
    int*   part   = (int*)(ws + O_PART);

    float* xl2 = xl1;
    float* xr2 = xl1 + 3200000;

    init_k<<<NB_SCAN + 1, 256, 0, stream>>>(deg, (const u16*)x, ei, flags);
    cvt_k<<<NB_CVT, 256, 0, stream>>>(ei, flags, srcA, dstA, deg);
    scanA_k<<<NB_SCAN, 256, 0, stream>>>(deg, part);
    scanB_k<<<1, 256, 0, stream>>>(part);
    scanC_k<<<NB_SCAN, 256, 0, stream>>>(deg, part, rowptr, cursor);
    pws_k<<<NB_PWS, 256, 0, stream>>>(srcA, dstA, cursor, csr,
                                      x, AH, AM, AL,
                                      d_in[2], d_in[4], B1H, B1M, B1L,
                                      d_in[8], d_in[10], B2H, B2M, B2L,
                                      d_in[3], d_in[5], d_in[6], d_in[7],
                                      d_in[9], d_in[11], d_in[12], d_in[13],
                                      Wf, flags);

    gemm1_mfma<<<dim3(NTILES_PAD / 4, 4), 256, 0, stream>>>(AH, AM, AL, B1H, B1M, B1L, Wf, xl1, xr1);
    l1_agg<<<6250, 256, 0, stream>>>(rowptr, csr, xl1, xr1, Wf, AH, AM, AL);
    gemm2_mfma<<<dim3(NTILES_PAD / 4, 2), 256, 0, stream>>>(AH, AM, AL, B2H, B2M, B2L, Wf, xl2, xr2);
    l2_agg<<<3125, 256, 0, stream>>>(rowptr, csr, xl2, xr2, Wf, (float*)d_out);
}

// Round 12
// 254.944 us; speedup vs baseline: 42.5520x; 1.1228x over previous
//
#include <hip/hip_runtime.h>
#include <hip/hip_bf16.h>

typedef unsigned short u16;
typedef __attribute__((ext_vector_type(8))) short bf8v;   // 8 x bf16 (4 VGPRs)
typedef __attribute__((ext_vector_type(4))) float f4v;    // 4 x f32 acc

#define N_NODES 50000
#define N_EDGES 800000
#define ET (N_EDGES + N_NODES)
#define D1 128
#define D2 64
#define NEG 0.2f
#define EPSF 1e-16f
#define NTILES_PAD 3128
#define NP (NTILES_PAD * 16) // 50048 rows

// ---- ws layout (float offsets) ----
#define O_XL1    0           // 6,400,000 f32
#define O_XR1    6400000     // 6,400,000 f32
#define O_AH     12800000    // A planes shared by A1 (x) then A2 (h): 3 x 3,203,072
#define O_AM     16003072
#define O_AL     19206144
#define O_B1H    22409216    // 16384 f32 slots each
#define O_B1M    22425600
#define O_B1L    22441984
#define O_B2H    22458368    // 8192 f32 slots each
#define O_B2M    22466560
#define O_B2L    22474752
#define O_WF     22482944    // 1,024 f32
#define O_SRC    22483968    // 850,000 u16 = 425,000 f32
#define O_DST    22908968    // 850,000 u16
#define O_DEG    23333968    // 50,000 int
#define O_ROWPTR 23383968    // 50,001 int
#define O_RANK   23433969    // 850,000 u16
#define O_CSR    23858969    // 850,000 u16
#define O_FLAGS  24283969    // 2 int
#define O_PART   24283971    // 196 int

// ---- Wf internal offsets ----
#define W_BL1   0
#define W_BR1   128
#define W_ATT1  256
#define W_BIAS1 384
#define W_BL2   512
#define W_BR2   576
#define W_ATT2  640
#define W_BIAS2 704

#define NB_SCAN  196         // ceil(50000/256)
#define NB_CVT   3321        // (ET+255)/256
#define NB_PACKX 3128        // NP*128/8/256 (8 u16/thread/plane)
#define NB_PK    (NB_SCAN + NB_PACKX + 128 + 64 + 1)
#define NB_G1    3128        // gemm1 blocks (782 tile-groups x 4 col-chunks)
#define NB_SG    (NB_G1 + NB_CVT)

__device__ __forceinline__ float load_f32(const void* src, int i, int isbf16) {
    if (isbf16) {
        u16 u = ((const u16*)src)[i];
        return __uint_as_float((unsigned)u << 16);
    }
    return ((const float*)src)[i];
}
__device__ __forceinline__ u16 f2b(float v) {
    __hip_bfloat16 h = __float2bfloat16(v);
    return *(u16*)&h;
}
__device__ __forceinline__ float b2f(u16 u) { return __uint_as_float((unsigned)u << 16); }

// 3-way split: v ~ hi + mid + lo, error ~2^-24 |v|
__device__ __forceinline__ void split3(float v, u16& hi, u16& mid, u16& lo) {
    hi = f2b(v);
    float r1 = v - b2f(hi);
    mid = f2b(r1);
    float r2 = r1 - b2f(mid);
    lo = f2b(r2);
}

// ---- fused init: deg=0 fill (blocks 0..195) + dtype detection (block 196) ----
__global__ void init_k(int* deg, const u16* x16, const int* ei32, int* flags) {
    int b = blockIdx.x;
    if (b < NB_SCAN) {
        int i = b * 256 + threadIdx.x;
        if (i < N_NODES) deg[i] = 0;
        return;
    }
    int lane = threadIdx.x;
    if (lane >= 64) return;
    int hits = 0;
    for (int j = lane; j < 32768; j += 64) {
        u16 u = x16[2 * j];
        if (((u >> 7) & 0xFF) == 0xFF) hits++;
    }
#pragma unroll
    for (int off = 32; off > 0; off >>= 1) hits += __shfl_xor(hits, off);
    int nz = 0;
    if (lane < 32) nz = ei32[2 * lane + 1];
#pragma unroll
    for (int off = 32; off > 0; off >>= 1) nz |= __shfl_xor(nz, off);
    if (lane == 0) { flags[0] = hits ? 0 : 1; flags[1] = nz ? 0 : 1; }
}

// ---- canonicalize edges (+self-loops), histogram dst degree, CAPTURE RANK ----
// rank[e] = this edge's arrival index within its dst bucket (atomic return value).
__global__ void cvt_k(const int* __restrict__ ei, const int* __restrict__ flags,
                      u16* __restrict__ srcA, u16* __restrict__ dstA,
                      u16* __restrict__ rank, int* __restrict__ deg) {
    int e = blockIdx.x * 256 + threadIdx.x;
    if (e >= ET) return;
    int s, d;
    if (e < N_EDGES) {
        if (flags[1]) { s = ei[2 * e]; d = ei[2 * (N_EDGES + e)]; }
        else          { s = ei[e];     d = ei[N_EDGES + e]; }
    } else {
        s = d = e - N_EDGES;
    }
    srcA[e] = (u16)s; dstA[e] = (u16)d;
    rank[e] = (u16)atomicAdd(&deg[d], 1);
}

// ---- pk: scanA (deg block-sums) || pack_x || pack_w1 || pack_w2 || params ----
__global__ void pk_k(const int* __restrict__ deg, int* __restrict__ part,
                     const void* x, u16* AH, u16* AM, u16* AL,
                     const void* Wl1, const void* Wr1, u16* B1H, u16* B1M, u16* B1L,
                     const void* Wl2, const void* Wr2, u16* B2H, u16* B2M, u16* B2L,
                     const void* bl1, const void* br1, const void* att1, const void* bias1,
                     const void* bl2, const void* br2, const void* att2, const void* bias2,
                     float* Wf, const int* flags) {
    int b = blockIdx.x, t = threadIdx.x;
    int fb = flags[0];
    if (b < NB_SCAN) {
        __shared__ int s[256];
        int i = b * 256 + t;
        s[t] = (i < N_NODES) ? deg[i] : 0;
        __syncthreads();
        for (int off = 128; off > 0; off >>= 1) {
            if (t < off) s[t] += s[t + off];
            __syncthreads();
        }
        if (t == 0) part[b] = s[0];
        return;
    }
    b -= NB_SCAN;
    if (b < NB_PACKX) {
        int i = b * 256 + t;            // i < 800768 exactly
        int j = i * 8;                  // output u16 index
        int tile = j >> 11;
        int jj = j & 2047;
        int r = tile * 16 + ((jj >> 3) & 15);
        int k0 = (jj >> 7) * 8;
        uint4 H = {0, 0, 0, 0}, M = {0, 0, 0, 0}, L = {0, 0, 0, 0};
        u16* Hp = (u16*)&H; u16* Mp = (u16*)&M; u16* Lp = (u16*)&L;
        if (r < N_NODES) {
            if (fb) {
                H = *(const uint4*)((const u16*)x + r * D1 + k0);   // exact bf16: mid=lo=0
            } else {
                float4 xa = *(const float4*)((const float*)x + r * D1 + k0);
                float4 xb = *(const float4*)((const float*)x + r * D1 + k0 + 4);
                float vv[8] = {xa.x, xa.y, xa.z, xa.w, xb.x, xb.y, xb.z, xb.w};
#pragma unroll
                for (int e2 = 0; e2 < 8; e2++) split3(vv[e2], Hp[e2], Mp[e2], Lp[e2]);
            }
        }
        *(uint4*)(AH + j) = H;
        *(uint4*)(AM + j) = M;
        *(uint4*)(AL + j) = L;
        return;
    }
    b -= NB_PACKX;
    if (b < 128) {
        int i = b * 256 + t;           // i < 32768
        int k = i >> 8, n = i & 255;
        float v = (n < 128) ? load_f32(Wl1, k * 128 + n, fb)
                            : load_f32(Wr1, k * 128 + (n - 128), fb);
        u16 hi, mid, lo; split3(v, hi, mid, lo);
        int idx = ((k >> 3) * 256 + n) * 8 + (k & 7);
        B1H[idx] = hi; B1M[idx] = mid; B1L[idx] = lo;
        return;
    }
    b -= 128;
    if (b < 64) {
        int i = b * 256 + t;           // i < 16384
        int k = i >> 7, n = i & 127;
        float v = (n < 64) ? load_f32(Wl2, k * 64 + n, fb)
                           : load_f32(Wr2, k * 64 + (n - 64), fb);
        u16 hi, mid, lo; split3(v, hi, mid, lo);
        int idx = ((k >> 3) * 128 + n) * 8 + (k & 7);
        B2H[idx] = hi; B2M[idx] = mid; B2L[idx] = lo;
        return;
    }
    if (t < 128) {
        Wf[W_BL1 + t]   = load_f32(bl1, t, fb);
        Wf[W_BR1 + t]   = load_f32(br1, t, fb);
        Wf[W_ATT1 + t]  = load_f32(att1, t, fb);
        Wf[W_BIAS1 + t] = load_f32(bias1, t, fb);
        if (t < 64) {
            Wf[W_BL2 + t]   = load_f32(bl2, t, fb);
            Wf[W_BR2 + t]   = load_f32(br2, t, fb);
            Wf[W_ATT2 + t]  = load_f32(att2, t, fb);
            Wf[W_BIAS2 + t] = load_f32(bias2, t, fb);
        }
    }
}

__global__ __launch_bounds__(256) void scanB_k(int* __restrict__ part) {
    __shared__ int s[256];
    int t = threadIdx.x;
    s[t] = (t < NB_SCAN) ? part[t] : 0;
    __syncthreads();
    for (int off = 1; off < 256; off <<= 1) {
        int v = (t >= off) ? s[t - off] : 0;
        __syncthreads();
        s[t] += v;
        __syncthreads();
    }
    if (t < NB_SCAN) part[t] = (t == 0) ? 0 : s[t - 1];
}

__global__ __launch_bounds__(256) void scanC_k(const int* __restrict__ deg, const int* __restrict__ part,
                                               int* __restrict__ rowptr) {
    __shared__ int s[256];
    int t = threadIdx.x, i = blockIdx.x * 256 + t;
    int v = (i < N_NODES) ? deg[i] : 0;
    s[t] = v;
    __syncthreads();
    for (int off = 1; off < 256; off <<= 1) {
        int u = (t >= off) ? s[t - off] : 0;
        __syncthreads();
        s[t] += u;
        __syncthreads();
    }
    int excl = part[blockIdx.x] + s[t] - v;
    if (i < N_NODES) rowptr[i] = excl;
    if (i == N_NODES - 1) rowptr[N_NODES] = excl + v;
}

// 6-term split-precision MFMA accumulate: acc += A*B with ~2^-24 relative error
#define MFMA6(acc, ah, am, al, bh, bm, bl)                                    \
    acc = __builtin_amdgcn_mfma_f32_16x16x32_bf16(ah, bl, acc, 0, 0, 0);      \
    acc = __builtin_amdgcn_mfma_f32_16x16x32_bf16(am, bm, acc, 0, 0, 0);      \
    acc = __builtin_amdgcn_mfma_f32_16x16x32_bf16(al, bh, acc, 0, 0, 0);      \
    acc = __builtin_amdgcn_mfma_f32_16x16x32_bf16(ah, bm, acc, 0, 0, 0);      \
    acc = __builtin_amdgcn_mfma_f32_16x16x32_bf16(am, bh, acc, 0, 0, 0);      \
    acc = __builtin_amdgcn_mfma_f32_16x16x32_bf16(ah, bh, acc, 0, 0, 0);

// ---- sg: gemm1 (blocks [0,NB_G1)) || atomic-free csr scatter ----
__global__ __launch_bounds__(256) void sg_k(const u16* __restrict__ AH, const u16* __restrict__ AM,
                                            const u16* __restrict__ AL,
                                            const u16* __restrict__ BH, const u16* __restrict__ BM,
                                            const u16* __restrict__ BL,
                                            const float* __restrict__ Wf,
                                            float* __restrict__ xl, float* __restrict__ xr,
                                            const u16* __restrict__ srcA, const u16* __restrict__ dstA,
                                            const u16* __restrict__ rank, const int* __restrict__ rowptr,
                                            u16* __restrict__ csr) {
    int b = blockIdx.x;
    if (b < NB_G1) {
        int w = threadIdx.x >> 6, l = threadIdx.x & 63;
        int tile = (b >> 2) * 4 + w;
        int cb = (b & 3) << 6;                 // col base (0,64,128,192)
        int lr = l & 15, lg = l >> 4;
        f4v acc[4];
#pragma unroll
        for (int nt = 0; nt < 4; nt++) acc[nt] = (f4v)(0.f);
        int aoff = tile * 2048 + lg * 128 + lr * 8;
#pragma unroll
        for (int ks = 0; ks < 4; ks++) {
            bf8v ah = *(const bf8v*)(AH + aoff + ks * 512);
            bf8v am = *(const bf8v*)(AM + aoff + ks * 512);
            bf8v al = *(const bf8v*)(AL + aoff + ks * 512);
            int boff = ((ks * 4 + lg) * 256 + cb + lr) * 8;
#pragma unroll
            for (int nt = 0; nt < 4; nt++) {
                bf8v bh = *(const bf8v*)(BH + boff + nt * 128);
                bf8v bm = *(const bf8v*)(BM + boff + nt * 128);
                bf8v bl = *(const bf8v*)(BL + boff + nt * 128);
                MFMA6(acc[nt], ah, am, al, bh, bm, bl)
            }
        }
        int r0 = tile * 16 + lg * 4;
        if (r0 >= N_NODES) return;
#pragma unroll
        for (int nt = 0; nt < 4; nt++) {
            int col = cb + nt * 16 + lr;
            float bias = (col < D1) ? Wf[W_BL1 + col] : Wf[W_BR1 + col - D1];
            float* dst = (col < D1) ? (xl + col) : (xr + col - D1);
#pragma unroll
            for (int j = 0; j < 4; j++) {
                int row = r0 + j;
                dst[(size_t)row * D1] = acc[nt][j] + bias;
            }
        }
        return;
    }
    int e = (b - NB_G1) * 256 + threadIdx.x;
    if (e < ET) {
        int d = dstA[e];
        csr[rowptr[d] + rank[e]] = srcA[e];    // unique slot, no atomic
    }
}

// MFMA GEMM 2: wave = 16 rows x 64 cols. Grid (782, 2) x 256 thr.
__global__ __launch_bounds__(256) void gemm2_mfma(const u16* __restrict__ AH, const u16* __restrict__ AM,
                                                  const u16* __restrict__ AL,
                                                  const u16* __restrict__ BH, const u16* __restrict__ BM,
                                                  const u16* __restrict__ BL,
                                                  const float* __restrict__ Wf,
                                                  float* __restrict__ xl2, float* __restrict__ xr2) {
    int w = threadIdx.x >> 6, l = threadIdx.x & 63;
    int tile = blockIdx.x * 4 + w;
    int cb = blockIdx.y << 6;                 // col base (0,64)
    int lr = l & 15, lg = l >> 4;
    f4v acc[4];
#pragma unroll
    for (int nt = 0; nt < 4; nt++) acc[nt] = (f4v)(0.f);
    int aoff = tile * 2048 + lg * 128 + lr * 8;
#pragma unroll
    for (int ks = 0; ks < 4; ks++) {
        bf8v ah = *(const bf8v*)(AH + aoff + ks * 512);
        bf8v am = *(const bf8v*)(AM + aoff + ks * 512);
        bf8v al = *(const bf8v*)(AL + aoff + ks * 512);
        int boff = ((ks * 4 + lg) * 128 + cb + lr) * 8;
#pragma unroll
        for (int nt = 0; nt < 4; nt++) {
            bf8v bh = *(const bf8v*)(BH + boff + nt * 128);
            bf8v bm = *(const bf8v*)(BM + boff + nt * 128);
            bf8v bl = *(const bf8v*)(BL + boff + nt * 128);
            MFMA6(acc[nt], ah, am, al, bh, bm, bl)
        }
    }
    int r0 = tile * 16 + lg * 4;
    if (r0 >= N_NODES) return;
#pragma unroll
    for (int nt = 0; nt < 4; nt++) {
        int col = cb + nt * 16 + lr;
        float bias = (col < D2) ? Wf[W_BL2 + col] : Wf[W_BR2 + col - D2];
        float* dst = (col < D2) ? (xl2 + col) : (xr2 + col - D2);
#pragma unroll
        for (int j = 0; j < 4; j++) {
            int row = r0 + j;
            dst[(size_t)row * D2] = acc[nt][j] + bias;
        }
    }
}

// layer-1 aggregation: 32 lanes/node (float4/lane), no-max softmax (clamp +-60),
// 1-deep gather prefetch, + bias1 + ELU -> 3-plane A2 fragments. Grid 6250 x 256.
#define L1STEP(a)                                                              \
    {                                                                          \
        float m0 = a.x + xr4.x; m0 = fmaxf(m0, NEG * m0);                      \
        float m1 = a.y + xr4.y; m1 = fmaxf(m1, NEG * m1);                      \
        float m2 = a.z + xr4.z; m2 = fmaxf(m2, NEG * m2);                      \
        float m3 = a.w + xr4.w; m3 = fmaxf(m3, NEG * m3);                      \
        float p = m0 * at4.x + m1 * at4.y + m2 * at4.z + m3 * at4.w;           \
        p += __shfl_xor(p, 1);                                                 \
        p += __shfl_xor(p, 2);                                                 \
        p = fminf(fmaxf(p, -60.f), 60.f);                                      \
        float wgt = __expf(p);                                                 \
        l += wgt;                                                              \
        acc.x = fmaf(wgt, a.x, acc.x);                                         \
        acc.y = fmaf(wgt, a.y, acc.y);                                         \
        acc.z = fmaf(wgt, a.z, acc.z);                                         \
        acc.w = fmaf(wgt, a.w, acc.w);                                         \
    }

__global__ __launch_bounds__(256) void l1_agg(const int* __restrict__ rowptr, const u16* __restrict__ csr,
                                              const float* __restrict__ xl, const float* __restrict__ xr,
                                              const float* __restrict__ Wf,
                                              u16* __restrict__ A2H, u16* __restrict__ A2M, u16* __restrict__ A2L) {
    int n = (blockIdx.x * 256 + threadIdx.x) >> 5;   // node (grid exact: 6250*8 = 50000)
    int q = threadIdx.x & 31;                        // channels 4q..4q+3, head = q>>2
    const float4* xl4 = (const float4*)xl;
    float4 xr4 = ((const float4*)(xr + (size_t)n * D1))[q];
    float4 at4 = ((const float4*)(Wf + W_ATT1))[q];
    int i0 = rowptr[n], i1 = rowptr[n + 1];
    float l = 0.f;
    float4 acc = {0.f, 0.f, 0.f, 0.f};
    float4 a = xl4[(size_t)csr[i0] * 32 + q];        // deg >= 1 (self-loop)
    for (int i = i0 + 1; i < i1; i++) {
        float4 an = xl4[(size_t)csr[i] * 32 + q];    // prefetch next row
        L1STEP(a)
        a = an;
    }
    L1STEP(a)
    float rinv = 1.f / l;
    float4 bi4 = ((const float4*)(Wf + W_BIAS1))[q];
    float v0 = acc.x * rinv + bi4.x; v0 = v0 > 0.f ? v0 : expm1f(v0);
    float v1 = acc.y * rinv + bi4.y; v1 = v1 > 0.f ? v1 : expm1f(v1);
    float v2 = acc.z * rinv + bi4.z; v2 = v2 > 0.f ? v2 : expm1f(v2);
    float v3 = acc.w * rinv + bi4.w; v3 = v3 > 0.f ? v3 : expm1f(v3);
    int base = (n >> 4) * 2048 + (q >> 1) * 128 + (n & 15) * 8 + (q & 1) * 4;
    ushort4 h4, m4, l4;
    split3(v0, h4.x, m4.x, l4.x);
    split3(v1, h4.y, m4.y, l4.y);
    split3(v2, h4.z, m4.z, l4.z);
    split3(v3, h4.w, m4.w, l4.w);
    *(ushort4*)(A2H + base) = h4;
    *(ushort4*)(A2M + base) = m4;
    *(ushort4*)(A2L + base) = l4;
}

// layer-2 aggregation: 16 lanes/node, no-max softmax (clamp +-80),
// 1-deep prefetch, + bias2 + log_softmax + argmax. Grid 3125 x 256.
#define L2STEP(a)                                                              \
    {                                                                          \
        float m0 = a.x + xr4.x; m0 = fmaxf(m0, NEG * m0);                      \
        float m1 = a.y + xr4.y; m1 = fmaxf(m1, NEG * m1);                      \
        float m2 = a.z + xr4.z; m2 = fmaxf(m2, NEG * m2);                      \
        float m3 = a.w + xr4.w; m3 = fmaxf(m3, NEG * m3);                      \
        float p = m0 * at4.x + m1 * at4.y + m2 * at4.z + m3 * at4.w;           \
        p += __shfl_xor(p, 1);                                                 \
        p += __shfl_xor(p, 2);                                                 \
        p += __shfl_xor(p, 4);                                                 \
        p += __shfl_xor(p, 8);                                                 \
        p = fminf(fmaxf(p, -80.f), 80.f);                                      \
        float wgt = __expf(p);                                                 \
        l += wgt;                                                              \
        acc.x = fmaf(wgt, a.x, acc.x);                                         \
        acc.y = fmaf(wgt, a.y, acc.y);                                         \
        acc.z = fmaf(wgt, a.z, acc.z);                                         \
        acc.w = fmaf(wgt, a.w, acc.w);                                         \
    }

__global__ __launch_bounds__(256) void l2_agg(const int* __restrict__ rowptr, const u16* __restrict__ csr,
                                              const float* __restrict__ xl, const float* __restrict__ xr,
                                              const float* __restrict__ Wf, float* __restrict__ out) {
    int n = (blockIdx.x * 256 + threadIdx.x) >> 4;   // node (grid exact: 3125*16 = 50000)
    int q = threadIdx.x & 15;                        // channels 4q..4q+3
    const float4* xl4 = (const float4*)xl;
    float4 xr4 = ((const float4*)(xr + (size_t)n * D2))[q];
    float4 at4 = ((const float4*)(Wf + W_ATT2))[q];
    int i0 = rowptr[n], i1 = rowptr[n + 1];
    float l = 0.f;
    float4 acc = {0.f, 0.f, 0.f, 0.f};
    float4 a = xl4[(size_t)csr[i0] * 16 + q];
    for (int i = i0 + 1; i < i1; i++) {
        float4 an = xl4[(size_t)csr[i] * 16 + q];
        L2STEP(a)
        a = an;
    }
    L2STEP(a)
    float rinv = 1.f / (l + EPSF);
    float4 bi4 = ((const float4*)(Wf + W_BIAS2))[q];
    float v0 = acc.x * rinv + bi4.x;
    float v1 = acc.y * rinv + bi4.y;
    float v2 = acc.z * rinv + bi4.z;
    float v3 = acc.w * rinv + bi4.w;
    float4 hv = {v0, v1, v2, v3};
    ((float4*)(out + (size_t)n * D2))[q] = hv;
    // log-softmax over 64 classes = 16 lanes x 4
    float mx = fmaxf(fmaxf(v0, v1), fmaxf(v2, v3));
#pragma unroll
    for (int off = 1; off < 16; off <<= 1) mx = fmaxf(mx, __shfl_xor(mx, off));
    float sum = expf(v0 - mx) + expf(v1 - mx) + expf(v2 - mx) + expf(v3 - mx);
#pragma unroll
    for (int off = 1; off < 16; off <<= 1) sum += __shfl_xor(sum, off);
    float lse = mx + logf(sum);
    float4 ls = {v0 - lse, v1 - lse, v2 - lse, v3 - lse};
    ((float4*)(out + (size_t)N_NODES * D2 + (size_t)n * D2))[q] = ls;
    // argmax, first occurrence on ties (channels 4q+j are lane-contiguous)
    float bv = v0; int bi = 4 * q;
    if (v1 > bv) { bv = v1; bi = 4 * q + 1; }
    if (v2 > bv) { bv = v2; bi = 4 * q + 2; }
    if (v3 > bv) { bv = v3; bi = 4 * q + 3; }
#pragma unroll
    for (int off = 1; off < 16; off <<= 1) {
        float ov = __shfl_xor(bv, off);
        int   oi = __shfl_xor(bi, off);
        if (ov > bv || (ov == bv && oi < bi)) { bv = ov; bi = oi; }
    }
    if (q == 0) out[(size_t)2 * N_NODES * D2 + n] = (float)bi;
}

extern "C" void kernel_launch(void* const* d_in, const int* in_sizes, int n_in,
                              void* d_out, int out_size, void* d_ws, size_t ws_size,
                              hipStream_t stream) {
    const void* x  = d_in[0];
    const int*  ei = (const int*)d_in[1];

    float* ws = (float*)d_ws;
    float* xl1    = ws + O_XL1;
    float* xr1    = ws + O_XR1;
    u16*   AH     = (u16*)(ws + O_AH);
    u16*   AM     = (u16*)(ws + O_AM);
    u16*   AL     = (u16*)(ws + O_AL);
    u16*   B1H    = (u16*)(ws + O_B1H);
    u16*   B1M    = (u16*)(ws + O_B1M);
    u16*   B1L    = (u16*)(ws + O_B1L);
    u16*   B2H    = (u16*)(ws + O_B2H);
    u16*   B2M    = (u16*)(ws + O_B2M);
    u16*   B2L    = (u16*)(ws + O_B2L);
    float* Wf     = ws + O_WF;
    u16*   srcA   = (u16*)(ws + O_SRC);
    u16*   dstA   = (u16*)(ws + O_DST);
    int*   deg    = (int*)(ws + O_DEG);
    int*   rowptr = (int*)(ws + O_ROWPTR);
    u16*   rank   = (u16*)(ws + O_RANK);
    u16*   csr    = (u16*)(ws + O_CSR);
    int*   flags  = (int*)(ws + O_FLAGS);
    int*   part   = (int*)(ws + O_PART);

    float* xl2 = xl1;
    float* xr2 = xl1 + 3200000;

    init_k<<<NB_SCAN + 1, 256, 0, stream>>>(deg, (const u16*)x, ei, flags);
    cvt_k<<<NB_CVT, 256, 0, stream>>>(ei, flags, srcA, dstA, rank, deg);
    pk_k<<<NB_PK, 256, 0, stream>>>(deg, part,
                                    x, AH, AM, AL,
                                    d_in[2], d_in[4], B1H, B1M, B1L,
                                    d_in[8], d_in[10], B2H, B2M, B2L,
                                    d_in[3], d_in[5], d_in[6], d_in[7],
                                    d_in[9], d_in[11], d_in[12], d_in[13],
                                    Wf, flags);
    scanB_k<<<1, 256, 0, stream>>>(part);
    scanC_k<<<NB_SCAN, 256, 0, stream>>>(deg, part, rowptr);
    sg_k<<<NB_SG, 256, 0, stream>>>(AH, AM, AL, B1H, B1M, B1L, Wf, xl1, xr1,
                                    srcA, dstA, rank, rowptr, csr);

    l1_agg<<<6250, 256, 0, stream>>>(rowptr, csr, xl1, xr1, Wf, AH, AM, AL);
    gemm2_mfma<<<dim3(NTILES_PAD / 4, 2), 256, 0, stream>>>(AH, AM, AL, B2H, B2M, B2L, Wf, xl2, xr2);
    l2_agg<<<3125, 256, 0, stream>>>(rowptr, csr, xl2, xr2, Wf, (float*)d_out);
}